// Round 6
// baseline (2226.379 us; speedup 1.0000x reference)
//
#include <hip/hip_runtime.h>

#define DEV __device__ __forceinline__

typedef unsigned short bhalf;
typedef __attribute__((ext_vector_type(8))) short bf8v;
typedef __attribute__((ext_vector_type(4))) float f4;

namespace {
constexpr int TPB = 256;
constexpr float ATT_SCALE = 0.08838834764831845f; // 1/sqrt(128)

// ---- workspace byte offsets ----
constexpr size_t O_PT  = 0;          // bf16 [640][64][256]  modalities, zero-pad rows
constexpr size_t O_WTS = 20971520;   // bf16 transposed weights (see W_* below)
constexpr size_t O_K1B = 21626880;   // bf16 [128][64][128]
constexpr size_t O_V1B = 23724032;   // bf16 [128][64][256]
constexpr size_t O_VQT = 27918336;   // bf16 [128][128][64]  (v1@arm_q)^T
constexpr size_t O_VKT = 30015488;   // bf16 [128][128][64]
constexpr size_t O_VTB = 32112640;   // bf16 [128][64][256]  v1@arm_v
constexpr size_t O_VWT = 36306944;   // bf16 [128][256][64]  (vt@epw)^T
constexpr size_t O_Q2B = 40501248;   // bf16 [640][64][128]
constexpr size_t O_K2B = 50987008;   // bf16 [640][64][128]
constexpr size_t O_W2T = 61472768;   // bf16 [640][256][64]
constexpr size_t O_FV  = 82444288;   // f32  [640][256]  node features X
constexpr size_t O_HWS = 83099648;   // f32  [3200][256]
constexpr size_t O_EDG = 86376448;   // f32  [3200][256]
constexpr size_t O_ST  = 89653248;   // f32  [256] stats + grid barrier
constexpr size_t O_XA  = 89654272;
constexpr size_t O_XB  = 90309632;
constexpr size_t O_XU  = 90964992;
constexpr size_t O_XV  = 91620352;
constexpr size_t O_EE  = 92275712;
constexpr size_t O_ET  = 95552512;

// WTS element offsets (bf16 elems), all stored as Wt[n][k=256]
constexpr size_t W_FAMQ = 0, W_FAMK = 32768, W_ARMQ = 65536, W_ARMK = 98304,
                 W_FAMV = 131072, W_ARMV = 196608, W_EPW = 262144;
} // namespace

// ---------- helpers ----------

DEV bhalf f2b(float f) {
  unsigned u = __float_as_uint(f);
  return (bhalf)((u + 0x7FFFu + ((u >> 16) & 1u)) >> 16);
}

DEV f4 mfma16(bf8v a, bf8v b, f4 c) {
  return __builtin_amdgcn_mfma_f32_16x16x32_bf16(a, b, c, 0, 0, 0);
}

// fragment load: lane l reads row (r0 + (l&15)), 8 contiguous k at k0 + (l>>4)*8
DEV bf8v ldfrag(const bhalf* base, int r0, int k0, int S, int l) {
  return *reinterpret_cast<const bf8v*>(base + (size_t)(r0 + (l & 15)) * S + k0 + ((l >> 4) << 3));
}

// swizzled LDS fragment load: byte = row*stride + koffB, XOR'd with ((row&7)<<4)
DEV bf8v ldswz(const bhalf* base, int row, int koffB, int strideB) {
  int byte = row * strideB + koffB;
  byte ^= ((row & 7) << 4);
  return *reinterpret_cast<const bf8v*>(reinterpret_cast<const char*>(base) + byte);
}

// in-register row softmax: sv[nt][reg], row per reg spans cols nt*16+(l&15) across 16 lanes
DEV void regSoftmax(float sv[4][4]) {
  #pragma unroll
  for (int reg = 0; reg < 4; ++reg) {
    float m = fmaxf(fmaxf(sv[0][reg], sv[1][reg]), fmaxf(sv[2][reg], sv[3][reg]));
    #pragma unroll
    for (int off = 1; off <= 8; off <<= 1) m = fmaxf(m, __shfl_xor(m, off));
    float s = 0.f;
    #pragma unroll
    for (int nt = 0; nt < 4; ++nt) { float e = __expf(sv[nt][reg] - m); sv[nt][reg] = e; s += e; }
    #pragma unroll
    for (int off = 1; off <= 8; off <<= 1) s += __shfl_xor(s, off);
    float inv = 1.f / s;
    #pragma unroll
    for (int nt = 0; nt < 4; ++nt) sv[nt][reg] *= inv;
  }
}

DEV void reduce2Atomic(float a, float b, float* ga, float* gb, float* red) {
  #pragma unroll
  for (int off = 32; off; off >>= 1) { a += __shfl_down(a, off); b += __shfl_down(b, off); }
  if ((threadIdx.x & 63) == 0) { int w = threadIdx.x >> 6; red[w*2] = a; red[w*2+1] = b; }
  __syncthreads();
  if (threadIdx.x == 0) {
    atomicAdd(ga, red[0]+red[2]+red[4]+red[6]);
    atomicAdd(gb, red[1]+red[3]+red[5]+red[7]);
  }
  __syncthreads();
}

// manual grid barrier (device-scope atomics; requires all blocks co-resident,
// guaranteed by __launch_bounds__(256,3): 768 slots >= 640 blocks).
// bar[0] = arrival counter, bar[1] = generation. Zeroed by host memset per launch.
DEV void gridSync(unsigned* bar, unsigned nblk) {
  __syncthreads();
  if (threadIdx.x == 0) {
    unsigned gen = __hip_atomic_load(&bar[1], __ATOMIC_RELAXED, __HIP_MEMORY_SCOPE_AGENT);
    unsigned prev = __hip_atomic_fetch_add(&bar[0], 1u, __ATOMIC_ACQ_REL, __HIP_MEMORY_SCOPE_AGENT);
    if (prev == nblk - 1u) {
      __hip_atomic_store(&bar[0], 0u, __ATOMIC_RELAXED, __HIP_MEMORY_SCOPE_AGENT);
      __hip_atomic_fetch_add(&bar[1], 1u, __ATOMIC_ACQ_REL, __HIP_MEMORY_SCOPE_AGENT);
    } else {
      while (__hip_atomic_load(&bar[1], __ATOMIC_ACQUIRE, __HIP_MEMORY_SCOPE_AGENT) == gen)
        __builtin_amdgcn_s_sleep(1);
    }
  }
  __syncthreads();
}

// ---------- prep kernels ----------

// transpose 7 weight matrices to bf16 Wt[n][256]
__global__ void __launch_bounds__(256) wprep(const float* fq, const float* fk, const float* fv,
                                             const float* aq, const float* ak, const float* av,
                                             const float* ep, bhalf* WT) {
  int blk = blockIdx.x, tid = threadIdx.x;
  const float* src; bhalf* dst; int N, n;
  if (blk < 512) {
    int m = blk >> 7; n = blk & 127; N = 128;
    src = (m==0)?fq:(m==1)?fk:(m==2)?aq:ak;
    dst = WT + (size_t)m*32768;
  } else {
    int r = blk - 512; int m = r >> 8; n = r & 255; N = 256;
    src = (m==0)?fv:(m==1)?av:ep;
    dst = WT + 131072 + (size_t)m*65536;
  }
  dst[(size_t)n*256 + tid] = f2b(src[(size_t)tid*N + n]);
}

// per (bt,u): transpose modality slice to bf16 Pt[64][256] (zero-pad rows) + fv means
__global__ void __launch_bounds__(256) modprep(const float* af, const float* ef, const float* gf,
                                               const float* attf, const float* sf,
                                               bhalf* PT, float* FV) {
  __shared__ float lb[49*260];
  int blk = blockIdx.x, tid = threadIdx.x;
  int u = blk % 5, bt = blk / 5, b = bt >> 4, t = bt & 15;
  const float* src = (u==0)?af:(u==1)?ef:(u==2)?gf:(u==3)?attf:sf;
  src += ((size_t)b*256*16 + t)*49;
  for (int o = tid; o < 49*256; o += TPB) {
    int c = o / 49, p = o % 49;
    lb[p*260 + c] = src[(size_t)c*784 + p];
  }
  __syncthreads();
  bhalf* pt = PT + (size_t)blk*16384;
  for (int p = 0; p < 64; ++p)
    pt[p*256 + tid] = (p < 49) ? f2b(lb[p*260 + tid]) : (bhalf)0;
  float s = 0.f;
  for (int p = 0; p < 49; ++p) s += lb[p*260 + tid];
  FV[(((size_t)(b*5+u)*16) + t)*256 + tid] = s * (1.f/49.f);
}

// ---------- MFMA GEMM chain (fine nt-split over blockIdx.y for latency hiding) ----------

// per (bt, part): parts 0-1: k1 = Paf@fam_k nt quarters; parts 2-5: v1 = Paf@fam_v quarters
__global__ void __launch_bounds__(256) kv1a(const bhalf* PT, const bhalf* WT,
                                            bhalf* K1B, bhalf* V1B) {
  int bt = blockIdx.x, part = blockIdx.y;
  int tid = threadIdx.x, w = tid >> 6, l = tid & 63;
  const bhalf* A = PT + (size_t)bt*5*16384; // u=0 (af)
  bf8v a8[8];
  #pragma unroll
  for (int kt = 0; kt < 8; ++kt) a8[kt] = ldfrag(A, w*16, kt*32, 256, l);
  const bhalf* Wb; bhalf* dst; int nt0, S;
  if (part < 2) { Wb = WT + W_FAMK; dst = K1B + (size_t)bt*8192;  nt0 = part*4;     S = 128; }
  else          { Wb = WT + W_FAMV; dst = V1B + (size_t)bt*16384; nt0 = (part-2)*4; S = 256; }
  #pragma unroll
  for (int nn = 0; nn < 4; ++nn) {
    int nt = nt0 + nn;
    f4 acc = {0.f,0.f,0.f,0.f};
    #pragma unroll
    for (int kt = 0; kt < 8; ++kt)
      acc = mfma16(a8[kt], ldfrag(Wb, nt*16, kt*32, 256, l), acc);
    #pragma unroll
    for (int reg = 0; reg < 4; ++reg) {
      int p = w*16 + ((l>>4)<<2) + reg;
      dst[(size_t)p*S + nt*16 + (l&15)] = f2b(acc[reg]);
    }
  }
}

// per (bt, part): parts 0-1: vqt; 2-3: vkt (transposed [128][64]); 4-7: vtb quarters
__global__ void __launch_bounds__(256) kv1b(const bhalf* V1B, const bhalf* WT,
                                            bhalf* VQT, bhalf* VKT, bhalf* VTB) {
  int bt = blockIdx.x, part = blockIdx.y;
  int tid = threadIdx.x, w = tid >> 6, l = tid & 63;
  const bhalf* A = V1B + (size_t)bt*16384;
  bf8v a8[8];
  #pragma unroll
  for (int kt = 0; kt < 8; ++kt) a8[kt] = ldfrag(A, w*16, kt*32, 256, l);
  if (part < 4) {
    const bhalf* Wb = WT + ((part < 2) ? W_ARMQ : W_ARMK);
    bhalf* o = ((part < 2) ? VQT : VKT) + (size_t)bt*8192;
    int nt0 = (part & 1) * 4;
    #pragma unroll
    for (int nn = 0; nn < 4; ++nn) {
      int nt = nt0 + nn;
      f4 acc = {0.f,0.f,0.f,0.f};
      #pragma unroll
      for (int kt = 0; kt < 8; ++kt)
        acc = mfma16(a8[kt], ldfrag(Wb, nt*16, kt*32, 256, l), acc);
      #pragma unroll
      for (int reg = 0; reg < 4; ++reg) {
        int p = w*16 + ((l>>4)<<2) + reg;
        int n = nt*16 + (l&15);
        o[(size_t)n*64 + p] = f2b(acc[reg]);   // transposed store
      }
    }
  } else {
    bhalf* ov = VTB + (size_t)bt*16384;
    int nt0 = (part - 4) * 4;
    #pragma unroll
    for (int nn = 0; nn < 4; ++nn) {
      int nt = nt0 + nn;
      f4 acc = {0.f,0.f,0.f,0.f};
      #pragma unroll
      for (int kt = 0; kt < 8; ++kt)
        acc = mfma16(a8[kt], ldfrag(WT + W_ARMV, nt*16, kt*32, 256, l), acc);
      #pragma unroll
      for (int reg = 0; reg < 4; ++reg) {
        int p = w*16 + ((l>>4)<<2) + reg;
        ov[(size_t)p*256 + nt*16 + (l&15)] = f2b(acc[reg]);
      }
    }
  }
}

// per (bt, part): vwt = (vt@epw)^T [256][64], nt quarters
__global__ void __launch_bounds__(256) kv1c(const bhalf* VTB, const bhalf* WT, bhalf* VWT) {
  int bt = blockIdx.x, part = blockIdx.y;
  int tid = threadIdx.x, w = tid >> 6, l = tid & 63;
  const bhalf* A = VTB + (size_t)bt*16384;
  bf8v a8[8];
  #pragma unroll
  for (int kt = 0; kt < 8; ++kt) a8[kt] = ldfrag(A, w*16, kt*32, 256, l);
  bhalf* ow = VWT + (size_t)bt*16384;
  int nt0 = part * 4;
  #pragma unroll
  for (int nn = 0; nn < 4; ++nn) {
    int nt = nt0 + nn;
    f4 acc = {0.f,0.f,0.f,0.f};
    #pragma unroll
    for (int kt = 0; kt < 8; ++kt)
      acc = mfma16(a8[kt], ldfrag(WT + W_EPW, nt*16, kt*32, 256, l), acc);
    #pragma unroll
    for (int reg = 0; reg < 4; ++reg) {
      int p = w*16 + ((l>>4)<<2) + reg;
      ow[(size_t)(nt*16 + (l&15))*64 + p] = f2b(acc[reg]);  // transposed
    }
  }
}

// ---------- stage 1: FAM attention + ARM input projections ----------
__global__ void __launch_bounds__(256) s1ker(const bhalf* PT, const bhalf* WT,
    const bhalf* K1B, const bhalf* VQT, const bhalf* VKT, const bhalf* VWT,
    bhalf* Q2B, bhalf* K2B, bhalf* W2T)
{
  __shared__ bhalf bufA[64*280];  // q1 staging, then w2 staging
  __shared__ bhalf bufP[64*72];
  __shared__ bhalf vqL[64*128];   // 16 KB, swizzled rows of 128 B
  __shared__ bhalf vkL[64*128];   // 16 KB
  int blk = blockIdx.x;           // bt*5 + u
  int bt = blk / 5;
  int tid = threadIdx.x, w = tid >> 6, l = tid & 63;
  const bhalf* Pt = PT + (size_t)blk*16384;
  // T14 issue-early: vq/vk tile loads (consumed after phase 1)
  float4 stg[8];
  {
    const char* gq = reinterpret_cast<const char*>(VQT + (size_t)bt*8192);
    const char* gk = reinterpret_cast<const char*>(VKT + (size_t)bt*8192);
    #pragma unroll
    for (int c = 0; c < 4; ++c) stg[c]   = *reinterpret_cast<const float4*>(gq + ((c*256 + tid) << 4));
    #pragma unroll
    for (int c = 0; c < 4; ++c) stg[4+c] = *reinterpret_cast<const float4*>(gk + ((c*256 + tid) << 4));
  }
  // phase 1: q1 (M=64, N=128, K=256) -> bufA bf16
  {
    bf8v a8[8];
    #pragma unroll
    for (int kt = 0; kt < 8; ++kt) a8[kt] = ldfrag(Pt, w*16, kt*32, 256, l);
    #pragma unroll
    for (int nt = 0; nt < 8; ++nt) {
      f4 acc = {0.f,0.f,0.f,0.f};
      #pragma unroll
      for (int kt = 0; kt < 8; ++kt)
        acc = mfma16(a8[kt], ldfrag(WT + W_FAMQ, nt*16, kt*32, 256, l), acc);
      #pragma unroll
      for (int reg = 0; reg < 4; ++reg)
        bufA[(w*16 + ((l>>4)<<2) + reg)*280 + nt*16 + (l&15)] = f2b(acc[reg]);
    }
  }
  // T14 write-late: swizzled LDS writes of vq/vk
  {
    char* lq = reinterpret_cast<char*>(vqL);
    char* lk = reinterpret_cast<char*>(vkL);
    #pragma unroll
    for (int c = 0; c < 4; ++c) {
      int x = (c*256 + tid) << 4;               // row = x>>7 (128 B rows)
      int xs = x ^ (((x >> 7) & 7) << 4);
      *reinterpret_cast<float4*>(lq + xs) = stg[c];
      *reinterpret_cast<float4*>(lk + xs) = stg[4+c];
    }
  }
  __syncthreads();
  // phase 2: scores vs k1 (own-wave rows from bufA), softmax in regs
  float sv[4][4];
  {
    const bhalf* K1 = K1B + (size_t)bt*8192;
    bf8v aq[4];
    #pragma unroll
    for (int kt = 0; kt < 4; ++kt) aq[kt] = ldfrag(bufA, w*16, kt*32, 280, l);
    #pragma unroll
    for (int nt = 0; nt < 4; ++nt) {
      f4 acc = {0.f,0.f,0.f,0.f};
      #pragma unroll
      for (int kt = 0; kt < 4; ++kt)
        acc = mfma16(aq[kt], ldfrag(K1, nt*16, kt*32, 128, l), acc);
      #pragma unroll
      for (int reg = 0; reg < 4; ++reg) sv[nt][reg] = acc[reg] * ATT_SCALE;
    }
  }
  if ((l & 15) > 0) { sv[3][0] = -1e30f; sv[3][1] = -1e30f; sv[3][2] = -1e30f; sv[3][3] = -1e30f; }
  regSoftmax(sv);
  #pragma unroll
  for (int nt = 0; nt < 4; ++nt)
    #pragma unroll
    for (int reg = 0; reg < 4; ++reg)
      bufP[(w*16 + ((l>>4)<<2) + reg)*72 + nt*16 + (l&15)] = f2b(sv[nt][reg]);
  __syncthreads();
  // phase 3: PVs
  bf8v ap0 = ldfrag(bufP, w*16, 0, 72, l);
  bf8v ap1 = ldfrag(bufP, w*16, 32, 72, l);
  {
    bhalf* q2 = Q2B + (size_t)blk*8192;
    #pragma unroll
    for (int nt = 0; nt < 8; ++nt) {
      f4 acc = {0.f,0.f,0.f,0.f};
      acc = mfma16(ap0, ldswz(vqL, nt*16 + (l & 15), ((l >> 4) << 4), 128), acc);
      acc = mfma16(ap1, ldswz(vqL, nt*16 + (l & 15), 64 + ((l >> 4) << 4), 128), acc);
      #pragma unroll
      for (int reg = 0; reg < 4; ++reg) {
        int p = w*16 + ((l>>4)<<2) + reg;
        q2[(size_t)p*128 + nt*16 + (l&15)] = (p < 49) ? f2b(acc[reg]) : (bhalf)0;
      }
    }
  }
  {
    bhalf* k2 = K2B + (size_t)blk*8192;
    #pragma unroll
    for (int nt = 0; nt < 8; ++nt) {
      f4 acc = {0.f,0.f,0.f,0.f};
      acc = mfma16(ap0, ldswz(vkL, nt*16 + (l & 15), ((l >> 4) << 4), 128), acc);
      acc = mfma16(ap1, ldswz(vkL, nt*16 + (l & 15), 64 + ((l >> 4) << 4), 128), acc);
      #pragma unroll
      for (int reg = 0; reg < 4; ++reg) {
        int p = w*16 + ((l>>4)<<2) + reg;
        k2[(size_t)p*128 + nt*16 + (l&15)] = (p < 49) ? f2b(acc[reg]) : (bhalf)0;
      }
    }
  }
  {
    const bhalf* vw = VWT + (size_t)bt*16384;
    #pragma unroll
    for (int nt = 0; nt < 16; ++nt) {
      f4 acc = {0.f,0.f,0.f,0.f};
      acc = mfma16(ap0, ldfrag(vw, nt*16, 0, 64, l), acc);
      acc = mfma16(ap1, ldfrag(vw, nt*16, 32, 64, l), acc);
      #pragma unroll
      for (int reg = 0; reg < 4; ++reg)
        bufA[(w*16 + ((l>>4)<<2) + reg)*280 + nt*16 + (l&15)] = f2b(acc[reg]);
    }
  }
  __syncthreads();
  // epilogue: w2t[c][r] coalesced (pairs packed into u32)
  unsigned* wt = reinterpret_cast<unsigned*>(W2T + (size_t)blk*16384);
  for (int it = 0; it < 32; ++it) {
    int o = it*256 + tid;       // 0..8191
    int c = o >> 5, ii = o & 31;
    int r0 = ii*2;
    unsigned lo = (r0   < 49) ? (unsigned)bufA[r0*280 + c]     : 0u;
    unsigned hi = (r0+1 < 49) ? (unsigned)bufA[(r0+1)*280 + c] : 0u;
    wt[o] = lo | (hi << 16);
  }
}

// ---------- stage 2: ARM attention + edge stats (round-3 measured-best variant) ----------
__global__ void __launch_bounds__(256) s2ker(const bhalf* Q2B, const bhalf* K2B, const bhalf* W2T,
    const float* epb, float* hws, float* gs1, float* gs2)
{
  __shared__ bhalf Kl[64*128];    // 16 KB, swizzled rows of 256 B
  __shared__ bhalf Vl[256*64];    // 32 KB, swizzled rows of 128 B
  __shared__ bhalf bufP[64*72];   // 9 KB, wave-private
  __shared__ float redH[4*256];   // 4 KB
  __shared__ float redS[8];
  int orig = blockIdx.x;
  int blk = (orig & 7) * 400 + (orig >> 3);   // 3200 = 8*400, bijective XCD grouping
  int e = blk % 25, bt = blk / 25, b = bt >> 4, t = bt & 15;
  int i = e / 5, j = e % 5;
  int tid = threadIdx.x, w = tid >> 6, l = tid & 63;
  const bhalf* K = K2B + (size_t)(bt*5 + i)*8192;
  const bhalf* V = W2T + (size_t)(bt*5 + i)*16384;
  const bhalf* Q = Q2B + (size_t)(bt*5 + j)*8192;
  // prefetch Q fragments (independent of LDS staging)
  bf8v aq[4];
  #pragma unroll
  for (int kt = 0; kt < 4; ++kt) aq[kt] = ldfrag(Q, w*16, kt*32, 128, l);
  // ---- stage K (16 KB) and V (32 KB): coalesced global read, swizzled LDS write ----
  {
    const char* gk = reinterpret_cast<const char*>(K);
    const char* gv = reinterpret_cast<const char*>(V);
    char* lk = reinterpret_cast<char*>(Kl);
    char* lv = reinterpret_cast<char*>(Vl);
    #pragma unroll
    for (int c = 0; c < 4; ++c) {
      int x = (c*256 + tid) << 4;                 // K: row = x>>8 (256 B rows)
      float4 val = *reinterpret_cast<const float4*>(gk + x);
      *reinterpret_cast<float4*>(lk + (x ^ (((x >> 8) & 7) << 4))) = val;
    }
    #pragma unroll
    for (int c = 0; c < 8; ++c) {
      int x = (c*256 + tid) << 4;                 // V: row = x>>7 (128 B rows)
      float4 val = *reinterpret_cast<const float4*>(gv + x);
      *reinterpret_cast<float4*>(lv + (x ^ (((x >> 7) & 7) << 4))) = val;
    }
  }
  __syncthreads();
  // QK^T from LDS + in-register softmax
  float sv[4][4];
  #pragma unroll
  for (int nt = 0; nt < 4; ++nt) {
    f4 acc = {0.f,0.f,0.f,0.f};
    #pragma unroll
    for (int kt = 0; kt < 4; ++kt)
      acc = mfma16(aq[kt], ldswz(Kl, nt*16 + (l & 15), kt*64 + ((l >> 4) << 4), 256), acc);
    #pragma unroll
    for (int reg = 0; reg < 4; ++reg) sv[nt][reg] = acc[reg] * ATT_SCALE;
  }
  if ((l & 15) > 0) { sv[3][0] = -1e30f; sv[3][1] = -1e30f; sv[3][2] = -1e30f; sv[3][3] = -1e30f; }
  regSoftmax(sv);
  // wave-private P transpose through LDS (no barrier needed)
  #pragma unroll
  for (int nt = 0; nt < 4; ++nt)
    #pragma unroll
    for (int reg = 0; reg < 4; ++reg)
      bufP[(w*16 + ((l>>4)<<2) + reg)*72 + nt*16 + (l&15)] = f2b(sv[nt][reg]);
  bf8v ap0 = ldfrag(bufP, w*16, 0, 72, l);
  bf8v ap1 = ldfrag(bufP, w*16, 32, 72, l);
  float sqa = 0.f;
  #pragma unroll
  for (int nt2 = 0; nt2 < 16; ++nt2) {
    f4 acc = {0.f,0.f,0.f,0.f};
    acc = mfma16(ap0, ldswz(Vl, nt2*16 + (l & 15), ((l >> 4) << 4), 128), acc);
    acc = mfma16(ap1, ldswz(Vl, nt2*16 + (l & 15), 64 + ((l >> 4) << 4), 128), acc);
    int c = nt2*16 + (l & 15);
    float bias = epb[c];
    float hw = 0.f;
    #pragma unroll
    for (int reg = 0; reg < 4; ++reg) {
      int p = w*16 + ((l>>4)<<2) + reg;
      if (p < 49) { float v = acc[reg] + bias; hw += v; sqa += v*v; }
    }
    hw += __shfl_xor(hw, 16);
    hw += __shfl_xor(hw, 32);
    if ((l >> 4) == 0) redH[w*256 + c] = hw;
  }
  __syncthreads();
  float hwtot = redH[tid] + redH[256+tid] + redH[512+tid] + redH[768+tid];
  hws[(((size_t)(b*25+e)*16) + t)*256 + tid] = hwtot;
  reduce2Atomic(hwtot, sqa, gs1 + e, gs2 + e, redS);
}

// ---------- fused GNN back-half (manual grid barrier, normal launch) ----------
// Replaces s2finker + 2x{gnnProj,g2a,g2b,g3a,g3b} + finker (12 dispatches) with
// ONE kernel: grid 640x256, gridSync between phases. g2b+g3a fused (block
// (b,i,t) owns edges i*5+j); xn survives in registers across the sync.
// __launch_bounds__(256,3) -> 3 blocks/CU schedulable -> 768 slots >= 640
// blocks all co-resident (no block retires before barrier 1).
struct GArgs {
  const float* hws; const float* gemg; const float* gemb;
  float* EDG; float* FV; float* ET;
  float* xA; float* xB; float* xU; float* xV; float* eE;
  const float* Wa[2]; const float* Wb[2]; const float* Wu[2]; const float* Wv[2]; const float* We[2];
  const float* bnvg[2]; const float* bnvb[2]; const float* bneg[2]; const float* bneb[2];
  const float* sc; const float* efw; const float* efb;
  float* st; unsigned* bar; float* out;
};

__global__ void __launch_bounds__(256, 3) gnnAll(GArgs a) {
  __shared__ float red[12];
  int blk = blockIdx.x, tid = threadIdx.x;
  // ---- P0: s2finker (EDG = gem-BN of hw-mean), 5 rows per block ----
  {
    const float* gs1 = a.st + 0;
    const float* gs2 = a.st + 25;
    constexpr float invCnt = 1.f/1605632.f;
    #pragma unroll
    for (int r = 0; r < 5; ++r) {
      int row = blk*5 + r;
      int e = (row >> 4) % 25;
      float m = gs1[e]*invCnt;
      float var = gs2[e]*invCnt - m*m;
      float rstd = rsqrtf(var + 1e-5f);
      size_t idx = (size_t)row*256 + tid;
      a.EDG[idx] = a.gemg[e]*((a.hws[idx]*(1.f/49.f) - m)*rstd) + a.gemb[e];
    }
  }
  gridSync(a.bar, 640);

  constexpr float inv32k = 1.f/32768.f;
  for (int L = 0; L < 2; ++L) {
    float* es1 = a.st + 64 + L*64;
    float* es2 = es1 + 25;
    float* ns1 = es1 + 50;
    float* ns2 = es1 + 55;
    // ---- P1: projections (720 virtual 8-row units over 640 blocks) ----
    for (int pass = 0; pass < 2; ++pass) {
      if (pass == 1 && blk >= 80) break;
      int vb = blk + pass*640;
      const float* src; const float* W; float* dst; int r0;
      if (vb < 320) {
        int m = vb / 80; r0 = (vb % 80) * 8;
        src = a.FV;
        W   = (m==0)?a.Wa[L]:(m==1)?a.Wb[L]:(m==2)?a.Wu[L]:a.Wv[L];
        dst = (m==0)?a.xA:(m==1)?a.xB:(m==2)?a.xU:a.xV;
      } else { r0 = (vb - 320) * 8; src = a.EDG; W = a.We[L]; dst = a.eE; }
      float acc[8];
      #pragma unroll
      for (int r = 0; r < 8; ++r) acc[r] = 0.f;
      for (int c = 0; c < 256; c += 4) {
        float w0 = W[(size_t)(c+0)*256 + tid];
        float w1 = W[(size_t)(c+1)*256 + tid];
        float w2 = W[(size_t)(c+2)*256 + tid];
        float w3 = W[(size_t)(c+3)*256 + tid];
        #pragma unroll
        for (int r = 0; r < 8; ++r) {
          float4 av = *reinterpret_cast<const float4*>(&src[(size_t)(r0+r)*256 + c]);
          acc[r] += av.x*w0 + av.y*w1 + av.z*w2 + av.w*w3;
        }
      }
      #pragma unroll
      for (int r = 0; r < 8; ++r) dst[(size_t)(r0+r)*256 + tid] = acc[r];
    }
    gridSync(a.bar, 640);
    // ---- P2: g2a (edge pre-activation + stats), 5 rows per block ----
    for (int r = 0; r < 5; ++r) {
      int row = blk*5 + r;               // = old g2a blk
      int bq = row / 400, e = (row >> 4) % 25, t = row & 15;
      int i = e / 5, j = e % 5;
      size_t ni = ((size_t)(bq*5+i)*16 + t)*256 + tid;
      size_t nj = ((size_t)(bq*5+j)*16 + t)*256 + tid;
      size_t ee = (size_t)row*256 + tid;
      float v = a.xA[ni] + a.xB[nj] + a.eE[ee];
      a.ET[ee] = v;
      reduce2Atomic(v, v*v, es1 + e, es2 + e, red);
    }
    gridSync(a.bar, 640);
    // ---- P3: g2b+g3a fused; xn retained in register ----
    int b = blk / 80, i = (blk >> 4) % 5, t = blk & 15;
    float xn;
    {
      float ssum = 0.f, exv[5], xvv[5];
      #pragma unroll
      for (int j = 0; j < 5; ++j) {
        int e = i*5 + j;
        size_t ee = ((size_t)(b*25 + e)*16 + t)*256 + tid;
        float m = es1[e]*inv32k;
        float var = es2[e]*inv32k - m*m;
        float rstd = rsqrtf(var + 1e-5f);
        float v = a.bneg[L][e]*((a.ET[ee]-m)*rstd) + a.bneb[L][e];
        if (v != v) v = 0.f;
        float edg = a.EDG[ee] + fmaxf(v, 0.f);
        a.EDG[ee] = edg;
        float sg = 1.f/(1.f + __expf(-edg));
        exv[j] = __expf(sg);
        ssum += exv[j];
        xvv[j] = a.xV[((size_t)(b*5+j)*16 + t)*256 + tid];
      }
      float agg = 0.f;
      #pragma unroll
      for (int j = 0; j < 5; ++j) agg += exv[j]*xvv[j];
      agg *= 0.2f/ssum;
      xn = a.xU[(size_t)blk*256 + tid] + agg;
      reduce2Atomic(xn, xn*xn, ns1 + i, ns2 + i, red);
    }
    gridSync(a.bar, 640);
    // ---- P4: g3b (node BN + residual relu) ----
    {
      float m = ns1[i]*inv32k;
      float var = ns2[i]*inv32k - m*m;
      float rstd = rsqrtf(var + 1e-5f);
      float v = a.bnvg[L][i]*((xn-m)*rstd) + a.bnvb[L][i];
      if (L == 0 && v != v) v = 0.f;
      size_t ni = (size_t)blk*256 + tid;
      a.FV[ni] = fmaxf(a.FV[ni] + v, 0.f);
    }
    gridSync(a.bar, 640);
  }
  // ---- P5: finker (3840 virtual units, 6 per block) ----
  for (int k = 0; k < 6; ++k) {
    int vb = blk + k*640;
    if (vb < 640) {
      int nn = (vb >> 4) % 5;
      float x = a.FV[(size_t)vb*256 + tid];
      float s = fmaxf(a.sc[nn*256 + tid], 0.f);
      float xx = x*x, ss = s*s, xs = x*s;
      #pragma unroll
      for (int off = 32; off; off >>= 1) {
        xx += __shfl_down(xx, off); ss += __shfl_down(ss, off); xs += __shfl_down(xs, off);
      }
      if ((tid & 63) == 0) { int w = tid >> 6; red[w*3] = xx; red[w*3+1] = ss; red[w*3+2] = xs; }
      __syncthreads();
      if (tid == 0) {
        float sxx = red[0]+red[3]+red[6]+red[9];
        float sss = red[1]+red[4]+red[7]+red[10];
        float sxs = red[2]+red[5]+red[8]+red[11];
        float nx = fmaxf(sqrtf(sxx), 1e-12f);
        float ns = fmaxf(sqrtf(sss), 1e-12f);
        a.out[vb] = sxs / (nx * ns);
      }
      __syncthreads();
    } else {
      int eb = vb - 640;
      float v = a.EDG[(size_t)eb*256 + tid] * a.efw[tid];
      #pragma unroll
      for (int off = 32; off; off >>= 1) v += __shfl_down(v, off);
      if ((tid & 63) == 0) red[tid >> 6] = v;
      __syncthreads();
      if (tid == 0) a.out[640 + eb] = red[0]+red[1]+red[2]+red[3] + a.efb[0];
      __syncthreads();
    }
  }
}

// ---------- host ----------

extern "C" void kernel_launch(void* const* d_in, const int* in_sizes, int n_in,
                              void* d_out, int out_size, void* d_ws, size_t ws_size,
                              hipStream_t stream) {
  (void)in_sizes; (void)n_in; (void)out_size; (void)ws_size;
  const float* af    = (const float*)d_in[0];
  const float* ef    = (const float*)d_in[1];
  const float* gfm   = (const float*)d_in[2];
  const float* attf  = (const float*)d_in[3];
  const float* sfm   = (const float*)d_in[4];
  const float* fam_q = (const float*)d_in[5];
  const float* fam_k = (const float*)d_in[6];
  const float* fam_v = (const float*)d_in[7];
  const float* arm_q = (const float*)d_in[8];
  const float* arm_k = (const float*)d_in[9];
  const float* arm_v = (const float*)d_in[10];
  const float* epw   = (const float*)d_in[11];
  const float* epb   = (const float*)d_in[12];
  const float* gemg  = (const float*)d_in[13];
  const float* gemb  = (const float*)d_in[14];
  const float* Us[2]   = {(const float*)d_in[15], (const float*)d_in[20]};
  const float* Vs[2]   = {(const float*)d_in[16], (const float*)d_in[21]};
  const float* As[2]   = {(const float*)d_in[17], (const float*)d_in[22]};
  const float* Bs[2]   = {(const float*)d_in[18], (const float*)d_in[23]};
  const float* Es[2]   = {(const float*)d_in[19], (const float*)d_in[24]};
  const float* bnvg[2] = {(const float*)d_in[25], (const float*)d_in[29]};
  const float* bnvb[2] = {(const float*)d_in[26], (const float*)d_in[30]};
  const float* bneg[2] = {(const float*)d_in[27], (const float*)d_in[31]};
  const float* bneb[2] = {(const float*)d_in[28], (const float*)d_in[32]};
  const float* scp  = (const float*)d_in[33];
  const float* efw  = (const float*)d_in[34];
  const float* efb  = (const float*)d_in[35];

  char* ws = (char*)d_ws;
  bhalf* PT  = (bhalf*)(ws + O_PT);
  bhalf* WTS = (bhalf*)(ws + O_WTS);
  bhalf* K1B = (bhalf*)(ws + O_K1B);
  bhalf* V1B = (bhalf*)(ws + O_V1B);
  bhalf* VQT = (bhalf*)(ws + O_VQT);
  bhalf* VKT = (bhalf*)(ws + O_VKT);
  bhalf* VTB = (bhalf*)(ws + O_VTB);
  bhalf* VWT = (bhalf*)(ws + O_VWT);
  bhalf* Q2B = (bhalf*)(ws + O_Q2B);
  bhalf* K2B = (bhalf*)(ws + O_K2B);
  bhalf* W2T = (bhalf*)(ws + O_W2T);
  float* FV  = (float*)(ws + O_FV);
  float* HWS = (float*)(ws + O_HWS);
  float* EDG = (float*)(ws + O_EDG);
  float* st  = (float*)(ws + O_ST);
  float* XA  = (float*)(ws + O_XA);
  float* XB  = (float*)(ws + O_XB);
  float* XU  = (float*)(ws + O_XU);
  float* XV  = (float*)(ws + O_XV);
  float* EE  = (float*)(ws + O_EE);
  float* ET  = (float*)(ws + O_ET);

  hipMemsetAsync(st, 0, 256*sizeof(float), stream);

  wprep<<<1280, TPB, 0, stream>>>(fam_q, fam_k, fam_v, arm_q, arm_k, arm_v, epw, WTS);
  modprep<<<640, TPB, 0, stream>>>(af, ef, gfm, attf, sfm, PT, FV);
  kv1a<<<dim3(128, 6), TPB, 0, stream>>>(PT, WTS, K1B, V1B);
  kv1b<<<dim3(128, 8), TPB, 0, stream>>>(V1B, WTS, VQT, VKT, VTB);
  kv1c<<<dim3(128, 4), TPB, 0, stream>>>(VTB, WTS, VWT);
  s1ker<<<640, TPB, 0, stream>>>(PT, WTS, K1B, VQT, VKT, VWT, Q2B, K2B, W2T);
  s2ker<<<3200, TPB, 0, stream>>>(Q2B, K2B, W2T, epb, HWS, st+0, st+25);

  GArgs ga;
  ga.hws = HWS; ga.gemg = gemg; ga.gemb = gemb;
  ga.EDG = EDG; ga.FV = FV; ga.ET = ET;
  ga.xA = XA; ga.xB = XB; ga.xU = XU; ga.xV = XV; ga.eE = EE;
  for (int L = 0; L < 2; ++L) {
    ga.Wa[L] = As[L]; ga.Wb[L] = Bs[L]; ga.Wu[L] = Us[L]; ga.Wv[L] = Vs[L]; ga.We[L] = Es[L];
    ga.bnvg[L] = bnvg[L]; ga.bnvb[L] = bnvb[L]; ga.bneg[L] = bneg[L]; ga.bneb[L] = bneb[L];
  }
  ga.sc = scp; ga.efw = efw; ga.efb = efb;
  ga.st = st; ga.bar = (unsigned*)(st + 192); ga.out = (float*)d_out;
  gnnAll<<<640, TPB, 0, stream>>>(ga);
}

// Round 7
// 391.624 us; speedup vs baseline: 5.6850x; 5.6850x over previous
//
#include <hip/hip_runtime.h>

#define DEV __device__ __forceinline__

typedef unsigned short bhalf;
typedef __attribute__((ext_vector_type(8))) short bf8v;
typedef __attribute__((ext_vector_type(4))) float f4;

namespace {
constexpr int TPB = 256;
constexpr float ATT_SCALE = 0.08838834764831845f; // 1/sqrt(128)

// ---- workspace byte offsets ----
constexpr size_t O_PT  = 0;          // bf16 [640][64][256]  modalities, zero-pad rows
constexpr size_t O_WTS = 20971520;   // bf16 transposed weights (see W_* below)
constexpr size_t O_K1B = 21626880;   // bf16 [128][64][128]
constexpr size_t O_V1B = 23724032;   // bf16 [128][64][256]
constexpr size_t O_VQT = 27918336;   // bf16 [128][128][64]  (v1@arm_q)^T
constexpr size_t O_VKT = 30015488;   // bf16 [128][128][64]
constexpr size_t O_VTB = 32112640;   // bf16 [128][64][256]  v1@arm_v
constexpr size_t O_VWT = 36306944;   // bf16 [128][256][64]  (vt@epw)^T
constexpr size_t O_Q2B = 40501248;   // bf16 [640][64][128]
constexpr size_t O_K2B = 50987008;   // bf16 [640][64][128]
constexpr size_t O_W2T = 61472768;   // bf16 [640][256][64]
constexpr size_t O_FV  = 82444288;   // f32  [640][256]  node features X
constexpr size_t O_HWS = 83099648;   // f32  [3200][256]
constexpr size_t O_EDG = 86376448;   // f32  [3200][256]
constexpr size_t O_ST  = 89653248;   // f32  [256] stats
constexpr size_t O_XA  = 89654272;
constexpr size_t O_XB  = 90309632;
constexpr size_t O_XU  = 90964992;
constexpr size_t O_XV  = 91620352;
constexpr size_t O_EE  = 92275712;
constexpr size_t O_ET  = 95552512;
constexpr size_t O_XN  = 98829312;

// WTS element offsets (bf16 elems), all stored as Wt[n][k=256]
constexpr size_t W_FAMQ = 0, W_FAMK = 32768, W_ARMQ = 65536, W_ARMK = 98304,
                 W_FAMV = 131072, W_ARMV = 196608, W_EPW = 262144;
} // namespace

// ---------- helpers ----------

DEV bhalf f2b(float f) {
  unsigned u = __float_as_uint(f);
  return (bhalf)((u + 0x7FFFu + ((u >> 16) & 1u)) >> 16);
}

DEV f4 mfma16(bf8v a, bf8v b, f4 c) {
  return __builtin_amdgcn_mfma_f32_16x16x32_bf16(a, b, c, 0, 0, 0);
}

// fragment load: lane l reads row (r0 + (l&15)), 8 contiguous k at k0 + (l>>4)*8
DEV bf8v ldfrag(const bhalf* base, int r0, int k0, int S, int l) {
  return *reinterpret_cast<const bf8v*>(base + (size_t)(r0 + (l & 15)) * S + k0 + ((l >> 4) << 3));
}

// swizzled LDS fragment load: byte = row*stride + koffB, XOR'd with ((row&7)<<4)
DEV bf8v ldswz(const bhalf* base, int row, int koffB, int strideB) {
  int byte = row * strideB + koffB;
  byte ^= ((row & 7) << 4);
  return *reinterpret_cast<const bf8v*>(reinterpret_cast<const char*>(base) + byte);
}

// in-register row softmax: sv[nt][reg], row per reg spans cols nt*16+(l&15) across 16 lanes
DEV void regSoftmax(float sv[4][4]) {
  #pragma unroll
  for (int reg = 0; reg < 4; ++reg) {
    float m = fmaxf(fmaxf(sv[0][reg], sv[1][reg]), fmaxf(sv[2][reg], sv[3][reg]));
    #pragma unroll
    for (int off = 1; off <= 8; off <<= 1) m = fmaxf(m, __shfl_xor(m, off));
    float s = 0.f;
    #pragma unroll
    for (int nt = 0; nt < 4; ++nt) { float e = __expf(sv[nt][reg] - m); sv[nt][reg] = e; s += e; }
    #pragma unroll
    for (int off = 1; off <= 8; off <<= 1) s += __shfl_xor(s, off);
    float inv = 1.f / s;
    #pragma unroll
    for (int nt = 0; nt < 4; ++nt) sv[nt][reg] *= inv;
  }
}

DEV void reduce2Atomic(float a, float b, float* ga, float* gb, float* red) {
  #pragma unroll
  for (int off = 32; off; off >>= 1) { a += __shfl_down(a, off); b += __shfl_down(b, off); }
  if ((threadIdx.x & 63) == 0) { int w = threadIdx.x >> 6; red[w*2] = a; red[w*2+1] = b; }
  __syncthreads();
  if (threadIdx.x == 0) {
    atomicAdd(ga, red[0]+red[2]+red[4]+red[6]);
    atomicAdd(gb, red[1]+red[3]+red[5]+red[7]);
  }
  __syncthreads();
}

// ---------- prep kernels ----------

// transpose 7 weight matrices to bf16 Wt[n][256]
__global__ void __launch_bounds__(256) wprep(const float* fq, const float* fk, const float* fv,
                                             const float* aq, const float* ak, const float* av,
                                             const float* ep, bhalf* WT) {
  int blk = blockIdx.x, tid = threadIdx.x;
  const float* src; bhalf* dst; int N, n;
  if (blk < 512) {
    int m = blk >> 7; n = blk & 127; N = 128;
    src = (m==0)?fq:(m==1)?fk:(m==2)?aq:ak;
    dst = WT + (size_t)m*32768;
  } else {
    int r = blk - 512; int m = r >> 8; n = r & 255; N = 256;
    src = (m==0)?fv:(m==1)?av:ep;
    dst = WT + 131072 + (size_t)m*65536;
  }
  dst[(size_t)n*256 + tid] = f2b(src[(size_t)tid*N + n]);
}

// per (bt,u): transpose modality slice to bf16 Pt[64][256] (zero-pad rows) + fv means
__global__ void __launch_bounds__(256) modprep(const float* af, const float* ef, const float* gf,
                                               const float* attf, const float* sf,
                                               bhalf* PT, float* FV) {
  __shared__ float lb[49*260];
  int blk = blockIdx.x, tid = threadIdx.x;
  int u = blk % 5, bt = blk / 5, b = bt >> 4, t = bt & 15;
  const float* src = (u==0)?af:(u==1)?ef:(u==2)?gf:(u==3)?attf:sf;
  src += ((size_t)b*256*16 + t)*49;
  for (int o = tid; o < 49*256; o += TPB) {
    int c = o / 49, p = o % 49;
    lb[p*260 + c] = src[(size_t)c*784 + p];
  }
  __syncthreads();
  bhalf* pt = PT + (size_t)blk*16384;
  for (int p = 0; p < 64; ++p)
    pt[p*256 + tid] = (p < 49) ? f2b(lb[p*260 + tid]) : (bhalf)0;
  float s = 0.f;
  for (int p = 0; p < 49; ++p) s += lb[p*260 + tid];
  FV[(((size_t)(b*5+u)*16) + t)*256 + tid] = s * (1.f/49.f);
}

// ---------- MFMA GEMM chain (fine nt-split over blockIdx.y for latency hiding) ----------

// per (bt, part): parts 0-1: k1 = Paf@fam_k nt quarters; parts 2-5: v1 = Paf@fam_v quarters
__global__ void __launch_bounds__(256) kv1a(const bhalf* PT, const bhalf* WT,
                                            bhalf* K1B, bhalf* V1B) {
  int bt = blockIdx.x, part = blockIdx.y;
  int tid = threadIdx.x, w = tid >> 6, l = tid & 63;
  const bhalf* A = PT + (size_t)bt*5*16384; // u=0 (af)
  bf8v a8[8];
  #pragma unroll
  for (int kt = 0; kt < 8; ++kt) a8[kt] = ldfrag(A, w*16, kt*32, 256, l);
  const bhalf* Wb; bhalf* dst; int nt0, S;
  if (part < 2) { Wb = WT + W_FAMK; dst = K1B + (size_t)bt*8192;  nt0 = part*4;     S = 128; }
  else          { Wb = WT + W_FAMV; dst = V1B + (size_t)bt*16384; nt0 = (part-2)*4; S = 256; }
  #pragma unroll
  for (int nn = 0; nn < 4; ++nn) {
    int nt = nt0 + nn;
    f4 acc = {0.f,0.f,0.f,0.f};
    #pragma unroll
    for (int kt = 0; kt < 8; ++kt)
      acc = mfma16(a8[kt], ldfrag(Wb, nt*16, kt*32, 256, l), acc);
    #pragma unroll
    for (int reg = 0; reg < 4; ++reg) {
      int p = w*16 + ((l>>4)<<2) + reg;
      dst[(size_t)p*S + nt*16 + (l&15)] = f2b(acc[reg]);
    }
  }
}

// per (bt, part): parts 0-1: vqt; 2-3: vkt (transposed [128][64]); 4-7: vtb quarters
__global__ void __launch_bounds__(256) kv1b(const bhalf* V1B, const bhalf* WT,
                                            bhalf* VQT, bhalf* VKT, bhalf* VTB) {
  int bt = blockIdx.x, part = blockIdx.y;
  int tid = threadIdx.x, w = tid >> 6, l = tid & 63;
  const bhalf* A = V1B + (size_t)bt*16384;
  bf8v a8[8];
  #pragma unroll
  for (int kt = 0; kt < 8; ++kt) a8[kt] = ldfrag(A, w*16, kt*32, 256, l);
  if (part < 4) {
    const bhalf* Wb = WT + ((part < 2) ? W_ARMQ : W_ARMK);
    bhalf* o = ((part < 2) ? VQT : VKT) + (size_t)bt*8192;
    int nt0 = (part & 1) * 4;
    #pragma unroll
    for (int nn = 0; nn < 4; ++nn) {
      int nt = nt0 + nn;
      f4 acc = {0.f,0.f,0.f,0.f};
      #pragma unroll
      for (int kt = 0; kt < 8; ++kt)
        acc = mfma16(a8[kt], ldfrag(Wb, nt*16, kt*32, 256, l), acc);
      #pragma unroll
      for (int reg = 0; reg < 4; ++reg) {
        int p = w*16 + ((l>>4)<<2) + reg;
        int n = nt*16 + (l&15);
        o[(size_t)n*64 + p] = f2b(acc[reg]);   // transposed store
      }
    }
  } else {
    bhalf* ov = VTB + (size_t)bt*16384;
    int nt0 = (part - 4) * 4;
    #pragma unroll
    for (int nn = 0; nn < 4; ++nn) {
      int nt = nt0 + nn;
      f4 acc = {0.f,0.f,0.f,0.f};
      #pragma unroll
      for (int kt = 0; kt < 8; ++kt)
        acc = mfma16(a8[kt], ldfrag(WT + W_ARMV, nt*16, kt*32, 256, l), acc);
      #pragma unroll
      for (int reg = 0; reg < 4; ++reg) {
        int p = w*16 + ((l>>4)<<2) + reg;
        ov[(size_t)p*256 + nt*16 + (l&15)] = f2b(acc[reg]);
      }
    }
  }
}

// per (bt, part): vwt = (vt@epw)^T [256][64], nt quarters
__global__ void __launch_bounds__(256) kv1c(const bhalf* VTB, const bhalf* WT, bhalf* VWT) {
  int bt = blockIdx.x, part = blockIdx.y;
  int tid = threadIdx.x, w = tid >> 6, l = tid & 63;
  const bhalf* A = VTB + (size_t)bt*16384;
  bf8v a8[8];
  #pragma unroll
  for (int kt = 0; kt < 8; ++kt) a8[kt] = ldfrag(A, w*16, kt*32, 256, l);
  bhalf* ow = VWT + (size_t)bt*16384;
  int nt0 = part * 4;
  #pragma unroll
  for (int nn = 0; nn < 4; ++nn) {
    int nt = nt0 + nn;
    f4 acc = {0.f,0.f,0.f,0.f};
    #pragma unroll
    for (int kt = 0; kt < 8; ++kt)
      acc = mfma16(a8[kt], ldfrag(WT + W_EPW, nt*16, kt*32, 256, l), acc);
    #pragma unroll
    for (int reg = 0; reg < 4; ++reg) {
      int p = w*16 + ((l>>4)<<2) + reg;
      ow[(size_t)(nt*16 + (l&15))*64 + p] = f2b(acc[reg]);  // transposed
    }
  }
}

// ---------- stage 1: FAM attention + ARM input projections ----------
__global__ void __launch_bounds__(256) s1ker(const bhalf* PT, const bhalf* WT,
    const bhalf* K1B, const bhalf* VQT, const bhalf* VKT, const bhalf* VWT,
    bhalf* Q2B, bhalf* K2B, bhalf* W2T)
{
  __shared__ bhalf bufA[64*280];  // q1 staging, then w2 staging
  __shared__ bhalf bufP[64*72];
  __shared__ bhalf vqL[64*128];   // 16 KB, swizzled rows of 128 B
  __shared__ bhalf vkL[64*128];   // 16 KB
  int blk = blockIdx.x;           // bt*5 + u
  int bt = blk / 5;
  int tid = threadIdx.x, w = tid >> 6, l = tid & 63;
  const bhalf* Pt = PT + (size_t)blk*16384;
  // T14 issue-early: vq/vk tile loads (consumed after phase 1)
  float4 stg[8];
  {
    const char* gq = reinterpret_cast<const char*>(VQT + (size_t)bt*8192);
    const char* gk = reinterpret_cast<const char*>(VKT + (size_t)bt*8192);
    #pragma unroll
    for (int c = 0; c < 4; ++c) stg[c]   = *reinterpret_cast<const float4*>(gq + ((c*256 + tid) << 4));
    #pragma unroll
    for (int c = 0; c < 4; ++c) stg[4+c] = *reinterpret_cast<const float4*>(gk + ((c*256 + tid) << 4));
  }
  // phase 1: q1 (M=64, N=128, K=256) -> bufA bf16
  {
    bf8v a8[8];
    #pragma unroll
    for (int kt = 0; kt < 8; ++kt) a8[kt] = ldfrag(Pt, w*16, kt*32, 256, l);
    #pragma unroll
    for (int nt = 0; nt < 8; ++nt) {
      f4 acc = {0.f,0.f,0.f,0.f};
      #pragma unroll
      for (int kt = 0; kt < 8; ++kt)
        acc = mfma16(a8[kt], ldfrag(WT + W_FAMQ, nt*16, kt*32, 256, l), acc);
      #pragma unroll
      for (int reg = 0; reg < 4; ++reg)
        bufA[(w*16 + ((l>>4)<<2) + reg)*280 + nt*16 + (l&15)] = f2b(acc[reg]);
    }
  }
  // T14 write-late: swizzled LDS writes of vq/vk
  {
    char* lq = reinterpret_cast<char*>(vqL);
    char* lk = reinterpret_cast<char*>(vkL);
    #pragma unroll
    for (int c = 0; c < 4; ++c) {
      int x = (c*256 + tid) << 4;               // row = x>>7 (128 B rows)
      int xs = x ^ (((x >> 7) & 7) << 4);
      *reinterpret_cast<float4*>(lq + xs) = stg[c];
      *reinterpret_cast<float4*>(lk + xs) = stg[4+c];
    }
  }
  __syncthreads();
  // phase 2: scores vs k1 (own-wave rows from bufA), softmax in regs
  float sv[4][4];
  {
    const bhalf* K1 = K1B + (size_t)bt*8192;
    bf8v aq[4];
    #pragma unroll
    for (int kt = 0; kt < 4; ++kt) aq[kt] = ldfrag(bufA, w*16, kt*32, 280, l);
    #pragma unroll
    for (int nt = 0; nt < 4; ++nt) {
      f4 acc = {0.f,0.f,0.f,0.f};
      #pragma unroll
      for (int kt = 0; kt < 4; ++kt)
        acc = mfma16(aq[kt], ldfrag(K1, nt*16, kt*32, 128, l), acc);
      #pragma unroll
      for (int reg = 0; reg < 4; ++reg) sv[nt][reg] = acc[reg] * ATT_SCALE;
    }
  }
  if ((l & 15) > 0) { sv[3][0] = -1e30f; sv[3][1] = -1e30f; sv[3][2] = -1e30f; sv[3][3] = -1e30f; }
  regSoftmax(sv);
  #pragma unroll
  for (int nt = 0; nt < 4; ++nt)
    #pragma unroll
    for (int reg = 0; reg < 4; ++reg)
      bufP[(w*16 + ((l>>4)<<2) + reg)*72 + nt*16 + (l&15)] = f2b(sv[nt][reg]);
  __syncthreads();
  // phase 3: PVs
  bf8v ap0 = ldfrag(bufP, w*16, 0, 72, l);
  bf8v ap1 = ldfrag(bufP, w*16, 32, 72, l);
  {
    bhalf* q2 = Q2B + (size_t)blk*8192;
    #pragma unroll
    for (int nt = 0; nt < 8; ++nt) {
      f4 acc = {0.f,0.f,0.f,0.f};
      acc = mfma16(ap0, ldswz(vqL, nt*16 + (l & 15), ((l >> 4) << 4), 128), acc);
      acc = mfma16(ap1, ldswz(vqL, nt*16 + (l & 15), 64 + ((l >> 4) << 4), 128), acc);
      #pragma unroll
      for (int reg = 0; reg < 4; ++reg) {
        int p = w*16 + ((l>>4)<<2) + reg;
        q2[(size_t)p*128 + nt*16 + (l&15)] = (p < 49) ? f2b(acc[reg]) : (bhalf)0;
      }
    }
  }
  {
    bhalf* k2 = K2B + (size_t)blk*8192;
    #pragma unroll
    for (int nt = 0; nt < 8; ++nt) {
      f4 acc = {0.f,0.f,0.f,0.f};
      acc = mfma16(ap0, ldswz(vkL, nt*16 + (l & 15), ((l >> 4) << 4), 128), acc);
      acc = mfma16(ap1, ldswz(vkL, nt*16 + (l & 15), 64 + ((l >> 4) << 4), 128), acc);
      #pragma unroll
      for (int reg = 0; reg < 4; ++reg) {
        int p = w*16 + ((l>>4)<<2) + reg;
        k2[(size_t)p*128 + nt*16 + (l&15)] = (p < 49) ? f2b(acc[reg]) : (bhalf)0;
      }
    }
  }
  {
    const bhalf* vw = VWT + (size_t)bt*16384;
    #pragma unroll
    for (int nt = 0; nt < 16; ++nt) {
      f4 acc = {0.f,0.f,0.f,0.f};
      acc = mfma16(ap0, ldfrag(vw, nt*16, 0, 64, l), acc);
      acc = mfma16(ap1, ldfrag(vw, nt*16, 32, 64, l), acc);
      #pragma unroll
      for (int reg = 0; reg < 4; ++reg)
        bufA[(w*16 + ((l>>4)<<2) + reg)*280 + nt*16 + (l&15)] = f2b(acc[reg]);
    }
  }
  __syncthreads();
  // epilogue: w2t[c][r] coalesced (pairs packed into u32)
  unsigned* wt = reinterpret_cast<unsigned*>(W2T + (size_t)blk*16384);
  for (int it = 0; it < 32; ++it) {
    int o = it*256 + tid;       // 0..8191
    int c = o >> 5, ii = o & 31;
    int r0 = ii*2;
    unsigned lo = (r0   < 49) ? (unsigned)bufA[r0*280 + c]     : 0u;
    unsigned hi = (r0+1 < 49) ? (unsigned)bufA[(r0+1)*280 + c] : 0u;
    wt[o] = lo | (hi << 16);
  }
}

// ---------- stage 2: ARM attention + edge stats (round-3 measured-best variant) ----------
__global__ void __launch_bounds__(256) s2ker(const bhalf* Q2B, const bhalf* K2B, const bhalf* W2T,
    const float* epb, float* hws, float* gs1, float* gs2)
{
  __shared__ bhalf Kl[64*128];    // 16 KB, swizzled rows of 256 B
  __shared__ bhalf Vl[256*64];    // 32 KB, swizzled rows of 128 B
  __shared__ bhalf bufP[64*72];   // 9 KB, wave-private
  __shared__ float redH[4*256];   // 4 KB
  __shared__ float redS[8];
  int orig = blockIdx.x;
  int blk = (orig & 7) * 400 + (orig >> 3);   // 3200 = 8*400, bijective XCD grouping
  int e = blk % 25, bt = blk / 25, b = bt >> 4, t = bt & 15;
  int i = e / 5, j = e % 5;
  int tid = threadIdx.x, w = tid >> 6, l = tid & 63;
  const bhalf* K = K2B + (size_t)(bt*5 + i)*8192;
  const bhalf* V = W2T + (size_t)(bt*5 + i)*16384;
  const bhalf* Q = Q2B + (size_t)(bt*5 + j)*8192;
  // prefetch Q fragments (independent of LDS staging)
  bf8v aq[4];
  #pragma unroll
  for (int kt = 0; kt < 4; ++kt) aq[kt] = ldfrag(Q, w*16, kt*32, 128, l);
  // ---- stage K (16 KB) and V (32 KB): coalesced global read, swizzled LDS write ----
  {
    const char* gk = reinterpret_cast<const char*>(K);
    const char* gv = reinterpret_cast<const char*>(V);
    char* lk = reinterpret_cast<char*>(Kl);
    char* lv = reinterpret_cast<char*>(Vl);
    #pragma unroll
    for (int c = 0; c < 4; ++c) {
      int x = (c*256 + tid) << 4;                 // K: row = x>>8 (256 B rows)
      float4 val = *reinterpret_cast<const float4*>(gk + x);
      *reinterpret_cast<float4*>(lk + (x ^ (((x >> 8) & 7) << 4))) = val;
    }
    #pragma unroll
    for (int c = 0; c < 8; ++c) {
      int x = (c*256 + tid) << 4;                 // V: row = x>>7 (128 B rows)
      float4 val = *reinterpret_cast<const float4*>(gv + x);
      *reinterpret_cast<float4*>(lv + (x ^ (((x >> 7) & 7) << 4))) = val;
    }
  }
  __syncthreads();
  // QK^T from LDS + in-register softmax
  float sv[4][4];
  #pragma unroll
  for (int nt = 0; nt < 4; ++nt) {
    f4 acc = {0.f,0.f,0.f,0.f};
    #pragma unroll
    for (int kt = 0; kt < 4; ++kt)
      acc = mfma16(aq[kt], ldswz(Kl, nt*16 + (l & 15), kt*64 + ((l >> 4) << 4), 256), acc);
    #pragma unroll
    for (int reg = 0; reg < 4; ++reg) sv[nt][reg] = acc[reg] * ATT_SCALE;
  }
  if ((l & 15) > 0) { sv[3][0] = -1e30f; sv[3][1] = -1e30f; sv[3][2] = -1e30f; sv[3][3] = -1e30f; }
  regSoftmax(sv);
  // wave-private P transpose through LDS (no barrier needed)
  #pragma unroll
  for (int nt = 0; nt < 4; ++nt)
    #pragma unroll
    for (int reg = 0; reg < 4; ++reg)
      bufP[(w*16 + ((l>>4)<<2) + reg)*72 + nt*16 + (l&15)] = f2b(sv[nt][reg]);
  bf8v ap0 = ldfrag(bufP, w*16, 0, 72, l);
  bf8v ap1 = ldfrag(bufP, w*16, 32, 72, l);
  float sqa = 0.f;
  #pragma unroll
  for (int nt2 = 0; nt2 < 16; ++nt2) {
    f4 acc = {0.f,0.f,0.f,0.f};
    acc = mfma16(ap0, ldswz(Vl, nt2*16 + (l & 15), ((l >> 4) << 4), 128), acc);
    acc = mfma16(ap1, ldswz(Vl, nt2*16 + (l & 15), 64 + ((l >> 4) << 4), 128), acc);
    int c = nt2*16 + (l & 15);
    float bias = epb[c];
    float hw = 0.f;
    #pragma unroll
    for (int reg = 0; reg < 4; ++reg) {
      int p = w*16 + ((l>>4)<<2) + reg;
      if (p < 49) { float v = acc[reg] + bias; hw += v; sqa += v*v; }
    }
    hw += __shfl_xor(hw, 16);
    hw += __shfl_xor(hw, 32);
    if ((l >> 4) == 0) redH[w*256 + c] = hw;
  }
  __syncthreads();
  float hwtot = redH[tid] + redH[256+tid] + redH[512+tid] + redH[768+tid];
  hws[(((size_t)(b*25+e)*16) + t)*256 + tid] = hwtot;
  reduce2Atomic(hwtot, sqa, gs1 + e, gs2 + e, redS);
}

// ---------- GNN back-half (8 dispatches, verified fusions, no grid sync) ----------

// projections, 720 blocks x 8 rows. Edge-src BN applied on the fly when bnfly=1
// (L0: src=HWS, EDG = scl[e]*hws + off[e] folded into the FMA chain).
__global__ void __launch_bounds__(256) gnnProj(const float* X, const float* ESRC,
    const float* gs1, const float* gs2, const float* gg, const float* gb, int bnfly,
    const float* Wa, const float* Wb, const float* Wu, const float* Wv, const float* We,
    float* xA, float* xB, float* xU, float* xV, float* eE) {
  int blk = blockIdx.x, tid = threadIdx.x;
  const float* src; const float* W; float* dst; int r0; int isE = 0;
  if (blk < 320) {
    int m = blk / 80; r0 = (blk % 80) * 8;
    src = X;
    W   = (m==0)?Wa:(m==1)?Wb:(m==2)?Wu:Wv;
    dst = (m==0)?xA:(m==1)?xB:(m==2)?xU:xV;
  } else { r0 = (blk-320)*8; src = ESRC; W = We; dst = eE; isE = 1; }
  float scl[8], off[8];
  #pragma unroll
  for (int r = 0; r < 8; ++r) { scl[r] = 1.f; off[r] = 0.f; }
  if (isE && bnfly) {
    constexpr float invCnt = 1.f/1605632.f;
    #pragma unroll
    for (int r = 0; r < 8; ++r) {
      int e = ((r0 + r) >> 4) % 25;
      float m = gs1[e]*invCnt;
      float var = gs2[e]*invCnt - m*m;
      float rstd = rsqrtf(var + 1e-5f);
      float g = gg[e]*rstd;
      scl[r] = g * (1.f/49.f);
      off[r] = gb[e] - g*m;
    }
  }
  float acc[8];
  #pragma unroll
  for (int r = 0; r < 8; ++r) acc[r] = 0.f;
  for (int c = 0; c < 256; c += 4) {
    float w0 = W[(size_t)(c+0)*256 + tid];
    float w1 = W[(size_t)(c+1)*256 + tid];
    float w2 = W[(size_t)(c+2)*256 + tid];
    float w3 = W[(size_t)(c+3)*256 + tid];
    #pragma unroll
    for (int r = 0; r < 8; ++r) {
      float4 a = *reinterpret_cast<const float4*>(&src[(size_t)(r0+r)*256 + c]);
      float ax = fmaf(a.x, scl[r], off[r]);
      float ay = fmaf(a.y, scl[r], off[r]);
      float az = fmaf(a.z, scl[r], off[r]);
      float aw = fmaf(a.w, scl[r], off[r]);
      acc[r] += ax*w0 + ay*w1 + az*w2 + aw*w3;
    }
  }
  #pragma unroll
  for (int r = 0; r < 8; ++r) dst[(size_t)(r0+r)*256 + tid] = acc[r];
}

__global__ void __launch_bounds__(256) g2a(const float* xA, const float* xB, const float* eE,
                                           float* ET, float* s1, float* s2) {
  __shared__ float red[8];
  int blk = blockIdx.x, tid = threadIdx.x;
  int b = blk / 400, e = (blk >> 4) % 25, t = blk & 15;
  int i = e / 5, j = e % 5;
  size_t ni = ((size_t)(b*5+i)*16 + t)*256 + tid;
  size_t nj = ((size_t)(b*5+j)*16 + t)*256 + tid;
  size_t ee = (size_t)blk*256 + tid;
  float v = xA[ni] + xB[nj] + eE[ee];
  ET[ee] = v;
  reduce2Atomic(v, v*v, s1 + e, s2 + e, red);
}

// fused g2b+g3a (verified in round-6's passing run). Block (b,i,t) owns edges
// e=i*5+j. layer==0: base EDG recomputed from HWS via gem-BN-fly, final EDG
// written. layer==1: base from EDG buffer; EDG NOT written; instead the
// finker edge output (sum_c edg*efw + efb) is computed in-register -> out.
__global__ void __launch_bounds__(256) g2bg3a(const float* ET, const float* HWS, const float* EDGin,
    float* EDGout, const float* xV, const float* xU, float* XN,
    const float* gs1, const float* gs2, const float* gemg, const float* gemb,
    const float* bg, const float* bb2, const float* es1, const float* es2,
    float* ns1, float* ns2, const float* efw, const float* efb, float* out, int layer) {
  __shared__ float red[8];
  int blk = blockIdx.x, tid = threadIdx.x;
  int b = blk / 80, i = (blk >> 4) % 5, t = blk & 15;
  constexpr float inv32k = 1.f/32768.f;
  constexpr float invCnt = 1.f/1605632.f;
  float ssum = 0.f, exv[5], xvv[5];
  #pragma unroll
  for (int j = 0; j < 5; ++j) {
    int e = i*5 + j;
    size_t ee = ((size_t)(b*25 + e)*16 + t)*256 + tid;
    float m = es1[e]*inv32k;
    float var = es2[e]*inv32k - m*m;
    float rstd = rsqrtf(var + 1e-5f);
    float v = bg[e]*((ET[ee]-m)*rstd) + bb2[e];
    if (v != v) v = 0.f;
    float base;
    if (layer == 0) {
      float gm = gs1[e]*invCnt;
      float gvar = gs2[e]*invCnt - gm*gm;
      float gr = rsqrtf(gvar + 1e-5f);
      base = gemg[e]*((HWS[ee]*(1.f/49.f) - gm)*gr) + gemb[e];
    } else {
      base = EDGin[ee];
    }
    float edg = base + fmaxf(v, 0.f);
    if (layer == 0) {
      EDGout[ee] = edg;
    } else {
      // fused finker edge part
      float vv = edg * efw[tid];
      #pragma unroll
      for (int off = 32; off; off >>= 1) vv += __shfl_down(vv, off);
      if ((tid & 63) == 0) red[tid >> 6] = vv;
      __syncthreads();
      if (tid == 0) out[640 + (size_t)(b*25 + e)*16 + t] = red[0]+red[1]+red[2]+red[3] + efb[0];
      __syncthreads();
    }
    float sg = 1.f/(1.f + __expf(-edg));
    exv[j] = __expf(sg);
    ssum += exv[j];
    xvv[j] = xV[((size_t)(b*5+j)*16 + t)*256 + tid];
  }
  float agg = 0.f;
  #pragma unroll
  for (int j = 0; j < 5; ++j) agg += exv[j]*xvv[j];
  agg *= 0.2f/ssum;
  float xn = xU[(size_t)blk*256 + tid] + agg;
  XN[(size_t)blk*256 + tid] = xn;
  reduce2Atomic(xn, xn*xn, ns1 + i, ns2 + i, red);
}

// L0 node BN + residual relu (writes FV for the next layer)
__global__ void __launch_bounds__(256) g3b(const float* XN, float* X, const float* g, const float* bb,
                                           const float* s1, const float* s2, int mask) {
  int blk = blockIdx.x, tid = threadIdx.x;
  int i = (blk >> 4) % 5;
  size_t ni = (size_t)blk*256 + tid;
  constexpr float invCnt = 1.f/32768.f;
  float m = s1[i]*invCnt;
  float var = s2[i]*invCnt - m*m;
  float rstd = rsqrtf(var + 1e-5f);
  float v = g[i]*((XN[ni]-m)*rstd) + bb[i];
  if (mask && v != v) v = 0.f;
  X[ni] = fmaxf(X[ni] + v, 0.f);
}

// L1 node BN + residual relu fused with finker node part (FV never written)
__global__ void __launch_bounds__(256) g3bfin(const float* XN, const float* FV,
    const float* g, const float* bb, const float* s1, const float* s2,
    const float* sc, float* out) {
  __shared__ float red[12];
  int blk = blockIdx.x, tid = threadIdx.x;
  int i = (blk >> 4) % 5;
  size_t ni = (size_t)blk*256 + tid;
  constexpr float inv32k = 1.f/32768.f;
  float m = s1[i]*inv32k;
  float var = s2[i]*inv32k - m*m;
  float rstd = rsqrtf(var + 1e-5f);
  float v = g[i]*((XN[ni]-m)*rstd) + bb[i];   // L1: no NaN mask
  float x = fmaxf(FV[ni] + v, 0.f);
  float s = fmaxf(sc[i*256 + tid], 0.f);
  float xx = x*x, ss = s*s, xs = x*s;
  #pragma unroll
  for (int off = 32; off; off >>= 1) {
    xx += __shfl_down(xx, off); ss += __shfl_down(ss, off); xs += __shfl_down(xs, off);
  }
  if ((tid & 63) == 0) { int w = tid >> 6; red[w*3] = xx; red[w*3+1] = ss; red[w*3+2] = xs; }
  __syncthreads();
  if (tid == 0) {
    float sxx = red[0]+red[3]+red[6]+red[9];
    float sss = red[1]+red[4]+red[7]+red[10];
    float sxs = red[2]+red[5]+red[8]+red[11];
    float nx = fmaxf(sqrtf(sxx), 1e-12f);
    float ns = fmaxf(sqrtf(sss), 1e-12f);
    out[blk] = sxs / (nx * ns);
  }
}

// ---------- host ----------

extern "C" void kernel_launch(void* const* d_in, const int* in_sizes, int n_in,
                              void* d_out, int out_size, void* d_ws, size_t ws_size,
                              hipStream_t stream) {
  (void)in_sizes; (void)n_in; (void)out_size; (void)ws_size;
  const float* af    = (const float*)d_in[0];
  const float* ef    = (const float*)d_in[1];
  const float* gfm   = (const float*)d_in[2];
  const float* attf  = (const float*)d_in[3];
  const float* sfm   = (const float*)d_in[4];
  const float* fam_q = (const float*)d_in[5];
  const float* fam_k = (const float*)d_in[6];
  const float* fam_v = (const float*)d_in[7];
  const float* arm_q = (const float*)d_in[8];
  const float* arm_k = (const float*)d_in[9];
  const float* arm_v = (const float*)d_in[10];
  const float* epw   = (const float*)d_in[11];
  const float* epb   = (const float*)d_in[12];
  const float* gemg  = (const float*)d_in[13];
  const float* gemb  = (const float*)d_in[14];
  const float* Us[2]   = {(const float*)d_in[15], (const float*)d_in[20]};
  const float* Vs[2]   = {(const float*)d_in[16], (const float*)d_in[21]};
  const float* As[2]   = {(const float*)d_in[17], (const float*)d_in[22]};
  const float* Bs[2]   = {(const float*)d_in[18], (const float*)d_in[23]};
  const float* Es[2]   = {(const float*)d_in[19], (const float*)d_in[24]};
  const float* bnvg[2] = {(const float*)d_in[25], (const float*)d_in[29]};
  const float* bnvb[2] = {(const float*)d_in[26], (const float*)d_in[30]};
  const float* bneg[2] = {(const float*)d_in[27], (const float*)d_in[31]};
  const float* bneb[2] = {(const float*)d_in[28], (const float*)d_in[32]};
  const float* scp  = (const float*)d_in[33];
  const float* efw  = (const float*)d_in[34];
  const float* efb  = (const float*)d_in[35];

  char* ws = (char*)d_ws;
  bhalf* PT  = (bhalf*)(ws + O_PT);
  bhalf* WTS = (bhalf*)(ws + O_WTS);
  bhalf* K1B = (bhalf*)(ws + O_K1B);
  bhalf* V1B = (bhalf*)(ws + O_V1B);
  bhalf* VQT = (bhalf*)(ws + O_VQT);
  bhalf* VKT = (bhalf*)(ws + O_VKT);
  bhalf* VTB = (bhalf*)(ws + O_VTB);
  bhalf* VWT = (bhalf*)(ws + O_VWT);
  bhalf* Q2B = (bhalf*)(ws + O_Q2B);
  bhalf* K2B = (bhalf*)(ws + O_K2B);
  bhalf* W2T = (bhalf*)(ws + O_W2T);
  float* FV  = (float*)(ws + O_FV);
  float* HWS = (float*)(ws + O_HWS);
  float* EDG = (float*)(ws + O_EDG);
  float* st  = (float*)(ws + O_ST);
  float* XA  = (float*)(ws + O_XA);
  float* XB  = (float*)(ws + O_XB);
  float* XU  = (float*)(ws + O_XU);
  float* XV  = (float*)(ws + O_XV);
  float* EE  = (float*)(ws + O_EE);
  float* ET  = (float*)(ws + O_ET);
  float* XN  = (float*)(ws + O_XN);

  hipMemsetAsync(st, 0, 256*sizeof(float), stream);

  wprep<<<1280, TPB, 0, stream>>>(fam_q, fam_k, fam_v, arm_q, arm_k, arm_v, epw, WTS);
  modprep<<<640, TPB, 0, stream>>>(af, ef, gfm, attf, sfm, PT, FV);
  kv1a<<<dim3(128, 6), TPB, 0, stream>>>(PT, WTS, K1B, V1B);
  kv1b<<<dim3(128, 8), TPB, 0, stream>>>(V1B, WTS, VQT, VKT, VTB);
  kv1c<<<dim3(128, 4), TPB, 0, stream>>>(VTB, WTS, VWT);
  s1ker<<<640, TPB, 0, stream>>>(PT, WTS, K1B, VQT, VKT, VWT, Q2B, K2B, W2T);
  s2ker<<<3200, TPB, 0, stream>>>(Q2B, K2B, W2T, epb, HWS, st+0, st+25);

  float* out = (float*)d_out;
  for (int L = 0; L < 2; ++L) {
    float* es1 = st + 64 + L*64;
    float* es2 = es1 + 25;
    float* ns1 = es1 + 50;
    float* ns2 = es1 + 55;
    gnnProj<<<720, TPB, 0, stream>>>(FV, (L == 0) ? HWS : EDG, st+0, st+25, gemg, gemb,
                                     (L == 0) ? 1 : 0,
                                     As[L], Bs[L], Us[L], Vs[L], Es[L],
                                     XA, XB, XU, XV, EE);
    g2a<<<3200, TPB, 0, stream>>>(XA, XB, EE, ET, es1, es2);
    g2bg3a<<<640, TPB, 0, stream>>>(ET, HWS, EDG, EDG, XV, XU, XN,
                                    st+0, st+25, gemg, gemb,
                                    bneg[L], bneb[L], es1, es2, ns1, ns2,
                                    efw, efb, out, L);
    if (L == 0)
      g3b<<<640, TPB, 0, stream>>>(XN, FV, bnvg[0], bnvb[0], ns1, ns2, 1);
    else
      g3bfin<<<640, TPB, 0, stream>>>(XN, FV, bnvg[1], bnvb[1], ns1, ns2, scp, out);
  }
}

// Round 8
// 387.052 us; speedup vs baseline: 5.7522x; 1.0118x over previous
//
#include <hip/hip_runtime.h>

#define DEV __device__ __forceinline__

typedef unsigned short bhalf;
typedef __attribute__((ext_vector_type(8))) short bf8v;
typedef __attribute__((ext_vector_type(4))) float f4;

namespace {
constexpr int TPB = 256;
constexpr float ATT_SCALE = 0.08838834764831845f; // 1/sqrt(128)

// ---- workspace byte offsets ----
constexpr size_t O_PT  = 0;          // bf16 [640][64][256]  modalities, zero-pad rows
constexpr size_t O_WTS = 20971520;   // bf16 transposed weights (see W_* below)
constexpr size_t O_K1B = 21626880;   // bf16 [128][64][128]
constexpr size_t O_V1B = 23724032;   // bf16 [128][64][256]
constexpr size_t O_VQT = 27918336;   // bf16 [128][128][64]  (v1@arm_q)^T
constexpr size_t O_VKT = 30015488;   // bf16 [128][128][64]
constexpr size_t O_VTB = 32112640;   // bf16 [128][64][256]  v1@arm_v
constexpr size_t O_VWT = 36306944;   // bf16 [128][256][64]  (vt@epw)^T
constexpr size_t O_Q2B = 40501248;   // bf16 [640][64][128]
constexpr size_t O_K2B = 50987008;   // bf16 [640][64][128]
constexpr size_t O_W2T = 61472768;   // bf16 [640][256][64]
constexpr size_t O_FV  = 82444288;   // f32  [640][256]  node features X
constexpr size_t O_HWS = 83099648;   // f32  [3200][256]
constexpr size_t O_EDG = 86376448;   // f32  [3200][256]
constexpr size_t O_ST  = 89653248;   // f32  [256] stats
constexpr size_t O_XA  = 89654272;
constexpr size_t O_XB  = 90309632;
constexpr size_t O_XU  = 90964992;
constexpr size_t O_XV  = 91620352;
constexpr size_t O_EE  = 92275712;
constexpr size_t O_ET  = 95552512;
constexpr size_t O_XN  = 98829312;

// WTS element offsets (bf16 elems), all stored as Wt[n][k=256]
constexpr size_t W_FAMQ = 0, W_FAMK = 32768, W_ARMQ = 65536, W_ARMK = 98304,
                 W_FAMV = 131072, W_ARMV = 196608, W_EPW = 262144;
} // namespace

// ---------- helpers ----------

DEV bhalf f2b(float f) {
  unsigned u = __float_as_uint(f);
  return (bhalf)((u + 0x7FFFu + ((u >> 16) & 1u)) >> 16);
}

DEV f4 mfma16(bf8v a, bf8v b, f4 c) {
  return __builtin_amdgcn_mfma_f32_16x16x32_bf16(a, b, c, 0, 0, 0);
}

// fragment load: lane l reads row (r0 + (l&15)), 8 contiguous k at k0 + (l>>4)*8
DEV bf8v ldfrag(const bhalf* base, int r0, int k0, int S, int l) {
  return *reinterpret_cast<const bf8v*>(base + (size_t)(r0 + (l & 15)) * S + k0 + ((l >> 4) << 3));
}

// swizzled LDS fragment load: byte = row*stride + koffB, XOR'd with ((row&7)<<4)
DEV bf8v ldswz(const bhalf* base, int row, int koffB, int strideB) {
  int byte = row * strideB + koffB;
  byte ^= ((row & 7) << 4);
  return *reinterpret_cast<const bf8v*>(reinterpret_cast<const char*>(base) + byte);
}

// in-register row softmax: sv[nt][reg], row per reg spans cols nt*16+(l&15) across 16 lanes
DEV void regSoftmax(float sv[4][4]) {
  #pragma unroll
  for (int reg = 0; reg < 4; ++reg) {
    float m = fmaxf(fmaxf(sv[0][reg], sv[1][reg]), fmaxf(sv[2][reg], sv[3][reg]));
    #pragma unroll
    for (int off = 1; off <= 8; off <<= 1) m = fmaxf(m, __shfl_xor(m, off));
    float s = 0.f;
    #pragma unroll
    for (int nt = 0; nt < 4; ++nt) { float e = __expf(sv[nt][reg] - m); sv[nt][reg] = e; s += e; }
    #pragma unroll
    for (int off = 1; off <= 8; off <<= 1) s += __shfl_xor(s, off);
    float inv = 1.f / s;
    #pragma unroll
    for (int nt = 0; nt < 4; ++nt) sv[nt][reg] *= inv;
  }
}

DEV void reduce2Atomic(float a, float b, float* ga, float* gb, float* red) {
  #pragma unroll
  for (int off = 32; off; off >>= 1) { a += __shfl_down(a, off); b += __shfl_down(b, off); }
  if ((threadIdx.x & 63) == 0) { int w = threadIdx.x >> 6; red[w*2] = a; red[w*2+1] = b; }
  __syncthreads();
  if (threadIdx.x == 0) {
    atomicAdd(ga, red[0]+red[2]+red[4]+red[6]);
    atomicAdd(gb, red[1]+red[3]+red[5]+red[7]);
  }
  __syncthreads();
}

// ---------- prep kernels ----------

// transpose 7 weight matrices to bf16 Wt[n][256]
__global__ void __launch_bounds__(256) wprep(const float* fq, const float* fk, const float* fv,
                                             const float* aq, const float* ak, const float* av,
                                             const float* ep, bhalf* WT) {
  int blk = blockIdx.x, tid = threadIdx.x;
  const float* src; bhalf* dst; int N, n;
  if (blk < 512) {
    int m = blk >> 7; n = blk & 127; N = 128;
    src = (m==0)?fq:(m==1)?fk:(m==2)?aq:ak;
    dst = WT + (size_t)m*32768;
  } else {
    int r = blk - 512; int m = r >> 8; n = r & 255; N = 256;
    src = (m==0)?fv:(m==1)?av:ep;
    dst = WT + 131072 + (size_t)m*65536;
  }
  dst[(size_t)n*256 + tid] = f2b(src[(size_t)tid*N + n]);
}

// per (bt,u): transpose modality slice to bf16 Pt[64][256] (zero-pad rows) + fv means
__global__ void __launch_bounds__(256) modprep(const float* af, const float* ef, const float* gf,
                                               const float* attf, const float* sf,
                                               bhalf* PT, float* FV) {
  __shared__ float lb[49*260];
  int blk = blockIdx.x, tid = threadIdx.x;
  int u = blk % 5, bt = blk / 5, b = bt >> 4, t = bt & 15;
  const float* src = (u==0)?af:(u==1)?ef:(u==2)?gf:(u==3)?attf:sf;
  src += ((size_t)b*256*16 + t)*49;
  for (int o = tid; o < 49*256; o += TPB) {
    int c = o / 49, p = o % 49;
    lb[p*260 + c] = src[(size_t)c*784 + p];
  }
  __syncthreads();
  bhalf* pt = PT + (size_t)blk*16384;
  for (int p = 0; p < 64; ++p)
    pt[p*256 + tid] = (p < 49) ? f2b(lb[p*260 + tid]) : (bhalf)0;
  float s = 0.f;
  for (int p = 0; p < 49; ++p) s += lb[p*260 + tid];
  FV[(((size_t)(b*5+u)*16) + t)*256 + tid] = s * (1.f/49.f);
}

// ---------- MFMA GEMM chain (fine nt-split over blockIdx.y for latency hiding) ----------

// per (bt, part): parts 0-1: k1 = Paf@fam_k nt quarters; parts 2-5: v1 = Paf@fam_v quarters
__global__ void __launch_bounds__(256) kv1a(const bhalf* PT, const bhalf* WT,
                                            bhalf* K1B, bhalf* V1B) {
  int bt = blockIdx.x, part = blockIdx.y;
  int tid = threadIdx.x, w = tid >> 6, l = tid & 63;
  const bhalf* A = PT + (size_t)bt*5*16384; // u=0 (af)
  bf8v a8[8];
  #pragma unroll
  for (int kt = 0; kt < 8; ++kt) a8[kt] = ldfrag(A, w*16, kt*32, 256, l);
  const bhalf* Wb; bhalf* dst; int nt0, S;
  if (part < 2) { Wb = WT + W_FAMK; dst = K1B + (size_t)bt*8192;  nt0 = part*4;     S = 128; }
  else          { Wb = WT + W_FAMV; dst = V1B + (size_t)bt*16384; nt0 = (part-2)*4; S = 256; }
  #pragma unroll
  for (int nn = 0; nn < 4; ++nn) {
    int nt = nt0 + nn;
    f4 acc = {0.f,0.f,0.f,0.f};
    #pragma unroll
    for (int kt = 0; kt < 8; ++kt)
      acc = mfma16(a8[kt], ldfrag(Wb, nt*16, kt*32, 256, l), acc);
    #pragma unroll
    for (int reg = 0; reg < 4; ++reg) {
      int p = w*16 + ((l>>4)<<2) + reg;
      dst[(size_t)p*S + nt*16 + (l&15)] = f2b(acc[reg]);
    }
  }
}

// per (bt, part): parts 0-1: vqt; 2-3: vkt (transposed [128][64]); 4-7: vtb quarters
__global__ void __launch_bounds__(256) kv1b(const bhalf* V1B, const bhalf* WT,
                                            bhalf* VQT, bhalf* VKT, bhalf* VTB) {
  int bt = blockIdx.x, part = blockIdx.y;
  int tid = threadIdx.x, w = tid >> 6, l = tid & 63;
  const bhalf* A = V1B + (size_t)bt*16384;
  bf8v a8[8];
  #pragma unroll
  for (int kt = 0; kt < 8; ++kt) a8[kt] = ldfrag(A, w*16, kt*32, 256, l);
  if (part < 4) {
    const bhalf* Wb = WT + ((part < 2) ? W_ARMQ : W_ARMK);
    bhalf* o = ((part < 2) ? VQT : VKT) + (size_t)bt*8192;
    int nt0 = (part & 1) * 4;
    #pragma unroll
    for (int nn = 0; nn < 4; ++nn) {
      int nt = nt0 + nn;
      f4 acc = {0.f,0.f,0.f,0.f};
      #pragma unroll
      for (int kt = 0; kt < 8; ++kt)
        acc = mfma16(a8[kt], ldfrag(Wb, nt*16, kt*32, 256, l), acc);
      #pragma unroll
      for (int reg = 0; reg < 4; ++reg) {
        int p = w*16 + ((l>>4)<<2) + reg;
        int n = nt*16 + (l&15);
        o[(size_t)n*64 + p] = f2b(acc[reg]);   // transposed store
      }
    }
  } else {
    bhalf* ov = VTB + (size_t)bt*16384;
    int nt0 = (part - 4) * 4;
    #pragma unroll
    for (int nn = 0; nn < 4; ++nn) {
      int nt = nt0 + nn;
      f4 acc = {0.f,0.f,0.f,0.f};
      #pragma unroll
      for (int kt = 0; kt < 8; ++kt)
        acc = mfma16(a8[kt], ldfrag(WT + W_ARMV, nt*16, kt*32, 256, l), acc);
      #pragma unroll
      for (int reg = 0; reg < 4; ++reg) {
        int p = w*16 + ((l>>4)<<2) + reg;
        ov[(size_t)p*256 + nt*16 + (l&15)] = f2b(acc[reg]);
      }
    }
  }
}

// per (bt, part): vwt = (vt@epw)^T [256][64], nt quarters
__global__ void __launch_bounds__(256) kv1c(const bhalf* VTB, const bhalf* WT, bhalf* VWT) {
  int bt = blockIdx.x, part = blockIdx.y;
  int tid = threadIdx.x, w = tid >> 6, l = tid & 63;
  const bhalf* A = VTB + (size_t)bt*16384;
  bf8v a8[8];
  #pragma unroll
  for (int kt = 0; kt < 8; ++kt) a8[kt] = ldfrag(A, w*16, kt*32, 256, l);
  bhalf* ow = VWT + (size_t)bt*16384;
  int nt0 = part * 4;
  #pragma unroll
  for (int nn = 0; nn < 4; ++nn) {
    int nt = nt0 + nn;
    f4 acc = {0.f,0.f,0.f,0.f};
    #pragma unroll
    for (int kt = 0; kt < 8; ++kt)
      acc = mfma16(a8[kt], ldfrag(WT + W_EPW, nt*16, kt*32, 256, l), acc);
    #pragma unroll
    for (int reg = 0; reg < 4; ++reg) {
      int p = w*16 + ((l>>4)<<2) + reg;
      ow[(size_t)(nt*16 + (l&15))*64 + p] = f2b(acc[reg]);  // transposed
    }
  }
}

// ---------- stage 1: FAM attention + ARM input projections ----------
// XCD-bijective remap (640 = 8*80): the 5 u-blocks of one bt share
// K1B/VQT/VKT/VWT tiles -> same-XCD L2 hits.
__global__ void __launch_bounds__(256) s1ker(const bhalf* PT, const bhalf* WT,
    const bhalf* K1B, const bhalf* VQT, const bhalf* VKT, const bhalf* VWT,
    bhalf* Q2B, bhalf* K2B, bhalf* W2T)
{
  __shared__ bhalf bufA[64*280];  // q1 staging, then w2 staging
  __shared__ bhalf bufP[64*72];
  __shared__ bhalf vqL[64*128];   // 16 KB, swizzled rows of 128 B
  __shared__ bhalf vkL[64*128];   // 16 KB
  int orig = blockIdx.x;
  int blk = (orig & 7) * 80 + (orig >> 3);   // bijective XCD grouping
  int bt = blk / 5;
  int tid = threadIdx.x, w = tid >> 6, l = tid & 63;
  const bhalf* Pt = PT + (size_t)blk*16384;
  // T14 issue-early: vq/vk tile loads (consumed after phase 1)
  float4 stg[8];
  {
    const char* gq = reinterpret_cast<const char*>(VQT + (size_t)bt*8192);
    const char* gk = reinterpret_cast<const char*>(VKT + (size_t)bt*8192);
    #pragma unroll
    for (int c = 0; c < 4; ++c) stg[c]   = *reinterpret_cast<const float4*>(gq + ((c*256 + tid) << 4));
    #pragma unroll
    for (int c = 0; c < 4; ++c) stg[4+c] = *reinterpret_cast<const float4*>(gk + ((c*256 + tid) << 4));
  }
  // phase 1: q1 (M=64, N=128, K=256) -> bufA bf16
  {
    bf8v a8[8];
    #pragma unroll
    for (int kt = 0; kt < 8; ++kt) a8[kt] = ldfrag(Pt, w*16, kt*32, 256, l);
    #pragma unroll
    for (int nt = 0; nt < 8; ++nt) {
      f4 acc = {0.f,0.f,0.f,0.f};
      #pragma unroll
      for (int kt = 0; kt < 8; ++kt)
        acc = mfma16(a8[kt], ldfrag(WT + W_FAMQ, nt*16, kt*32, 256, l), acc);
      #pragma unroll
      for (int reg = 0; reg < 4; ++reg)
        bufA[(w*16 + ((l>>4)<<2) + reg)*280 + nt*16 + (l&15)] = f2b(acc[reg]);
    }
  }
  // T14 write-late: swizzled LDS writes of vq/vk
  {
    char* lq = reinterpret_cast<char*>(vqL);
    char* lk = reinterpret_cast<char*>(vkL);
    #pragma unroll
    for (int c = 0; c < 4; ++c) {
      int x = (c*256 + tid) << 4;               // row = x>>7 (128 B rows)
      int xs = x ^ (((x >> 7) & 7) << 4);
      *reinterpret_cast<float4*>(lq + xs) = stg[c];
      *reinterpret_cast<float4*>(lk + xs) = stg[4+c];
    }
  }
  __syncthreads();
  // phase 2: scores vs k1 (own-wave rows from bufA), softmax in regs
  float sv[4][4];
  {
    const bhalf* K1 = K1B + (size_t)bt*8192;
    bf8v aq[4];
    #pragma unroll
    for (int kt = 0; kt < 4; ++kt) aq[kt] = ldfrag(bufA, w*16, kt*32, 280, l);
    #pragma unroll
    for (int nt = 0; nt < 4; ++nt) {
      f4 acc = {0.f,0.f,0.f,0.f};
      #pragma unroll
      for (int kt = 0; kt < 4; ++kt)
        acc = mfma16(aq[kt], ldfrag(K1, nt*16, kt*32, 128, l), acc);
      #pragma unroll
      for (int reg = 0; reg < 4; ++reg) sv[nt][reg] = acc[reg] * ATT_SCALE;
    }
  }
  if ((l & 15) > 0) { sv[3][0] = -1e30f; sv[3][1] = -1e30f; sv[3][2] = -1e30f; sv[3][3] = -1e30f; }
  regSoftmax(sv);
  #pragma unroll
  for (int nt = 0; nt < 4; ++nt)
    #pragma unroll
    for (int reg = 0; reg < 4; ++reg)
      bufP[(w*16 + ((l>>4)<<2) + reg)*72 + nt*16 + (l&15)] = f2b(sv[nt][reg]);
  __syncthreads();
  // phase 3: PVs
  bf8v ap0 = ldfrag(bufP, w*16, 0, 72, l);
  bf8v ap1 = ldfrag(bufP, w*16, 32, 72, l);
  {
    bhalf* q2 = Q2B + (size_t)blk*8192;
    #pragma unroll
    for (int nt = 0; nt < 8; ++nt) {
      f4 acc = {0.f,0.f,0.f,0.f};
      acc = mfma16(ap0, ldswz(vqL, nt*16 + (l & 15), ((l >> 4) << 4), 128), acc);
      acc = mfma16(ap1, ldswz(vqL, nt*16 + (l & 15), 64 + ((l >> 4) << 4), 128), acc);
      #pragma unroll
      for (int reg = 0; reg < 4; ++reg) {
        int p = w*16 + ((l>>4)<<2) + reg;
        q2[(size_t)p*128 + nt*16 + (l&15)] = (p < 49) ? f2b(acc[reg]) : (bhalf)0;
      }
    }
  }
  {
    bhalf* k2 = K2B + (size_t)blk*8192;
    #pragma unroll
    for (int nt = 0; nt < 8; ++nt) {
      f4 acc = {0.f,0.f,0.f,0.f};
      acc = mfma16(ap0, ldswz(vkL, nt*16 + (l & 15), ((l >> 4) << 4), 128), acc);
      acc = mfma16(ap1, ldswz(vkL, nt*16 + (l & 15), 64 + ((l >> 4) << 4), 128), acc);
      #pragma unroll
      for (int reg = 0; reg < 4; ++reg) {
        int p = w*16 + ((l>>4)<<2) + reg;
        k2[(size_t)p*128 + nt*16 + (l&15)] = (p < 49) ? f2b(acc[reg]) : (bhalf)0;
      }
    }
  }
  {
    const bhalf* vw = VWT + (size_t)bt*16384;
    #pragma unroll
    for (int nt = 0; nt < 16; ++nt) {
      f4 acc = {0.f,0.f,0.f,0.f};
      acc = mfma16(ap0, ldfrag(vw, nt*16, 0, 64, l), acc);
      acc = mfma16(ap1, ldfrag(vw, nt*16, 32, 64, l), acc);
      #pragma unroll
      for (int reg = 0; reg < 4; ++reg)
        bufA[(w*16 + ((l>>4)<<2) + reg)*280 + nt*16 + (l&15)] = f2b(acc[reg]);
    }
  }
  __syncthreads();
  // epilogue: w2t[c][r] coalesced (pairs packed into u32)
  unsigned* wt = reinterpret_cast<unsigned*>(W2T + (size_t)blk*16384);
  for (int it = 0; it < 32; ++it) {
    int o = it*256 + tid;       // 0..8191
    int c = o >> 5, ii = o & 31;
    int r0 = ii*2;
    unsigned lo = (r0   < 49) ? (unsigned)bufA[r0*280 + c]     : 0u;
    unsigned hi = (r0+1 < 49) ? (unsigned)bufA[(r0+1)*280 + c] : 0u;
    wt[o] = lo | (hi << 16);
  }
}

// ---------- stage 2: ARM attention + edge stats (column-split PV, V in registers) ----------
// One block per (bt,e). K staged to swizzled LDS (16 KB, read by all waves).
// PV is COLUMN-SPLIT: wave w owns nt2 in [4w,4w+4) -> its disjoint 64-row slice
// of V held in 8 bf8v registers (no Vl -> LDS 62.9->26.6 KB -> 3 blocks/CU).
// P becomes cross-wave readable via bufP + one extra barrier. redH columns are
// per-wave disjoint (no cross-wave sum). V-frag loads issue just before the
// bufP barrier so their latency hides under the barrier wait.
__global__ void __launch_bounds__(256) s2ker(const bhalf* Q2B, const bhalf* K2B, const bhalf* W2T,
    const float* epb, float* hws, float* gs1, float* gs2)
{
  __shared__ bhalf Kl[64*128];    // 16 KB, swizzled rows of 256 B
  __shared__ bhalf bufP[64*72];   // 9 KB, full P (cross-wave)
  __shared__ float redH[256];     // 1 KB, per-wave disjoint columns
  __shared__ float redS[8];
  int orig = blockIdx.x;
  int blk = (orig & 7) * 400 + (orig >> 3);   // 3200 = 8*400, bijective XCD grouping
  int e = blk % 25, bt = blk / 25, b = bt >> 4, t = bt & 15;
  int i = e / 5, j = e % 5;
  int tid = threadIdx.x, w = tid >> 6, l = tid & 63;
  const bhalf* K = K2B + (size_t)(bt*5 + i)*8192;
  const bhalf* V = W2T + (size_t)(bt*5 + i)*16384;
  const bhalf* Q = Q2B + (size_t)(bt*5 + j)*8192;
  // prefetch Q fragments (independent of LDS staging)
  bf8v aq[4];
  #pragma unroll
  for (int kt = 0; kt < 4; ++kt) aq[kt] = ldfrag(Q, w*16, kt*32, 128, l);
  // ---- stage K (16 KB): coalesced global read, swizzled LDS write ----
  {
    const char* gk = reinterpret_cast<const char*>(K);
    char* lk = reinterpret_cast<char*>(Kl);
    #pragma unroll
    for (int c = 0; c < 4; ++c) {
      int x = (c*256 + tid) << 4;                 // K: row = x>>8 (256 B rows)
      float4 val = *reinterpret_cast<const float4*>(gk + x);
      *reinterpret_cast<float4*>(lk + (x ^ (((x >> 8) & 7) << 4))) = val;
    }
  }
  __syncthreads();
  // QK^T from LDS + in-register softmax
  float sv[4][4];
  __builtin_amdgcn_s_setprio(1);
  #pragma unroll
  for (int nt = 0; nt < 4; ++nt) {
    f4 acc = {0.f,0.f,0.f,0.f};
    #pragma unroll
    for (int kt = 0; kt < 4; ++kt)
      acc = mfma16(aq[kt], ldswz(Kl, nt*16 + (l & 15), kt*64 + ((l >> 4) << 4), 256), acc);
    #pragma unroll
    for (int reg = 0; reg < 4; ++reg) sv[nt][reg] = acc[reg] * ATT_SCALE;
  }
  __builtin_amdgcn_s_setprio(0);
  if ((l & 15) > 0) { sv[3][0] = -1e30f; sv[3][1] = -1e30f; sv[3][2] = -1e30f; sv[3][3] = -1e30f; }
  regSoftmax(sv);
  // write own P rows to bufP
  #pragma unroll
  for (int nt = 0; nt < 4; ++nt)
    #pragma unroll
    for (int reg = 0; reg < 4; ++reg)
      bufP[(w*16 + ((l>>4)<<2) + reg)*72 + nt*16 + (l&15)] = f2b(sv[nt][reg]);
  // V fragments for this wave's column slice (rows [w*64, w*64+64) of W2T tile);
  // issued before the barrier so global latency hides under the barrier wait.
  bf8v vf0[4], vf1[4];
  #pragma unroll
  for (int nn = 0; nn < 4; ++nn) {
    vf0[nn] = ldfrag(V, (w*4 + nn)*16, 0, 64, l);
    vf1[nn] = ldfrag(V, (w*4 + nn)*16, 32, 64, l);
  }
  __syncthreads();   // bufP complete (cross-wave read next)
  // A-fragments: all 4 row-groups of P
  bf8v ap0[4], ap1[4];
  #pragma unroll
  for (int g = 0; g < 4; ++g) {
    ap0[g] = ldfrag(bufP, g*16, 0, 72, l);
    ap1[g] = ldfrag(bufP, g*16, 32, 72, l);
  }
  float sqa = 0.f;
  __builtin_amdgcn_s_setprio(1);
  #pragma unroll
  for (int nn = 0; nn < 4; ++nn) {
    f4 acc[4];
    #pragma unroll
    for (int g = 0; g < 4; ++g) {
      f4 z = {0.f,0.f,0.f,0.f};
      z = mfma16(ap0[g], vf0[nn], z);
      acc[g] = mfma16(ap1[g], vf1[nn], z);
    }
    int c = ((w*4 + nn) << 4) + (l & 15);
    float bias = epb[c];
    float hw = 0.f;
    #pragma unroll
    for (int g = 0; g < 4; ++g) {
      #pragma unroll
      for (int reg = 0; reg < 4; ++reg) {
        int p = g*16 + ((l>>4)<<2) + reg;
        if (p < 49) { float v = acc[g][reg] + bias; hw += v; sqa += v*v; }
      }
    }
    hw += __shfl_xor(hw, 16);
    hw += __shfl_xor(hw, 32);
    if ((l >> 4) == 0) redH[c] = hw;   // per-wave disjoint c
  }
  __builtin_amdgcn_s_setprio(0);
  __syncthreads();
  float hwtot = redH[tid];
  hws[(((size_t)(b*25+e)*16) + t)*256 + tid] = hwtot;
  reduce2Atomic(hwtot, sqa, gs1 + e, gs2 + e, redS);
}

// ---------- GNN back-half (8 dispatches, verified fusions, no grid sync) ----------

// projections, 720 blocks x 8 rows. Edge-src BN applied on the fly when bnfly=1
// (L0: src=HWS, EDG = scl[e]*hws + off[e] folded into the FMA chain).
__global__ void __launch_bounds__(256) gnnProj(const float* X, const float* ESRC,
    const float* gs1, const float* gs2, const float* gg, const float* gb, int bnfly,
    const float* Wa, const float* Wb, const float* Wu, const float* Wv, const float* We,
    float* xA, float* xB, float* xU, float* xV, float* eE) {
  int blk = blockIdx.x, tid = threadIdx.x;
  const float* src; const float* W; float* dst; int r0; int isE = 0;
  if (blk < 320) {
    int m = blk / 80; r0 = (blk % 80) * 8;
    src = X;
    W   = (m==0)?Wa:(m==1)?Wb:(m==2)?Wu:Wv;
    dst = (m==0)?xA:(m==1)?xB:(m==2)?xU:xV;
  } else { r0 = (blk-320)*8; src = ESRC; W = We; dst = eE; isE = 1; }
  float scl[8], off[8];
  #pragma unroll
  for (int r = 0; r < 8; ++r) { scl[r] = 1.f; off[r] = 0.f; }
  if (isE && bnfly) {
    constexpr float invCnt = 1.f/1605632.f;
    #pragma unroll
    for (int r = 0; r < 8; ++r) {
      int e = ((r0 + r) >> 4) % 25;
      float m = gs1[e]*invCnt;
      float var = gs2[e]*invCnt - m*m;
      float rstd = rsqrtf(var + 1e-5f);
      float g = gg[e]*rstd;
      scl[r] = g * (1.f/49.f);
      off[r] = gb[e] - g*m;
    }
  }
  float acc[8];
  #pragma unroll
  for (int r = 0; r < 8; ++r) acc[r] = 0.f;
  for (int c = 0; c < 256; c += 4) {
    float w0 = W[(size_t)(c+0)*256 + tid];
    float w1 = W[(size_t)(c+1)*256 + tid];
    float w2 = W[(size_t)(c+2)*256 + tid];
    float w3 = W[(size_t)(c+3)*256 + tid];
    #pragma unroll
    for (int r = 0; r < 8; ++r) {
      float4 a = *reinterpret_cast<const float4*>(&src[(size_t)(r0+r)*256 + c]);
      float ax = fmaf(a.x, scl[r], off[r]);
      float ay = fmaf(a.y, scl[r], off[r]);
      float az = fmaf(a.z, scl[r], off[r]);
      float aw = fmaf(a.w, scl[r], off[r]);
      acc[r] += ax*w0 + ay*w1 + az*w2 + aw*w3;
    }
  }
  #pragma unroll
  for (int r = 0; r < 8; ++r) dst[(size_t)(r0+r)*256 + tid] = acc[r];
}

__global__ void __launch_bounds__(256) g2a(const float* xA, const float* xB, const float* eE,
                                           float* ET, float* s1, float* s2) {
  __shared__ float red[8];
  int blk = blockIdx.x, tid = threadIdx.x;
  int b = blk / 400, e = (blk >> 4) % 25, t = blk & 15;
  int i = e / 5, j = e % 5;
  size_t ni = ((size_t)(b*5+i)*16 + t)*256 + tid;
  size_t nj = ((size_t)(b*5+j)*16 + t)*256 + tid;
  size_t ee = (size_t)blk*256 + tid;
  float v = xA[ni] + xB[nj] + eE[ee];
  ET[ee] = v;
  reduce2Atomic(v, v*v, s1 + e, s2 + e, red);
}

// fused g2b+g3a. Block (b,i,t) owns edges e=i*5+j. layer==0: base EDG
// recomputed from HWS via gem-BN-fly, final EDG written. layer==1: base from
// EDG buffer; EDG NOT written; finker edge output computed in-register -> out.
__global__ void __launch_bounds__(256) g2bg3a(const float* ET, const float* HWS, const float* EDGin,
    float* EDGout, const float* xV, const float* xU, float* XN,
    const float* gs1, const float* gs2, const float* gemg, const float* gemb,
    const float* bg, const float* bb2, const float* es1, const float* es2,
    float* ns1, float* ns2, const float* efw, const float* efb, float* out, int layer) {
  __shared__ float red[8];
  int blk = blockIdx.x, tid = threadIdx.x;
  int b = blk / 80, i = (blk >> 4) % 5, t = blk & 15;
  constexpr float inv32k = 1.f/32768.f;
  constexpr float invCnt = 1.f/1605632.f;
  float ssum = 0.f, exv[5], xvv[5];
  #pragma unroll
  for (int j = 0; j < 5; ++j) {
    int e = i*5 + j;
    size_t ee = ((size_t)(b*25 + e)*16 + t)*256 + tid;
    float m = es1[e]*inv32k;
    float var = es2[e]*inv32k - m*m;
    float rstd = rsqrtf(var + 1e-5f);
    float v = bg[e]*((ET[ee]-m)*rstd) + bb2[e];
    if (v != v) v = 0.f;
    float base;
    if (layer == 0) {
      float gm = gs1[e]*invCnt;
      float gvar = gs2[e]*invCnt - gm*gm;
      float gr = rsqrtf(gvar + 1e-5f);
      base = gemg[e]*((HWS[ee]*(1.f/49.f) - gm)*gr) + gemb[e];
    } else {
      base = EDGin[ee];
    }
    float edg = base + fmaxf(v, 0.f);
    if (layer == 0) {
      EDGout[ee] = edg;
    } else {
      // fused finker edge part
      float vv = edg * efw[tid];
      #pragma unroll
      for (int off = 32; off; off >>= 1) vv += __shfl_down(vv, off);
      if ((tid & 63) == 0) red[tid >> 6] = vv;
      __syncthreads();
      if (tid == 0) out[640 + (size_t)(b*25 + e)*16 + t] = red[0]+red[1]+red[2]+red[3] + efb[0];
      __syncthreads();
    }
    float sg = 1.f/(1.f + __expf(-edg));
    exv[j] = __expf(sg);
    ssum += exv[j];
    xvv[j] = xV[((size_t)(b*5+j)*16 + t)*256 + tid];
  }
  float agg = 0.f;
  #pragma unroll
  for (int j = 0; j < 5; ++j) agg += exv[j]*xvv[j];
  agg *= 0.2f/ssum;
  float xn = xU[(size_t)blk*256 + tid] + agg;
  XN[(size_t)blk*256 + tid] = xn;
  reduce2Atomic(xn, xn*xn, ns1 + i, ns2 + i, red);
}

// L0 node BN + residual relu (writes FV for the next layer)
__global__ void __launch_bounds__(256) g3b(const float* XN, float* X, const float* g, const float* bb,
                                           const float* s1, const float* s2, int mask) {
  int blk = blockIdx.x, tid = threadIdx.x;
  int i = (blk >> 4) % 5;
  size_t ni = (size_t)blk*256 + tid;
  constexpr float invCnt = 1.f/32768.f;
  float m = s1[i]*invCnt;
  float var = s2[i]*invCnt - m*m;
  float rstd = rsqrtf(var + 1e-5f);
  float v = g[i]*((XN[ni]-m)*rstd) + bb[i];
  if (mask && v != v) v = 0.f;
  X[ni] = fmaxf(X[ni] + v, 0.f);
}

// L1 node BN + residual relu fused with finker node part (FV never written)
__global__ void __launch_bounds__(256) g3bfin(const float* XN, const float* FV,
    const float* g, const float* bb, const float* s1, const float* s2,
    const float* sc, float* out) {
  __shared__ float red[12];
  int blk = blockIdx.x, tid = threadIdx.x;
  int i = (blk >> 4) % 5;
  size_t ni = (size_t)blk*256 + tid;
  constexpr float inv32k = 1.f/32768.f;
  float m = s1[i]*inv32k;
  float var = s2[i]*inv32k - m*m;
  float rstd = rsqrtf(var + 1e-5f);
  float v = g[i]*((XN[ni]-m)*rstd) + bb[i];   // L1: no NaN mask
  float x = fmaxf(FV[ni] + v, 0.f);
  float s = fmaxf(sc[i*256 + tid], 0.f);
  float xx = x*x, ss = s*s, xs = x*s;
  #pragma unroll
  for (int off = 32; off; off >>= 1) {
    xx += __shfl_down(xx, off); ss += __shfl_down(ss, off); xs += __shfl_down(xs, off);
  }
  if ((tid & 63) == 0) { int w = tid >> 6; red[w*3] = xx; red[w*3+1] = ss; red[w*3+2] = xs; }
  __syncthreads();
  if (tid == 0) {
    float sxx = red[0]+red[3]+red[6]+red[9];
    float sss = red[1]+red[4]+red[7]+red[10];
    float sxs = red[2]+red[5]+red[8]+red[11];
    float nx = fmaxf(sqrtf(sxx), 1e-12f);
    float ns = fmaxf(sqrtf(sss), 1e-12f);
    out[blk] = sxs / (nx * ns);
  }
}

// ---------- host ----------

extern "C" void kernel_launch(void* const* d_in, const int* in_sizes, int n_in,
                              void* d_out, int out_size, void* d_ws, size_t ws_size,
                              hipStream_t stream) {
  (void)in_sizes; (void)n_in; (void)out_size; (void)ws_size;
  const float* af    = (const float*)d_in[0];
  const float* ef    = (const float*)d_in[1];
  const float* gfm   = (const float*)d_in[2];
  const float* attf  = (const float*)d_in[3];
  const float* sfm   = (const float*)d_in[4];
  const float* fam_q = (const float*)d_in[5];
  const float* fam_k = (const float*)d_in[6];
  const float* fam_v = (const float*)d_in[7];
  const float* arm_q = (const float*)d_in[8];
  const float* arm_k = (const float*)d_in[9];
  const float* arm_v = (const float*)d_in[10];
  const float* epw   = (const float*)d_in[11];
  const float* epb   = (const float*)d_in[12];
  const float* gemg  = (const float*)d_in[13];
  const float* gemb  = (const float*)d_in[14];
  const float* Us[2]   = {(const float*)d_in[15], (const float*)d_in[20]};
  const float* Vs[2]   = {(const float*)d_in[16], (const float*)d_in[21]};
  const float* As[2]   = {(const float*)d_in[17], (const float*)d_in[22]};
  const float* Bs[2]   = {(const float*)d_in[18], (const float*)d_in[23]};
  const float* Es[2]   = {(const float*)d_in[19], (const float*)d_in[24]};
  const float* bnvg[2] = {(const float*)d_in[25], (const float*)d_in[29]};
  const float* bnvb[2] = {(const float*)d_in[26], (const float*)d_in[30]};
  const float* bneg[2] = {(const float*)d_in[27], (const float*)d_in[31]};
  const float* bneb[2] = {(const float*)d_in[28], (const float*)d_in[32]};
  const float* scp  = (const float*)d_in[33];
  const float* efw  = (const float*)d_in[34];
  const float* efb  = (const float*)d_in[35];

  char* ws = (char*)d_ws;
  bhalf* PT  = (bhalf*)(ws + O_PT);
  bhalf* WTS = (bhalf*)(ws + O_WTS);
  bhalf* K1B = (bhalf*)(ws + O_K1B);
  bhalf* V1B = (bhalf*)(ws + O_V1B);
  bhalf* VQT = (bhalf*)(ws + O_VQT);
  bhalf* VKT = (bhalf*)(ws + O_VKT);
  bhalf* VTB = (bhalf*)(ws + O_VTB);
  bhalf* VWT = (bhalf*)(ws + O_VWT);
  bhalf* Q2B = (bhalf*)(ws + O_Q2B);
  bhalf* K2B = (bhalf*)(ws + O_K2B);
  bhalf* W2T = (bhalf*)(ws + O_W2T);
  float* FV  = (float*)(ws + O_FV);
  float* HWS = (float*)(ws + O_HWS);
  float* EDG = (float*)(ws + O_EDG);
  float* st  = (float*)(ws + O_ST);
  float* XA  = (float*)(ws + O_XA);
  float* XB  = (float*)(ws + O_XB);
  float* XU  = (float*)(ws + O_XU);
  float* XV  = (float*)(ws + O_XV);
  float* EE  = (float*)(ws + O_EE);
  float* ET  = (float*)(ws + O_ET);
  float* XN  = (float*)(ws + O_XN);

  hipMemsetAsync(st, 0, 256*sizeof(float), stream);

  wprep<<<1280, TPB, 0, stream>>>(fam_q, fam_k, fam_v, arm_q, arm_k, arm_v, epw, WTS);
  modprep<<<640, TPB, 0, stream>>>(af, ef, gfm, attf, sfm, PT, FV);
  kv1a<<<dim3(128, 6), TPB, 0, stream>>>(PT, WTS, K1B, V1B);
  kv1b<<<dim3(128, 8), TPB, 0, stream>>>(V1B, WTS, VQT, VKT, VTB);
  kv1c<<<dim3(128, 4), TPB, 0, stream>>>(VTB, WTS, VWT);
  s1ker<<<640, TPB, 0, stream>>>(PT, WTS, K1B, VQT, VKT, VWT, Q2B, K2B, W2T);
  s2ker<<<3200, TPB, 0, stream>>>(Q2B, K2B, W2T, epb, HWS, st+0, st+25);

  float* out = (float*)d_out;
  for (int L = 0; L < 2; ++L) {
    float* es1 = st + 64 + L*64;
    float* es2 = es1 + 25;
    float* ns1 = es1 + 50;
    float* ns2 = es1 + 55;
    gnnProj<<<720, TPB, 0, stream>>>(FV, (L == 0) ? HWS : EDG, st+0, st+25, gemg, gemb,
                                     (L == 0) ? 1 : 0,
                                     As[L], Bs[L], Us[L], Vs[L], Es[L],
                                     XA, XB, XU, XV, EE);
    g2a<<<3200, TPB, 0, stream>>>(XA, XB, EE, ET, es1, es2);
    g2bg3a<<<640, TPB, 0, stream>>>(ET, HWS, EDG, EDG, XV, XU, XN,
                                    st+0, st+25, gemg, gemb,
                                    bneg[L], bneb[L], es1, es2, ns1, ns2,
                                    efw, efb, out, L);
    if (L == 0)
      g3b<<<640, TPB, 0, stream>>>(XN, FV, bnvg[0], bnvb[0], ns1, ns2, 1);
    else
      g3bfin<<<640, TPB, 0, stream>>>(XN, FV, bnvg[1], bnvb[1], ns1, ns2, scp, out);
  }
}

// Round 9
// 376.032 us; speedup vs baseline: 5.9207x; 1.0293x over previous
//
#include <hip/hip_runtime.h>

#define DEV __device__ __forceinline__

typedef unsigned short bhalf;
typedef __attribute__((ext_vector_type(8))) short bf8v;
typedef __attribute__((ext_vector_type(4))) float f4;

namespace {
constexpr int TPB = 256;
constexpr float ATT_SCALE = 0.08838834764831845f; // 1/sqrt(128)

// ---- workspace byte offsets ----
constexpr size_t O_PT  = 0;          // bf16 [640][64][256]  modalities, zero-pad rows
constexpr size_t O_WTS = 20971520;   // bf16 transposed weights (see W_* below)
constexpr size_t O_K1B = 21626880;   // bf16 [128][64][128]
constexpr size_t O_V1B = 23724032;   // bf16 [128][64][256]
constexpr size_t O_VQT = 27918336;   // bf16 [128][128][64]  (v1@arm_q)^T
constexpr size_t O_VKT = 30015488;   // bf16 [128][128][64]
constexpr size_t O_VTB = 32112640;   // bf16 [128][64][256]  v1@arm_v
constexpr size_t O_VWT = 36306944;   // bf16 [128][256][64]  (vt@epw)^T
constexpr size_t O_Q2B = 40501248;   // bf16 [640][64][128]
constexpr size_t O_K2B = 50987008;   // bf16 [640][64][128]
constexpr size_t O_W2T = 61472768;   // bf16 [640][256][64]
constexpr size_t O_FV  = 82444288;   // f32  [640][256]  node features X
constexpr size_t O_HWS = 83099648;   // f32  [3200][256]
constexpr size_t O_EDG = 86376448;   // f32  [3200][256]
constexpr size_t O_ST  = 89653248;   // f32  [256] stats
constexpr size_t O_XA  = 89654272;
constexpr size_t O_XB  = 90309632;
constexpr size_t O_XU  = 90964992;
constexpr size_t O_XV  = 91620352;
constexpr size_t O_EE  = 92275712;
constexpr size_t O_ET  = 95552512;
constexpr size_t O_XN  = 98829312;

// WTS element offsets (bf16 elems), all stored as Wt[n][k=256]
constexpr size_t W_FAMQ = 0, W_FAMK = 32768, W_ARMQ = 65536, W_ARMK = 98304,
                 W_FAMV = 131072, W_ARMV = 196608, W_EPW = 262144;
} // namespace

// ---------- helpers ----------

DEV bhalf f2b(float f) {
  unsigned u = __float_as_uint(f);
  return (bhalf)((u + 0x7FFFu + ((u >> 16) & 1u)) >> 16);
}

DEV f4 mfma16(bf8v a, bf8v b, f4 c) {
  return __builtin_amdgcn_mfma_f32_16x16x32_bf16(a, b, c, 0, 0, 0);
}

// fragment load: lane l reads row (r0 + (l&15)), 8 contiguous k at k0 + (l>>4)*8
DEV bf8v ldfrag(const bhalf* base, int r0, int k0, int S, int l) {
  return *reinterpret_cast<const bf8v*>(base + (size_t)(r0 + (l & 15)) * S + k0 + ((l >> 4) << 3));
}

// swizzled LDS fragment load: byte = row*stride + koffB, XOR'd with ((row&7)<<4)
DEV bf8v ldswz(const bhalf* base, int row, int koffB, int strideB) {
  int byte = row * strideB + koffB;
  byte ^= ((row & 7) << 4);
  return *reinterpret_cast<const bf8v*>(reinterpret_cast<const char*>(base) + byte);
}

// in-register row softmax: sv[nt][reg], row per reg spans cols nt*16+(l&15) across 16 lanes
DEV void regSoftmax(float sv[4][4]) {
  #pragma unroll
  for (int reg = 0; reg < 4; ++reg) {
    float m = fmaxf(fmaxf(sv[0][reg], sv[1][reg]), fmaxf(sv[2][reg], sv[3][reg]));
    #pragma unroll
    for (int off = 1; off <= 8; off <<= 1) m = fmaxf(m, __shfl_xor(m, off));
    float s = 0.f;
    #pragma unroll
    for (int nt = 0; nt < 4; ++nt) { float e = __expf(sv[nt][reg] - m); sv[nt][reg] = e; s += e; }
    #pragma unroll
    for (int off = 1; off <= 8; off <<= 1) s += __shfl_xor(s, off);
    float inv = 1.f / s;
    #pragma unroll
    for (int nt = 0; nt < 4; ++nt) sv[nt][reg] *= inv;
  }
}

DEV void reduce2Atomic(float a, float b, float* ga, float* gb, float* red) {
  #pragma unroll
  for (int off = 32; off; off >>= 1) { a += __shfl_down(a, off); b += __shfl_down(b, off); }
  if ((threadIdx.x & 63) == 0) { int w = threadIdx.x >> 6; red[w*2] = a; red[w*2+1] = b; }
  __syncthreads();
  if (threadIdx.x == 0) {
    atomicAdd(ga, red[0]+red[2]+red[4]+red[6]);
    atomicAdd(gb, red[1]+red[3]+red[5]+red[7]);
  }
  __syncthreads();
}

// ---------- prep kernel (wprep + modprep merged: independent work, one dispatch) ----------

__global__ void __launch_bounds__(256) prepAll(const float* fq, const float* fk, const float* fv,
                                               const float* aq, const float* ak, const float* av,
                                               const float* ep, bhalf* WT,
                                               const float* af, const float* ef, const float* gf,
                                               const float* attf, const float* sf,
                                               bhalf* PT, float* FV) {
  __shared__ float lb[49*260];
  int tid = threadIdx.x;
  if (blockIdx.x < 1280) {
    // ---- wprep: transpose 7 weight matrices to bf16 Wt[n][256] ----
    int blk = blockIdx.x;
    const float* src; bhalf* dst; int N, n;
    if (blk < 512) {
      int m = blk >> 7; n = blk & 127; N = 128;
      src = (m==0)?fq:(m==1)?fk:(m==2)?aq:ak;
      dst = WT + (size_t)m*32768;
    } else {
      int r = blk - 512; int m = r >> 8; n = r & 255; N = 256;
      src = (m==0)?fv:(m==1)?av:ep;
      dst = WT + 131072 + (size_t)m*65536;
    }
    dst[(size_t)n*256 + tid] = f2b(src[(size_t)tid*N + n]);
  } else {
    // ---- modprep: per (bt,u) modality transpose + fv means ----
    int blk = blockIdx.x - 1280;
    int u = blk % 5, bt = blk / 5, b = bt >> 4, t = bt & 15;
    const float* src = (u==0)?af:(u==1)?ef:(u==2)?gf:(u==3)?attf:sf;
    src += ((size_t)b*256*16 + t)*49;
    for (int o = tid; o < 49*256; o += TPB) {
      int c = o / 49, p = o % 49;
      lb[p*260 + c] = src[(size_t)c*784 + p];
    }
    __syncthreads();
    bhalf* pt = PT + (size_t)blk*16384;
    for (int p = 0; p < 64; ++p)
      pt[p*256 + tid] = (p < 49) ? f2b(lb[p*260 + tid]) : (bhalf)0;
    float s = 0.f;
    for (int p = 0; p < 49; ++p) s += lb[p*260 + tid];
    FV[(((size_t)(b*5+u)*16) + t)*256 + tid] = s * (1.f/49.f);
  }
}

// ---------- MFMA GEMM chain (fine nt-split over blockIdx.y for latency hiding) ----------

// per (bt, part): parts 0-1: k1 = Paf@fam_k nt quarters; parts 2-5: v1 = Paf@fam_v quarters
__global__ void __launch_bounds__(256) kv1a(const bhalf* PT, const bhalf* WT,
                                            bhalf* K1B, bhalf* V1B) {
  int bt = blockIdx.x, part = blockIdx.y;
  int tid = threadIdx.x, w = tid >> 6, l = tid & 63;
  const bhalf* A = PT + (size_t)bt*5*16384; // u=0 (af)
  bf8v a8[8];
  #pragma unroll
  for (int kt = 0; kt < 8; ++kt) a8[kt] = ldfrag(A, w*16, kt*32, 256, l);
  const bhalf* Wb; bhalf* dst; int nt0, S;
  if (part < 2) { Wb = WT + W_FAMK; dst = K1B + (size_t)bt*8192;  nt0 = part*4;     S = 128; }
  else          { Wb = WT + W_FAMV; dst = V1B + (size_t)bt*16384; nt0 = (part-2)*4; S = 256; }
  #pragma unroll
  for (int nn = 0; nn < 4; ++nn) {
    int nt = nt0 + nn;
    f4 acc = {0.f,0.f,0.f,0.f};
    #pragma unroll
    for (int kt = 0; kt < 8; ++kt)
      acc = mfma16(a8[kt], ldfrag(Wb, nt*16, kt*32, 256, l), acc);
    #pragma unroll
    for (int reg = 0; reg < 4; ++reg) {
      int p = w*16 + ((l>>4)<<2) + reg;
      dst[(size_t)p*S + nt*16 + (l&15)] = f2b(acc[reg]);
    }
  }
}

// per (bt, part): parts 0-1: vqt; 2-3: vkt (transposed [128][64]); 4-7: vtb quarters
__global__ void __launch_bounds__(256) kv1b(const bhalf* V1B, const bhalf* WT,
                                            bhalf* VQT, bhalf* VKT, bhalf* VTB) {
  int bt = blockIdx.x, part = blockIdx.y;
  int tid = threadIdx.x, w = tid >> 6, l = tid & 63;
  const bhalf* A = V1B + (size_t)bt*16384;
  bf8v a8[8];
  #pragma unroll
  for (int kt = 0; kt < 8; ++kt) a8[kt] = ldfrag(A, w*16, kt*32, 256, l);
  if (part < 4) {
    const bhalf* Wb = WT + ((part < 2) ? W_ARMQ : W_ARMK);
    bhalf* o = ((part < 2) ? VQT : VKT) + (size_t)bt*8192;
    int nt0 = (part & 1) * 4;
    #pragma unroll
    for (int nn = 0; nn < 4; ++nn) {
      int nt = nt0 + nn;
      f4 acc = {0.f,0.f,0.f,0.f};
      #pragma unroll
      for (int kt = 0; kt < 8; ++kt)
        acc = mfma16(a8[kt], ldfrag(Wb, nt*16, kt*32, 256, l), acc);
      #pragma unroll
      for (int reg = 0; reg < 4; ++reg) {
        int p = w*16 + ((l>>4)<<2) + reg;
        int n = nt*16 + (l&15);
        o[(size_t)n*64 + p] = f2b(acc[reg]);   // transposed store
      }
    }
  } else {
    bhalf* ov = VTB + (size_t)bt*16384;
    int nt0 = (part - 4) * 4;
    #pragma unroll
    for (int nn = 0; nn < 4; ++nn) {
      int nt = nt0 + nn;
      f4 acc = {0.f,0.f,0.f,0.f};
      #pragma unroll
      for (int kt = 0; kt < 8; ++kt)
        acc = mfma16(a8[kt], ldfrag(WT + W_ARMV, nt*16, kt*32, 256, l), acc);
      #pragma unroll
      for (int reg = 0; reg < 4; ++reg) {
        int p = w*16 + ((l>>4)<<2) + reg;
        ov[(size_t)p*256 + nt*16 + (l&15)] = f2b(acc[reg]);
      }
    }
  }
}

// per (bt, part): vwt = (vt@epw)^T [256][64], nt quarters
__global__ void __launch_bounds__(256) kv1c(const bhalf* VTB, const bhalf* WT, bhalf* VWT) {
  int bt = blockIdx.x, part = blockIdx.y;
  int tid = threadIdx.x, w = tid >> 6, l = tid & 63;
  const bhalf* A = VTB + (size_t)bt*16384;
  bf8v a8[8];
  #pragma unroll
  for (int kt = 0; kt < 8; ++kt) a8[kt] = ldfrag(A, w*16, kt*32, 256, l);
  bhalf* ow = VWT + (size_t)bt*16384;
  int nt0 = part * 4;
  #pragma unroll
  for (int nn = 0; nn < 4; ++nn) {
    int nt = nt0 + nn;
    f4 acc = {0.f,0.f,0.f,0.f};
    #pragma unroll
    for (int kt = 0; kt < 8; ++kt)
      acc = mfma16(a8[kt], ldfrag(WT + W_EPW, nt*16, kt*32, 256, l), acc);
    #pragma unroll
    for (int reg = 0; reg < 4; ++reg) {
      int p = w*16 + ((l>>4)<<2) + reg;
      ow[(size_t)(nt*16 + (l&15))*64 + p] = f2b(acc[reg]);  // transposed
    }
  }
}

// ---------- stage 1: FAM attention + ARM input projections (column-split PV) ----------
// Same recipe as s2ker: phase-3 PV is column-split across waves (q2/k2: wave w
// owns cols {2w,2w+1}; w2t: cols {4w..4w+3}); B-operands (VQT/VKT/VWT frags)
// load directly from global (L2-hot, shared by the 5 u-blocks of one bt on one
// XCD). P cross-wave via bufP + barrier. bufA is q1-only and wave-private ->
// NO phase-1->2 barrier. W2T written by direct transposed 2B stores (same
// pattern as kv1b/kv1c). LDS 76.5 -> 26.6 KB.
__global__ void __launch_bounds__(256) s1ker(const bhalf* PT, const bhalf* WT,
    const bhalf* K1B, const bhalf* VQT, const bhalf* VKT, const bhalf* VWT,
    bhalf* Q2B, bhalf* K2B, bhalf* W2T)
{
  __shared__ bhalf bufA[64*136];  // q1 staging (17.4 KB), wave-private rows
  __shared__ bhalf bufP[64*72];   // 9.2 KB, cross-wave P
  int orig = blockIdx.x;
  int blk = (orig & 7) * 80 + (orig >> 3);   // bijective XCD grouping
  int bt = blk / 5;
  int tid = threadIdx.x, w = tid >> 6, l = tid & 63;
  const bhalf* Pt = PT + (size_t)blk*16384;
  // phase 1: q1 (M=64, N=128, K=256) -> bufA (own rows)
  {
    bf8v a8[8];
    #pragma unroll
    for (int kt = 0; kt < 8; ++kt) a8[kt] = ldfrag(Pt, w*16, kt*32, 256, l);
    __builtin_amdgcn_s_setprio(1);
    #pragma unroll
    for (int nt = 0; nt < 8; ++nt) {
      f4 acc = {0.f,0.f,0.f,0.f};
      #pragma unroll
      for (int kt = 0; kt < 8; ++kt)
        acc = mfma16(a8[kt], ldfrag(WT + W_FAMQ, nt*16, kt*32, 256, l), acc);
      #pragma unroll
      for (int reg = 0; reg < 4; ++reg)
        bufA[(w*16 + ((l>>4)<<2) + reg)*136 + nt*16 + (l&15)] = f2b(acc[reg]);
    }
    __builtin_amdgcn_s_setprio(0);
  }
  // phase 2 (no barrier: bufA rows are wave-private): scores vs k1, softmax in regs
  float sv[4][4];
  {
    const bhalf* K1 = K1B + (size_t)bt*8192;
    bf8v aq[4];
    #pragma unroll
    for (int kt = 0; kt < 4; ++kt) aq[kt] = ldfrag(bufA, w*16, kt*32, 136, l);
    #pragma unroll
    for (int nt = 0; nt < 4; ++nt) {
      f4 acc = {0.f,0.f,0.f,0.f};
      #pragma unroll
      for (int kt = 0; kt < 4; ++kt)
        acc = mfma16(aq[kt], ldfrag(K1, nt*16, kt*32, 128, l), acc);
      #pragma unroll
      for (int reg = 0; reg < 4; ++reg) sv[nt][reg] = acc[reg] * ATT_SCALE;
    }
  }
  if ((l & 15) > 0) { sv[3][0] = -1e30f; sv[3][1] = -1e30f; sv[3][2] = -1e30f; sv[3][3] = -1e30f; }
  regSoftmax(sv);
  #pragma unroll
  for (int nt = 0; nt < 4; ++nt)
    #pragma unroll
    for (int reg = 0; reg < 4; ++reg)
      bufP[(w*16 + ((l>>4)<<2) + reg)*72 + nt*16 + (l&15)] = f2b(sv[nt][reg]);
  __syncthreads();   // bufP cross-wave
  // phase 3: column-split PVs. A-frags: all 4 row-groups of P.
  bf8v ap0[4], ap1[4];
  #pragma unroll
  for (int g = 0; g < 4; ++g) {
    ap0[g] = ldfrag(bufP, g*16, 0, 72, l);
    ap1[g] = ldfrag(bufP, g*16, 32, 72, l);
  }
  const bhalf* vq = VQT + (size_t)bt*8192;
  const bhalf* vk = VKT + (size_t)bt*8192;
  const bhalf* vw = VWT + (size_t)bt*16384;
  bhalf* q2 = Q2B + (size_t)blk*8192;
  bhalf* k2 = K2B + (size_t)blk*8192;
  bhalf* w2 = W2T + (size_t)blk*16384;
  __builtin_amdgcn_s_setprio(1);
  #pragma unroll
  for (int nn = 0; nn < 2; ++nn) {     // q2 cols nt = 2w+nn
    int nt = w*2 + nn;
    bf8v b0 = ldfrag(vq, nt*16, 0, 64, l);
    bf8v b1 = ldfrag(vq, nt*16, 32, 64, l);
    f4 acc[4];
    #pragma unroll
    for (int g = 0; g < 4; ++g) {
      f4 z = {0.f,0.f,0.f,0.f};
      z = mfma16(ap0[g], b0, z);
      acc[g] = mfma16(ap1[g], b1, z);
    }
    int c = nt*16 + (l & 15);
    #pragma unroll
    for (int g = 0; g < 4; ++g)
      #pragma unroll
      for (int reg = 0; reg < 4; ++reg) {
        int p = g*16 + ((l>>4)<<2) + reg;
        q2[(size_t)p*128 + c] = (p < 49) ? f2b(acc[g][reg]) : (bhalf)0;
      }
  }
  #pragma unroll
  for (int nn = 0; nn < 2; ++nn) {     // k2 cols nt = 2w+nn
    int nt = w*2 + nn;
    bf8v b0 = ldfrag(vk, nt*16, 0, 64, l);
    bf8v b1 = ldfrag(vk, nt*16, 32, 64, l);
    f4 acc[4];
    #pragma unroll
    for (int g = 0; g < 4; ++g) {
      f4 z = {0.f,0.f,0.f,0.f};
      z = mfma16(ap0[g], b0, z);
      acc[g] = mfma16(ap1[g], b1, z);
    }
    int c = nt*16 + (l & 15);
    #pragma unroll
    for (int g = 0; g < 4; ++g)
      #pragma unroll
      for (int reg = 0; reg < 4; ++reg) {
        int p = g*16 + ((l>>4)<<2) + reg;
        k2[(size_t)p*128 + c] = (p < 49) ? f2b(acc[g][reg]) : (bhalf)0;
      }
  }
  #pragma unroll
  for (int nn = 0; nn < 4; ++nn) {     // w2t cols nt = 4w+nn, transposed store
    int nt = w*4 + nn;
    bf8v b0 = ldfrag(vw, nt*16, 0, 64, l);
    bf8v b1 = ldfrag(vw, nt*16, 32, 64, l);
    f4 acc[4];
    #pragma unroll
    for (int g = 0; g < 4; ++g) {
      f4 z = {0.f,0.f,0.f,0.f};
      z = mfma16(ap0[g], b0, z);
      acc[g] = mfma16(ap1[g], b1, z);
    }
    int c = nt*16 + (l & 15);
    #pragma unroll
    for (int g = 0; g < 4; ++g)
      #pragma unroll
      for (int reg = 0; reg < 4; ++reg) {
        int p = g*16 + ((l>>4)<<2) + reg;
        w2[(size_t)c*64 + p] = (p < 49) ? f2b(acc[g][reg]) : (bhalf)0;
      }
  }
  __builtin_amdgcn_s_setprio(0);
}

// ---------- stage 2: ARM attention + edge stats (column-split PV, V in registers) ----------
__global__ void __launch_bounds__(256) s2ker(const bhalf* Q2B, const bhalf* K2B, const bhalf* W2T,
    const float* epb, float* hws, float* gs1, float* gs2)
{
  __shared__ bhalf Kl[64*128];    // 16 KB, swizzled rows of 256 B
  __shared__ bhalf bufP[64*72];   // 9 KB, full P (cross-wave)
  __shared__ float redH[256];     // 1 KB, per-wave disjoint columns
  __shared__ float redS[8];
  int orig = blockIdx.x;
  int blk = (orig & 7) * 400 + (orig >> 3);   // 3200 = 8*400, bijective XCD grouping
  int e = blk % 25, bt = blk / 25, b = bt >> 4, t = bt & 15;
  int i = e / 5, j = e % 5;
  int tid = threadIdx.x, w = tid >> 6, l = tid & 63;
  const bhalf* K = K2B + (size_t)(bt*5 + i)*8192;
  const bhalf* V = W2T + (size_t)(bt*5 + i)*16384;
  const bhalf* Q = Q2B + (size_t)(bt*5 + j)*8192;
  // prefetch Q fragments (independent of LDS staging)
  bf8v aq[4];
  #pragma unroll
  for (int kt = 0; kt < 4; ++kt) aq[kt] = ldfrag(Q, w*16, kt*32, 128, l);
  // ---- stage K (16 KB): coalesced global read, swizzled LDS write ----
  {
    const char* gk = reinterpret_cast<const char*>(K);
    char* lk = reinterpret_cast<char*>(Kl);
    #pragma unroll
    for (int c = 0; c < 4; ++c) {
      int x = (c*256 + tid) << 4;                 // K: row = x>>8 (256 B rows)
      float4 val = *reinterpret_cast<const float4*>(gk + x);
      *reinterpret_cast<float4*>(lk + (x ^ (((x >> 8) & 7) << 4))) = val;
    }
  }
  __syncthreads();
  // QK^T from LDS + in-register softmax
  float sv[4][4];
  __builtin_amdgcn_s_setprio(1);
  #pragma unroll
  for (int nt = 0; nt < 4; ++nt) {
    f4 acc = {0.f,0.f,0.f,0.f};
    #pragma unroll
    for (int kt = 0; kt < 4; ++kt)
      acc = mfma16(aq[kt], ldswz(Kl, nt*16 + (l & 15), kt*64 + ((l >> 4) << 4), 256), acc);
    #pragma unroll
    for (int reg = 0; reg < 4; ++reg) sv[nt][reg] = acc[reg] * ATT_SCALE;
  }
  __builtin_amdgcn_s_setprio(0);
  if ((l & 15) > 0) { sv[3][0] = -1e30f; sv[3][1] = -1e30f; sv[3][2] = -1e30f; sv[3][3] = -1e30f; }
  regSoftmax(sv);
  // write own P rows to bufP
  #pragma unroll
  for (int nt = 0; nt < 4; ++nt)
    #pragma unroll
    for (int reg = 0; reg < 4; ++reg)
      bufP[(w*16 + ((l>>4)<<2) + reg)*72 + nt*16 + (l&15)] = f2b(sv[nt][reg]);
  // V fragments for this wave's column slice (rows [w*64, w*64+64) of W2T tile)
  bf8v vf0[4], vf1[4];
  #pragma unroll
  for (int nn = 0; nn < 4; ++nn) {
    vf0[nn] = ldfrag(V, (w*4 + nn)*16, 0, 64, l);
    vf1[nn] = ldfrag(V, (w*4 + nn)*16, 32, 64, l);
  }
  __syncthreads();   // bufP complete (cross-wave read next)
  // A-fragments: all 4 row-groups of P
  bf8v ap0[4], ap1[4];
  #pragma unroll
  for (int g = 0; g < 4; ++g) {
    ap0[g] = ldfrag(bufP, g*16, 0, 72, l);
    ap1[g] = ldfrag(bufP, g*16, 32, 72, l);
  }
  float sqa = 0.f;
  __builtin_amdgcn_s_setprio(1);
  #pragma unroll
  for (int nn = 0; nn < 4; ++nn) {
    f4 acc[4];
    #pragma unroll
    for (int g = 0; g < 4; ++g) {
      f4 z = {0.f,0.f,0.f,0.f};
      z = mfma16(ap0[g], vf0[nn], z);
      acc[g] = mfma16(ap1[g], vf1[nn], z);
    }
    int c = ((w*4 + nn) << 4) + (l & 15);
    float bias = epb[c];
    float hw = 0.f;
    #pragma unroll
    for (int g = 0; g < 4; ++g) {
      #pragma unroll
      for (int reg = 0; reg < 4; ++reg) {
        int p = g*16 + ((l>>4)<<2) + reg;
        if (p < 49) { float v = acc[g][reg] + bias; hw += v; sqa += v*v; }
      }
    }
    hw += __shfl_xor(hw, 16);
    hw += __shfl_xor(hw, 32);
    if ((l >> 4) == 0) redH[c] = hw;   // per-wave disjoint c
  }
  __builtin_amdgcn_s_setprio(0);
  __syncthreads();
  float hwtot = redH[tid];
  hws[(((size_t)(b*25+e)*16) + t)*256 + tid] = hwtot;
  reduce2Atomic(hwtot, sqa, gs1 + e, gs2 + e, redS);
}

// ---------- GNN back-half (verified fusions, no grid sync) ----------

// projections, 720 blocks x 8 rows. Edge-src BN applied on the fly when bnfly=1
// (L0: src=HWS, EDG = scl[e]*hws + off[e] folded into the FMA chain).
__global__ void __launch_bounds__(256) gnnProj(const float* X, const float* ESRC,
    const float* gs1, const float* gs2, const float* gg, const float* gb, int bnfly,
    const float* Wa, const float* Wb, const float* Wu, const float* Wv, const float* We,
    float* xA, float* xB, float* xU, float* xV, float* eE) {
  int blk = blockIdx.x, tid = threadIdx.x;
  const float* src; const float* W; float* dst; int r0; int isE = 0;
  if (blk < 320) {
    int m = blk / 80; r0 = (blk % 80) * 8;
    src = X;
    W   = (m==0)?Wa:(m==1)?Wb:(m==2)?Wu:Wv;
    dst = (m==0)?xA:(m==1)?xB:(m==2)?xU:xV;
  } else { r0 = (blk-320)*8; src = ESRC; W = We; dst = eE; isE = 1; }
  float scl[8], off[8];
  #pragma unroll
  for (int r = 0; r < 8; ++r) { scl[r] = 1.f; off[r] = 0.f; }
  if (isE && bnfly) {
    constexpr float invCnt = 1.f/1605632.f;
    #pragma unroll
    for (int r = 0; r < 8; ++r) {
      int e = ((r0 + r) >> 4) % 25;
      float m = gs1[e]*invCnt;
      float var = gs2[e]*invCnt - m*m;
      float rstd = rsqrtf(var + 1e-5f);
      float g = gg[e]*rstd;
      scl[r] = g * (1.f/49.f);
      off[r] = gb[e] - g*m;
    }
  }
  float acc[8];
  #pragma unroll
  for (int r = 0; r < 8; ++r) acc[r] = 0.f;
  for (int c = 0; c < 256; c += 4) {
    float w0 = W[(size_t)(c+0)*256 + tid];
    float w1 = W[(size_t)(c+1)*256 + tid];
    float w2 = W[(size_t)(c+2)*256 + tid];
    float w3 = W[(size_t)(c+3)*256 + tid];
    #pragma unroll
    for (int r = 0; r < 8; ++r) {
      float4 a = *reinterpret_cast<const float4*>(&src[(size_t)(r0+r)*256 + c]);
      float ax = fmaf(a.x, scl[r], off[r]);
      float ay = fmaf(a.y, scl[r], off[r]);
      float az = fmaf(a.z, scl[r], off[r]);
      float aw = fmaf(a.w, scl[r], off[r]);
      acc[r] += ax*w0 + ay*w1 + az*w2 + aw*w3;
    }
  }
  #pragma unroll
  for (int r = 0; r < 8; ++r) dst[(size_t)(r0+r)*256 + tid] = acc[r];
}

__global__ void __launch_bounds__(256) g2a(const float* xA, const float* xB, const float* eE,
                                           float* ET, float* s1, float* s2) {
  __shared__ float red[8];
  int blk = blockIdx.x, tid = threadIdx.x;
  int b = blk / 400, e = (blk >> 4) % 25, t = blk & 15;
  int i = e / 5, j = e % 5;
  size_t ni = ((size_t)(b*5+i)*16 + t)*256 + tid;
  size_t nj = ((size_t)(b*5+j)*16 + t)*256 + tid;
  size_t ee = (size_t)blk*256 + tid;
  float v = xA[ni] + xB[nj] + eE[ee];
  ET[ee] = v;
  reduce2Atomic(v, v*v, s1 + e, s2 + e, red);
}

// fused g2b+g3a. Block (b,i,t) owns edges e=i*5+j. layer==0: base EDG
// recomputed from HWS via gem-BN-fly, final EDG written. layer==1: base from
// EDG buffer; EDG NOT written; finker edge output computed in-register -> out.
__global__ void __launch_bounds__(256) g2bg3a(const float* ET, const float* HWS, const float* EDGin,
    float* EDGout, const float* xV, const float* xU, float* XN,
    const float* gs1, const float* gs2, const float* gemg, const float* gemb,
    const float* bg, const float* bb2, const float* es1, const float* es2,
    float* ns1, float* ns2, const float* efw, const float* efb, float* out, int layer) {
  __shared__ float red[8];
  int blk = blockIdx.x, tid = threadIdx.x;
  int b = blk / 80, i = (blk >> 4) % 5, t = blk & 15;
  constexpr float inv32k = 1.f/32768.f;
  constexpr float invCnt = 1.f/1605632.f;
  float ssum = 0.f, exv[5], xvv[5];
  #pragma unroll
  for (int j = 0; j < 5; ++j) {
    int e = i*5 + j;
    size_t ee = ((size_t)(b*25 + e)*16 + t)*256 + tid;
    float m = es1[e]*inv32k;
    float var = es2[e]*inv32k - m*m;
    float rstd = rsqrtf(var + 1e-5f);
    float v = bg[e]*((ET[ee]-m)*rstd) + bb2[e];
    if (v != v) v = 0.f;
    float base;
    if (layer == 0) {
      float gm = gs1[e]*invCnt;
      float gvar = gs2[e]*invCnt - gm*gm;
      float gr = rsqrtf(gvar + 1e-5f);
      base = gemg[e]*((HWS[ee]*(1.f/49.f) - gm)*gr) + gemb[e];
    } else {
      base = EDGin[ee];
    }
    float edg = base + fmaxf(v, 0.f);
    if (layer == 0) {
      EDGout[ee] = edg;
    } else {
      // fused finker edge part
      float vv = edg * efw[tid];
      #pragma unroll
      for (int off = 32; off; off >>= 1) vv += __shfl_down(vv, off);
      if ((tid & 63) == 0) red[tid >> 6] = vv;
      __syncthreads();
      if (tid == 0) out[640 + (size_t)(b*25 + e)*16 + t] = red[0]+red[1]+red[2]+red[3] + efb[0];
      __syncthreads();
    }
    float sg = 1.f/(1.f + __expf(-edg));
    exv[j] = __expf(sg);
    ssum += exv[j];
    xvv[j] = xV[((size_t)(b*5+j)*16 + t)*256 + tid];
  }
  float agg = 0.f;
  #pragma unroll
  for (int j = 0; j < 5; ++j) agg += exv[j]*xvv[j];
  agg *= 0.2f/ssum;
  float xn = xU[(size_t)blk*256 + tid] + agg;
  XN[(size_t)blk*256 + tid] = xn;
  reduce2Atomic(xn, xn*xn, ns1 + i, ns2 + i, red);
}

// L0 node BN + residual relu (writes FV for the next layer)
__global__ void __launch_bounds__(256) g3b(const float* XN, float* X, const float* g, const float* bb,
                                           const float* s1, const float* s2, int mask) {
  int blk = blockIdx.x, tid = threadIdx.x;
  int i = (blk >> 4) % 5;
  size_t ni = (size_t)blk*256 + tid;
  constexpr float invCnt = 1.f/32768.f;
  float m = s1[i]*invCnt;
  float var = s2[i]*invCnt - m*m;
  float rstd = rsqrtf(var + 1e-5f);
  float v = g[i]*((XN[ni]-m)*rstd) + bb[i];
  if (mask && v != v) v = 0.f;
  X[ni] = fmaxf(X[ni] + v, 0.f);
}

// L1 node BN + residual relu fused with finker node part (FV never written)
__global__ void __launch_bounds__(256) g3bfin(const float* XN, const float* FV,
    const float* g, const float* bb, const float* s1, const float* s2,
    const float* sc, float* out) {
  __shared__ float red[12];
  int blk = blockIdx.x, tid = threadIdx.x;
  int i = (blk >> 4) % 5;
  size_t ni = (size_t)blk*256 + tid;
  constexpr float inv32k = 1.f/32768.f;
  float m = s1[i]*inv32k;
  float var = s2[i]*inv32k - m*m;
  float rstd = rsqrtf(var + 1e-5f);
  float v = g[i]*((XN[ni]-m)*rstd) + bb[i];   // L1: no NaN mask
  float x = fmaxf(FV[ni] + v, 0.f);
  float s = fmaxf(sc[i*256 + tid], 0.f);
  float xx = x*x, ss = s*s, xs = x*s;
  #pragma unroll
  for (int off = 32; off; off >>= 1) {
    xx += __shfl_down(xx, off); ss += __shfl_down(ss, off); xs += __shfl_down(xs, off);
  }
  if ((tid & 63) == 0) { int w = tid >> 6; red[w*3] = xx; red[w*3+1] = ss; red[w*3+2] = xs; }
  __syncthreads();
  if (tid == 0) {
    float sxx = red[0]+red[3]+red[6]+red[9];
    float sss = red[1]+red[4]+red[7]+red[10];
    float sxs = red[2]+red[5]+red[8]+red[11];
    float nx = fmaxf(sqrtf(sxx), 1e-12f);
    float ns = fmaxf(sqrtf(sss), 1e-12f);
    out[blk] = sxs / (nx * ns);
  }
}

// ---------- host ----------

extern "C" void kernel_launch(void* const* d_in, const int* in_sizes, int n_in,
                              void* d_out, int out_size, void* d_ws, size_t ws_size,
                              hipStream_t stream) {
  (void)in_sizes; (void)n_in; (void)out_size; (void)ws_size;
  const float* af    = (const float*)d_in[0];
  const float* ef    = (const float*)d_in[1];
  const float* gfm   = (const float*)d_in[2];
  const float* attf  = (const float*)d_in[3];
  const float* sfm   = (const float*)d_in[4];
  const float* fam_q = (const float*)d_in[5];
  const float* fam_k = (const float*)d_in[6];
  const float* fam_v = (const float*)d_in[7];
  const float* arm_q = (const float*)d_in[8];
  const float* arm_k = (const float*)d_in[9];
  const float* arm_v = (const float*)d_in[10];
  const float* epw   = (const float*)d_in[11];
  const float* epb   = (const float*)d_in[12];
  const float* gemg  = (const float*)d_in[13];
  const float* gemb  = (const float*)d_in[14];
  const float* Us[2]   = {(const float*)d_in[15], (const float*)d_in[20]};
  const float* Vs[2]   = {(const float*)d_in[16], (const float*)d_in[21]};
  const float* As[2]   = {(const float*)d_in[17], (const float*)d_in[22]};
  const float* Bs[2]   = {(const float*)d_in[18], (const float*)d_in[23]};
  const float* Es[2]   = {(const float*)d_in[19], (const float*)d_in[24]};
  const float* bnvg[2] = {(const float*)d_in[25], (const float*)d_in[29]};
  const float* bnvb[2] = {(const float*)d_in[26], (const float*)d_in[30]};
  const float* bneg[2] = {(const float*)d_in[27], (const float*)d_in[31]};
  const float* bneb[2] = {(const float*)d_in[28], (const float*)d_in[32]};
  const float* scp  = (const float*)d_in[33];
  const float* efw  = (const float*)d_in[34];
  const float* efb  = (const float*)d_in[35];

  char* ws = (char*)d_ws;
  bhalf* PT  = (bhalf*)(ws + O_PT);
  bhalf* WTS = (bhalf*)(ws + O_WTS);
  bhalf* K1B = (bhalf*)(ws + O_K1B);
  bhalf* V1B = (bhalf*)(ws + O_V1B);
  bhalf* VQT = (bhalf*)(ws + O_VQT);
  bhalf* VKT = (bhalf*)(ws + O_VKT);
  bhalf* VTB = (bhalf*)(ws + O_VTB);
  bhalf* VWT = (bhalf*)(ws + O_VWT);
  bhalf* Q2B = (bhalf*)(ws + O_Q2B);
  bhalf* K2B = (bhalf*)(ws + O_K2B);
  bhalf* W2T = (bhalf*)(ws + O_W2T);
  float* FV  = (float*)(ws + O_FV);
  float* HWS = (float*)(ws + O_HWS);
  float* EDG = (float*)(ws + O_EDG);
  float* st  = (float*)(ws + O_ST);
  float* XA  = (float*)(ws + O_XA);
  float* XB  = (float*)(ws + O_XB);
  float* XU  = (float*)(ws + O_XU);
  float* XV  = (float*)(ws + O_XV);
  float* EE  = (float*)(ws + O_EE);
  float* ET  = (float*)(ws + O_ET);
  float* XN  = (float*)(ws + O_XN);

  hipMemsetAsync(st, 0, 256*sizeof(float), stream);

  prepAll<<<1920, TPB, 0, stream>>>(fam_q, fam_k, fam_v, arm_q, arm_k, arm_v, epw, WTS,
                                    af, ef, gfm, attf, sfm, PT, FV);
  kv1a<<<dim3(128, 6), TPB, 0, stream>>>(PT, WTS, K1B, V1B);
  kv1b<<<dim3(128, 8), TPB, 0, stream>>>(V1B, WTS, VQT, VKT, VTB);
  kv1c<<<dim3(128, 4), TPB, 0, stream>>>(VTB, WTS, VWT);
  s1ker<<<640, TPB, 0, stream>>>(PT, WTS, K1B, VQT, VKT, VWT, Q2B, K2B, W2T);
  s2ker<<<3200, TPB, 0, stream>>>(Q2B, K2B, W2T, epb, HWS, st+0, st+25);

  float* out = (float*)d_out;
  for (int L = 0; L < 2; ++L) {
    float* es1 = st + 64 + L*64;
    float* es2 = es1 + 25;
    float* ns1 = es1 + 50;
    float* ns2 = es1 + 55;
    gnnProj<<<720, TPB, 0, stream>>>(FV, (L == 0) ? HWS : EDG, st+0, st+25, gemg, gemb,
                                     (L == 0) ? 1 : 0,
                                     As[L], Bs[L], Us[L], Vs[L], Es[L],
                                     XA, XB, XU, XV, EE);
    g2a<<<3200, TPB, 0, stream>>>(XA, XB, EE, ET, es1, es2);
    g2bg3a<<<640, TPB, 0, stream>>>(ET, HWS, EDG, EDG, XV, XU, XN,
                                    st+0, st+25, gemg, gemb,
                                    bneg[L], bneb[L], es1, es2, ns1, ns2,
                                    efw, efb, out, L);
    if (L == 0)
      g3b<<<640, TPB, 0, stream>>>(XN, FV, bnvg[0], bnvb[0], ns1, ns2, 1);
    else
      g3bfin<<<640, TPB, 0, stream>>>(XN, FV, bnvg[1], bnvb[1], ns1, ns2, scp, out);
  }
}

// Round 10
// 371.661 us; speedup vs baseline: 5.9903x; 1.0118x over previous
//
#include <hip/hip_runtime.h>

#define DEV __device__ __forceinline__

typedef unsigned short bhalf;
typedef __attribute__((ext_vector_type(8))) short bf8v;
typedef __attribute__((ext_vector_type(4))) float f4;

namespace {
constexpr int TPB = 256;
constexpr float ATT_SCALE = 0.08838834764831845f; // 1/sqrt(128)

// ---- workspace byte offsets ----
constexpr size_t O_PT  = 0;          // bf16 [640][64][256]  modalities, zero-pad rows
constexpr size_t O_WTS = 20971520;   // bf16 transposed weights (see W_* below)
constexpr size_t O_K1B = 21626880;   // bf16 [128][64][128]
constexpr size_t O_FW  = 23724032;   // bf16 fused weights: VQ[128][256], VK[128][256], VW[256][256]
constexpr size_t O_VQT = 27918336;   // bf16 [128][128][64]  (v1@arm_q)^T
constexpr size_t O_VKT = 30015488;   // bf16 [128][128][64]
constexpr size_t O_G   = 32112640;   // f32  [256][256]  arm_v@epw
constexpr size_t O_VWT = 36306944;   // bf16 [128][256][64]  (vt@epw)^T
constexpr size_t O_Q2B = 40501248;   // bf16 [640][64][128]
constexpr size_t O_K2B = 50987008;   // bf16 [640][64][128]
constexpr size_t O_W2T = 61472768;   // bf16 [640][256][64]
constexpr size_t O_FV  = 82444288;   // f32  [640][256]  node features X
constexpr size_t O_HWS = 83099648;   // f32  [3200][256]
constexpr size_t O_EDG = 86376448;   // f32  [3200][256]
constexpr size_t O_ST  = 89653248;   // f32  [256] stats
constexpr size_t O_XA  = 89654272;
constexpr size_t O_XB  = 90309632;
constexpr size_t O_XU  = 90964992;
constexpr size_t O_XV  = 91620352;
constexpr size_t O_EE  = 92275712;
constexpr size_t O_ET  = 95552512;
constexpr size_t O_XN  = 98829312;

// WTS element offsets (bf16 elems), all stored as Wt[n][k=256]
constexpr size_t W_FAMQ = 0, W_FAMK = 32768, W_ARMQ = 65536, W_ARMK = 98304,
                 W_FAMV = 131072, W_ARMV = 196608, W_EPW = 262144;
// FW element offsets
constexpr size_t FW_VQ = 0, FW_VK = 32768, FW_VW = 65536;
} // namespace

// ---------- helpers ----------

DEV bhalf f2b(float f) {
  unsigned u = __float_as_uint(f);
  return (bhalf)((u + 0x7FFFu + ((u >> 16) & 1u)) >> 16);
}

DEV f4 mfma16(bf8v a, bf8v b, f4 c) {
  return __builtin_amdgcn_mfma_f32_16x16x32_bf16(a, b, c, 0, 0, 0);
}

// fragment load: lane l reads row (r0 + (l&15)), 8 contiguous k at k0 + (l>>4)*8
DEV bf8v ldfrag(const bhalf* base, int r0, int k0, int S, int l) {
  return *reinterpret_cast<const bf8v*>(base + (size_t)(r0 + (l & 15)) * S + k0 + ((l >> 4) << 3));
}

// swizzled LDS fragment load: byte = row*stride + koffB, XOR'd with ((row&7)<<4)
DEV bf8v ldswz(const bhalf* base, int row, int koffB, int strideB) {
  int byte = row * strideB + koffB;
  byte ^= ((row & 7) << 4);
  return *reinterpret_cast<const bf8v*>(reinterpret_cast<const char*>(base) + byte);
}

// in-register row softmax: sv[nt][reg], row per reg spans cols nt*16+(l&15) across 16 lanes
DEV void regSoftmax(float sv[4][4]) {
  #pragma unroll
  for (int reg = 0; reg < 4; ++reg) {
    float m = fmaxf(fmaxf(sv[0][reg], sv[1][reg]), fmaxf(sv[2][reg], sv[3][reg]));
    #pragma unroll
    for (int off = 1; off <= 8; off <<= 1) m = fmaxf(m, __shfl_xor(m, off));
    float s = 0.f;
    #pragma unroll
    for (int nt = 0; nt < 4; ++nt) { float e = __expf(sv[nt][reg] - m); sv[nt][reg] = e; s += e; }
    #pragma unroll
    for (int off = 1; off <= 8; off <<= 1) s += __shfl_xor(s, off);
    float inv = 1.f / s;
    #pragma unroll
    for (int nt = 0; nt < 4; ++nt) sv[nt][reg] *= inv;
  }
}

DEV void reduce2Atomic(float a, float b, float* ga, float* gb, float* red) {
  #pragma unroll
  for (int off = 32; off; off >>= 1) { a += __shfl_down(a, off); b += __shfl_down(b, off); }
  if ((threadIdx.x & 63) == 0) { int w = threadIdx.x >> 6; red[w*2] = a; red[w*2+1] = b; }
  __syncthreads();
  if (threadIdx.x == 0) {
    atomicAdd(ga, red[0]+red[2]+red[4]+red[6]);
    atomicAdd(gb, red[1]+red[3]+red[5]+red[7]);
  }
  __syncthreads();
}

// ---------- prep kernel (wprep + modprep + G=arm_v@epw merged) ----------

__global__ void __launch_bounds__(256) prepAll(const float* fq, const float* fk, const float* fv,
                                               const float* aq, const float* ak, const float* av,
                                               const float* ep, bhalf* WT,
                                               const float* af, const float* ef, const float* gf,
                                               const float* attf, const float* sf,
                                               bhalf* PT, float* FV, float* G) {
  __shared__ float lb[49*260];
  int tid = threadIdx.x;
  if (blockIdx.x < 1280) {
    // ---- wprep: transpose 7 weight matrices to bf16 Wt[n][256] ----
    int blk = blockIdx.x;
    const float* src; bhalf* dst; int N, n;
    if (blk < 512) {
      int m = blk >> 7; n = blk & 127; N = 128;
      src = (m==0)?fq:(m==1)?fk:(m==2)?aq:ak;
      dst = WT + (size_t)m*32768;
    } else {
      int r = blk - 512; int m = r >> 8; n = r & 255; N = 256;
      src = (m==0)?fv:(m==1)?av:ep;
      dst = WT + 131072 + (size_t)m*65536;
    }
    dst[(size_t)n*256 + tid] = f2b(src[(size_t)tid*N + n]);
  } else if (blockIdx.x < 1920) {
    // ---- modprep: per (bt,u) modality transpose + fv means ----
    int blk = blockIdx.x - 1280;
    int u = blk % 5, bt = blk / 5, b = bt >> 4, t = bt & 15;
    const float* src = (u==0)?af:(u==1)?ef:(u==2)?gf:(u==3)?attf:sf;
    src += ((size_t)b*256*16 + t)*49;
    for (int o = tid; o < 49*256; o += TPB) {
      int c = o / 49, p = o % 49;
      lb[p*260 + c] = src[(size_t)c*784 + p];
    }
    __syncthreads();
    bhalf* pt = PT + (size_t)blk*16384;
    for (int p = 0; p < 64; ++p)
      pt[p*256 + tid] = (p < 49) ? f2b(lb[p*260 + tid]) : (bhalf)0;
    float s = 0.f;
    for (int p = 0; p < 49; ++p) s += lb[p*260 + tid];
    FV[(((size_t)(b*5+u)*16) + t)*256 + tid] = s * (1.f/49.f);
  } else {
    // ---- G = arm_v @ epw (f32), row c per block ----
    int c = blockIdx.x - 1920;
    const float* ar = av + (size_t)c*256;
    float acc = 0.f;
    for (int d = 0; d < 256; ++d)
      acc = fmaf(ar[d], ep[(size_t)d*256 + tid], acc);
    G[(size_t)c*256 + tid] = acc;
  }
}

// fused weights: W_VQ[n][k]=sum_c famv[k][c]*armq[c][n]; W_VK likewise; W_VW uses G.
// block = k (famv row broadcast via scalar loads); reads coalesced; 2B stores scattered (cheap).
__global__ void __launch_bounds__(256) wf2(const float* fv, const float* aq, const float* ak,
                                           const float* G, bhalf* FW) {
  int blk = blockIdx.x, tid = threadIdx.x;
  if (blk < 256) {
    int k = blk;
    if (tid < 128) {
      float a1 = 0.f, a2 = 0.f;
      for (int c = 0; c < 256; ++c) {
        float f = fv[(size_t)k*256 + c];
        a1 = fmaf(f, aq[(size_t)c*128 + tid], a1);
        a2 = fmaf(f, ak[(size_t)c*128 + tid], a2);
      }
      FW[FW_VQ + (size_t)tid*256 + k] = f2b(a1);
      FW[FW_VK + (size_t)tid*256 + k] = f2b(a2);
    }
  } else {
    int k = blk - 256;
    float a = 0.f;
    for (int c = 0; c < 256; ++c)
      a = fmaf(fv[(size_t)k*256 + c], G[(size_t)c*256 + tid], a);
    FW[FW_VW + (size_t)tid*256 + k] = f2b(a);
  }
}

// ---------- MFMA chain collapsed to ONE kernel: everything from Paf ----------
// per (bt, part): parts 0-1: k1 = Paf@fam_k (nt quarters);
// parts 2-5: vqt/vkt = (Paf@FW_VQ/VK)^T [128][64]; parts 6-9: vwt = (Paf@FW_VW)^T [256][64].
__global__ void __launch_bounds__(256) kv1(const bhalf* PT, const bhalf* WT, const bhalf* FW,
                                           bhalf* K1B, bhalf* VQT, bhalf* VKT, bhalf* VWT) {
  int bt = blockIdx.x, part = blockIdx.y;
  int tid = threadIdx.x, w = tid >> 6, l = tid & 63;
  const bhalf* A = PT + (size_t)bt*5*16384; // u=0 (af)
  bf8v a8[8];
  #pragma unroll
  for (int kt = 0; kt < 8; ++kt) a8[kt] = ldfrag(A, w*16, kt*32, 256, l);
  if (part < 2) {
    bhalf* dst = K1B + (size_t)bt*8192;
    int nt0 = part*4;
    #pragma unroll
    for (int nn = 0; nn < 4; ++nn) {
      int nt = nt0 + nn;
      f4 acc = {0.f,0.f,0.f,0.f};
      #pragma unroll
      for (int kt = 0; kt < 8; ++kt)
        acc = mfma16(a8[kt], ldfrag(WT + W_FAMK, nt*16, kt*32, 256, l), acc);
      #pragma unroll
      for (int reg = 0; reg < 4; ++reg) {
        int p = w*16 + ((l>>4)<<2) + reg;
        dst[(size_t)p*128 + nt*16 + (l&15)] = f2b(acc[reg]);
      }
    }
  } else if (part < 6) {
    int which = (part - 2) >> 1;
    const bhalf* Wb = FW + ((which == 0) ? FW_VQ : FW_VK);
    bhalf* o = ((which == 0) ? VQT : VKT) + (size_t)bt*8192;
    int nt0 = ((part - 2) & 1) * 4;
    #pragma unroll
    for (int nn = 0; nn < 4; ++nn) {
      int nt = nt0 + nn;
      f4 acc = {0.f,0.f,0.f,0.f};
      #pragma unroll
      for (int kt = 0; kt < 8; ++kt)
        acc = mfma16(a8[kt], ldfrag(Wb, nt*16, kt*32, 256, l), acc);
      #pragma unroll
      for (int reg = 0; reg < 4; ++reg) {
        int p = w*16 + ((l>>4)<<2) + reg;
        int n = nt*16 + (l&15);
        o[(size_t)n*64 + p] = f2b(acc[reg]);   // transposed store
      }
    }
  } else {
    bhalf* ow = VWT + (size_t)bt*16384;
    int nt0 = (part - 6) * 4;
    #pragma unroll
    for (int nn = 0; nn < 4; ++nn) {
      int nt = nt0 + nn;
      f4 acc = {0.f,0.f,0.f,0.f};
      #pragma unroll
      for (int kt = 0; kt < 8; ++kt)
        acc = mfma16(a8[kt], ldfrag(FW + FW_VW, nt*16, kt*32, 256, l), acc);
      #pragma unroll
      for (int reg = 0; reg < 4; ++reg) {
        int p = w*16 + ((l>>4)<<2) + reg;
        ow[(size_t)(nt*16 + (l&15))*64 + p] = f2b(acc[reg]);  // transposed
      }
    }
  }
}

// ---------- stage 1: FAM attention + ARM input projections (column-split PV) ----------
__global__ void __launch_bounds__(256) s1ker(const bhalf* PT, const bhalf* WT,
    const bhalf* K1B, const bhalf* VQT, const bhalf* VKT, const bhalf* VWT,
    bhalf* Q2B, bhalf* K2B, bhalf* W2T)
{
  __shared__ bhalf bufA[64*136];  // q1 staging (17.4 KB), wave-private rows
  __shared__ bhalf bufP[64*72];   // 9.2 KB, cross-wave P
  int orig = blockIdx.x;
  int blk = (orig & 7) * 80 + (orig >> 3);   // bijective XCD grouping
  int bt = blk / 5;
  int tid = threadIdx.x, w = tid >> 6, l = tid & 63;
  const bhalf* Pt = PT + (size_t)blk*16384;
  // phase 1: q1 (M=64, N=128, K=256) -> bufA (own rows)
  {
    bf8v a8[8];
    #pragma unroll
    for (int kt = 0; kt < 8; ++kt) a8[kt] = ldfrag(Pt, w*16, kt*32, 256, l);
    __builtin_amdgcn_s_setprio(1);
    #pragma unroll
    for (int nt = 0; nt < 8; ++nt) {
      f4 acc = {0.f,0.f,0.f,0.f};
      #pragma unroll
      for (int kt = 0; kt < 8; ++kt)
        acc = mfma16(a8[kt], ldfrag(WT + W_FAMQ, nt*16, kt*32, 256, l), acc);
      #pragma unroll
      for (int reg = 0; reg < 4; ++reg)
        bufA[(w*16 + ((l>>4)<<2) + reg)*136 + nt*16 + (l&15)] = f2b(acc[reg]);
    }
    __builtin_amdgcn_s_setprio(0);
  }
  // phase 2 (no barrier: bufA rows are wave-private): scores vs k1, softmax in regs
  float sv[4][4];
  {
    const bhalf* K1 = K1B + (size_t)bt*8192;
    bf8v aq[4];
    #pragma unroll
    for (int kt = 0; kt < 4; ++kt) aq[kt] = ldfrag(bufA, w*16, kt*32, 136, l);
    #pragma unroll
    for (int nt = 0; nt < 4; ++nt) {
      f4 acc = {0.f,0.f,0.f,0.f};
      #pragma unroll
      for (int kt = 0; kt < 4; ++kt)
        acc = mfma16(aq[kt], ldfrag(K1, nt*16, kt*32, 128, l), acc);
      #pragma unroll
      for (int reg = 0; reg < 4; ++reg) sv[nt][reg] = acc[reg] * ATT_SCALE;
    }
  }
  if ((l & 15) > 0) { sv[3][0] = -1e30f; sv[3][1] = -1e30f; sv[3][2] = -1e30f; sv[3][3] = -1e30f; }
  regSoftmax(sv);
  #pragma unroll
  for (int nt = 0; nt < 4; ++nt)
    #pragma unroll
    for (int reg = 0; reg < 4; ++reg)
      bufP[(w*16 + ((l>>4)<<2) + reg)*72 + nt*16 + (l&15)] = f2b(sv[nt][reg]);
  __syncthreads();   // bufP cross-wave
  // phase 3: column-split PVs. A-frags: all 4 row-groups of P.
  bf8v ap0[4], ap1[4];
  #pragma unroll
  for (int g = 0; g < 4; ++g) {
    ap0[g] = ldfrag(bufP, g*16, 0, 72, l);
    ap1[g] = ldfrag(bufP, g*16, 32, 72, l);
  }
  const bhalf* vq = VQT + (size_t)bt*8192;
  const bhalf* vk = VKT + (size_t)bt*8192;
  const bhalf* vw = VWT + (size_t)bt*16384;
  bhalf* q2 = Q2B + (size_t)blk*8192;
  bhalf* k2 = K2B + (size_t)blk*8192;
  bhalf* w2 = W2T + (size_t)blk*16384;
  __builtin_amdgcn_s_setprio(1);
  #pragma unroll
  for (int nn = 0; nn < 2; ++nn) {     // q2 cols nt = 2w+nn
    int nt = w*2 + nn;
    bf8v b0 = ldfrag(vq, nt*16, 0, 64, l);
    bf8v b1 = ldfrag(vq, nt*16, 32, 64, l);
    f4 acc[4];
    #pragma unroll
    for (int g = 0; g < 4; ++g) {
      f4 z = {0.f,0.f,0.f,0.f};
      z = mfma16(ap0[g], b0, z);
      acc[g] = mfma16(ap1[g], b1, z);
    }
    int c = nt*16 + (l & 15);
    #pragma unroll
    for (int g = 0; g < 4; ++g)
      #pragma unroll
      for (int reg = 0; reg < 4; ++reg) {
        int p = g*16 + ((l>>4)<<2) + reg;
        q2[(size_t)p*128 + c] = (p < 49) ? f2b(acc[g][reg]) : (bhalf)0;
      }
  }
  #pragma unroll
  for (int nn = 0; nn < 2; ++nn) {     // k2 cols nt = 2w+nn
    int nt = w*2 + nn;
    bf8v b0 = ldfrag(vk, nt*16, 0, 64, l);
    bf8v b1 = ldfrag(vk, nt*16, 32, 64, l);
    f4 acc[4];
    #pragma unroll
    for (int g = 0; g < 4; ++g) {
      f4 z = {0.f,0.f,0.f,0.f};
      z = mfma16(ap0[g], b0, z);
      acc[g] = mfma16(ap1[g], b1, z);
    }
    int c = nt*16 + (l & 15);
    #pragma unroll
    for (int g = 0; g < 4; ++g)
      #pragma unroll
      for (int reg = 0; reg < 4; ++reg) {
        int p = g*16 + ((l>>4)<<2) + reg;
        k2[(size_t)p*128 + c] = (p < 49) ? f2b(acc[g][reg]) : (bhalf)0;
      }
  }
  #pragma unroll
  for (int nn = 0; nn < 4; ++nn) {     // w2t cols nt = 4w+nn, transposed store
    int nt = w*4 + nn;
    bf8v b0 = ldfrag(vw, nt*16, 0, 64, l);
    bf8v b1 = ldfrag(vw, nt*16, 32, 64, l);
    f4 acc[4];
    #pragma unroll
    for (int g = 0; g < 4; ++g) {
      f4 z = {0.f,0.f,0.f,0.f};
      z = mfma16(ap0[g], b0, z);
      acc[g] = mfma16(ap1[g], b1, z);
    }
    int c = nt*16 + (l & 15);
    #pragma unroll
    for (int g = 0; g < 4; ++g)
      #pragma unroll
      for (int reg = 0; reg < 4; ++reg) {
        int p = g*16 + ((l>>4)<<2) + reg;
        w2[(size_t)c*64 + p] = (p < 49) ? f2b(acc[g][reg]) : (bhalf)0;
      }
  }
  __builtin_amdgcn_s_setprio(0);
}

// ---------- stage 2: ARM attention + edge stats (column-split PV, V in registers) ----------
__global__ void __launch_bounds__(256) s2ker(const bhalf* Q2B, const bhalf* K2B, const bhalf* W2T,
    const float* epb, float* hws, float* gs1, float* gs2)
{
  __shared__ bhalf Kl[64*128];    // 16 KB, swizzled rows of 256 B
  __shared__ bhalf bufP[64*72];   // 9 KB, full P (cross-wave)
  __shared__ float redH[256];     // 1 KB, per-wave disjoint columns
  __shared__ float redS[8];
  int orig = blockIdx.x;
  int blk = (orig & 7) * 400 + (orig >> 3);   // 3200 = 8*400, bijective XCD grouping
  int e = blk % 25, bt = blk / 25, b = bt >> 4, t = bt & 15;
  int i = e / 5, j = e % 5;
  int tid = threadIdx.x, w = tid >> 6, l = tid & 63;
  const bhalf* K = K2B + (size_t)(bt*5 + i)*8192;
  const bhalf* V = W2T + (size_t)(bt*5 + i)*16384;
  const bhalf* Q = Q2B + (size_t)(bt*5 + j)*8192;
  // prefetch Q fragments (independent of LDS staging)
  bf8v aq[4];
  #pragma unroll
  for (int kt = 0; kt < 4; ++kt) aq[kt] = ldfrag(Q, w*16, kt*32, 128, l);
  // ---- stage K (16 KB): coalesced global read, swizzled LDS write ----
  {
    const char* gk = reinterpret_cast<const char*>(K);
    char* lk = reinterpret_cast<char*>(Kl);
    #pragma unroll
    for (int c = 0; c < 4; ++c) {
      int x = (c*256 + tid) << 4;                 // K: row = x>>8 (256 B rows)
      float4 val = *reinterpret_cast<const float4*>(gk + x);
      *reinterpret_cast<float4*>(lk + (x ^ (((x >> 8) & 7) << 4))) = val;
    }
  }
  __syncthreads();
  // QK^T from LDS + in-register softmax
  float sv[4][4];
  __builtin_amdgcn_s_setprio(1);
  #pragma unroll
  for (int nt = 0; nt < 4; ++nt) {
    f4 acc = {0.f,0.f,0.f,0.f};
    #pragma unroll
    for (int kt = 0; kt < 4; ++kt)
      acc = mfma16(aq[kt], ldswz(Kl, nt*16 + (l & 15), kt*64 + ((l >> 4) << 4), 256), acc);
    #pragma unroll
    for (int reg = 0; reg < 4; ++reg) sv[nt][reg] = acc[reg] * ATT_SCALE;
  }
  __builtin_amdgcn_s_setprio(0);
  if ((l & 15) > 0) { sv[3][0] = -1e30f; sv[3][1] = -1e30f; sv[3][2] = -1e30f; sv[3][3] = -1e30f; }
  regSoftmax(sv);
  // write own P rows to bufP
  #pragma unroll
  for (int nt = 0; nt < 4; ++nt)
    #pragma unroll
    for (int reg = 0; reg < 4; ++reg)
      bufP[(w*16 + ((l>>4)<<2) + reg)*72 + nt*16 + (l&15)] = f2b(sv[nt][reg]);
  // V fragments for this wave's column slice (rows [w*64, w*64+64) of W2T tile)
  bf8v vf0[4], vf1[4];
  #pragma unroll
  for (int nn = 0; nn < 4; ++nn) {
    vf0[nn] = ldfrag(V, (w*4 + nn)*16, 0, 64, l);
    vf1[nn] = ldfrag(V, (w*4 + nn)*16, 32, 64, l);
  }
  __syncthreads();   // bufP complete (cross-wave read next)
  // A-fragments: all 4 row-groups of P
  bf8v ap0[4], ap1[4];
  #pragma unroll
  for (int g = 0; g < 4; ++g) {
    ap0[g] = ldfrag(bufP, g*16, 0, 72, l);
    ap1[g] = ldfrag(bufP, g*16, 32, 72, l);
  }
  float sqa = 0.f;
  __builtin_amdgcn_s_setprio(1);
  #pragma unroll
  for (int nn = 0; nn < 4; ++nn) {
    f4 acc[4];
    #pragma unroll
    for (int g = 0; g < 4; ++g) {
      f4 z = {0.f,0.f,0.f,0.f};
      z = mfma16(ap0[g], vf0[nn], z);
      acc[g] = mfma16(ap1[g], vf1[nn], z);
    }
    int c = ((w*4 + nn) << 4) + (l & 15);
    float bias = epb[c];
    float hw = 0.f;
    #pragma unroll
    for (int g = 0; g < 4; ++g) {
      #pragma unroll
      for (int reg = 0; reg < 4; ++reg) {
        int p = g*16 + ((l>>4)<<2) + reg;
        if (p < 49) { float v = acc[g][reg] + bias; hw += v; sqa += v*v; }
      }
    }
    hw += __shfl_xor(hw, 16);
    hw += __shfl_xor(hw, 32);
    if ((l >> 4) == 0) redH[c] = hw;   // per-wave disjoint c
  }
  __builtin_amdgcn_s_setprio(0);
  __syncthreads();
  float hwtot = redH[tid];
  hws[(((size_t)(b*25+e)*16) + t)*256 + tid] = hwtot;
  reduce2Atomic(hwtot, sqa, gs1 + e, gs2 + e, redS);
}

// ---------- GNN back-half (verified fusions, no grid sync) ----------

// projections, 720 blocks x 8 rows. Edge-src BN applied on the fly when bnfly=1
// (L0: src=HWS, EDG = scl[e]*hws + off[e] folded into the FMA chain).
__global__ void __launch_bounds__(256) gnnProj(const float* X, const float* ESRC,
    const float* gs1, const float* gs2, const float* gg, const float* gb, int bnfly,
    const float* Wa, const float* Wb, const float* Wu, const float* Wv, const float* We,
    float* xA, float* xB, float* xU, float* xV, float* eE) {
  int blk = blockIdx.x, tid = threadIdx.x;
  const float* src; const float* W; float* dst; int r0; int isE = 0;
  if (blk < 320) {
    int m = blk / 80; r0 = (blk % 80) * 8;
    src = X;
    W   = (m==0)?Wa:(m==1)?Wb:(m==2)?Wu:Wv;
    dst = (m==0)?xA:(m==1)?xB:(m==2)?xU:xV;
  } else { r0 = (blk-320)*8; src = ESRC; W = We; dst = eE; isE = 1; }
  float scl[8], off[8];
  #pragma unroll
  for (int r = 0; r < 8; ++r) { scl[r] = 1.f; off[r] = 0.f; }
  if (isE && bnfly) {
    constexpr float invCnt = 1.f/1605632.f;
    #pragma unroll
    for (int r = 0; r < 8; ++r) {
      int e = ((r0 + r) >> 4) % 25;
      float m = gs1[e]*invCnt;
      float var = gs2[e]*invCnt - m*m;
      float rstd = rsqrtf(var + 1e-5f);
      float g = gg[e]*rstd;
      scl[r] = g * (1.f/49.f);
      off[r] = gb[e] - g*m;
    }
  }
  float acc[8];
  #pragma unroll
  for (int r = 0; r < 8; ++r) acc[r] = 0.f;
  for (int c = 0; c < 256; c += 4) {
    float w0 = W[(size_t)(c+0)*256 + tid];
    float w1 = W[(size_t)(c+1)*256 + tid];
    float w2 = W[(size_t)(c+2)*256 + tid];
    float w3 = W[(size_t)(c+3)*256 + tid];
    #pragma unroll
    for (int r = 0; r < 8; ++r) {
      float4 a = *reinterpret_cast<const float4*>(&src[(size_t)(r0+r)*256 + c]);
      float ax = fmaf(a.x, scl[r], off[r]);
      float ay = fmaf(a.y, scl[r], off[r]);
      float az = fmaf(a.z, scl[r], off[r]);
      float aw = fmaf(a.w, scl[r], off[r]);
      acc[r] += ax*w0 + ay*w1 + az*w2 + aw*w3;
    }
  }
  #pragma unroll
  for (int r = 0; r < 8; ++r) dst[(size_t)(r0+r)*256 + tid] = acc[r];
}

__global__ void __launch_bounds__(256) g2a(const float* xA, const float* xB, const float* eE,
                                           float* ET, float* s1, float* s2) {
  __shared__ float red[8];
  int blk = blockIdx.x, tid = threadIdx.x;
  int b = blk / 400, e = (blk >> 4) % 25, t = blk & 15;
  int i = e / 5, j = e % 5;
  size_t ni = ((size_t)(b*5+i)*16 + t)*256 + tid;
  size_t nj = ((size_t)(b*5+j)*16 + t)*256 + tid;
  size_t ee = (size_t)blk*256 + tid;
  float v = xA[ni] + xB[nj] + eE[ee];
  ET[ee] = v;
  reduce2Atomic(v, v*v, s1 + e, s2 + e, red);
}

// fused g2b+g3a. Block (b,i,t) owns edges e=i*5+j. layer==0: base EDG
// recomputed from HWS via gem-BN-fly, final EDG written. layer==1: base from
// EDG buffer; EDG NOT written; finker edge output computed in-register -> out.
__global__ void __launch_bounds__(256) g2bg3a(const float* ET, const float* HWS, const float* EDGin,
    float* EDGout, const float* xV, const float* xU, float* XN,
    const float* gs1, const float* gs2, const float* gemg, const float* gemb,
    const float* bg, const float* bb2, const float* es1, const float* es2,
    float* ns1, float* ns2, const float* efw, const float* efb, float* out, int layer) {
  __shared__ float red[8];
  int blk = blockIdx.x, tid = threadIdx.x;
  int b = blk / 80, i = (blk >> 4) % 5, t = blk & 15;
  constexpr float inv32k = 1.f/32768.f;
  constexpr float invCnt = 1.f/1605632.f;
  float ssum = 0.f, exv[5], xvv[5];
  #pragma unroll
  for (int j = 0; j < 5; ++j) {
    int e = i*5 + j;
    size_t ee = ((size_t)(b*25 + e)*16 + t)*256 + tid;
    float m = es1[e]*inv32k;
    float var = es2[e]*inv32k - m*m;
    float rstd = rsqrtf(var + 1e-5f);
    float v = bg[e]*((ET[ee]-m)*rstd) + bb2[e];
    if (v != v) v = 0.f;
    float base;
    if (layer == 0) {
      float gm = gs1[e]*invCnt;
      float gvar = gs2[e]*invCnt - gm*gm;
      float gr = rsqrtf(gvar + 1e-5f);
      base = gemg[e]*((HWS[ee]*(1.f/49.f) - gm)*gr) + gemb[e];
    } else {
      base = EDGin[ee];
    }
    float edg = base + fmaxf(v, 0.f);
    if (layer == 0) {
      EDGout[ee] = edg;
    } else {
      // fused finker edge part
      float vv = edg * efw[tid];
      #pragma unroll
      for (int off = 32; off; off >>= 1) vv += __shfl_down(vv, off);
      if ((tid & 63) == 0) red[tid >> 6] = vv;
      __syncthreads();
      if (tid == 0) out[640 + (size_t)(b*25 + e)*16 + t] = red[0]+red[1]+red[2]+red[3] + efb[0];
      __syncthreads();
    }
    float sg = 1.f/(1.f + __expf(-edg));
    exv[j] = __expf(sg);
    ssum += exv[j];
    xvv[j] = xV[((size_t)(b*5+j)*16 + t)*256 + tid];
  }
  float agg = 0.f;
  #pragma unroll
  for (int j = 0; j < 5; ++j) agg += exv[j]*xvv[j];
  agg *= 0.2f/ssum;
  float xn = xU[(size_t)blk*256 + tid] + agg;
  XN[(size_t)blk*256 + tid] = xn;
  reduce2Atomic(xn, xn*xn, ns1 + i, ns2 + i, red);
}

// L0 node BN + residual relu (writes FV for the next layer)
__global__ void __launch_bounds__(256) g3b(const float* XN, float* X, const float* g, const float* bb,
                                           const float* s1, const float* s2, int mask) {
  int blk = blockIdx.x, tid = threadIdx.x;
  int i = (blk >> 4) % 5;
  size_t ni = (size_t)blk*256 + tid;
  constexpr float invCnt = 1.f/32768.f;
  float m = s1[i]*invCnt;
  float var = s2[i]*invCnt - m*m;
  float rstd = rsqrtf(var + 1e-5f);
  float v = g[i]*((XN[ni]-m)*rstd) + bb[i];
  if (mask && v != v) v = 0.f;
  X[ni] = fmaxf(X[ni] + v, 0.f);
}

// L1 node BN + residual relu fused with finker node part (FV never written)
__global__ void __launch_bounds__(256) g3bfin(const float* XN, const float* FV,
    const float* g, const float* bb, const float* s1, const float* s2,
    const float* sc, float* out) {
  __shared__ float red[12];
  int blk = blockIdx.x, tid = threadIdx.x;
  int i = (blk >> 4) % 5;
  size_t ni = (size_t)blk*256 + tid;
  constexpr float inv32k = 1.f/32768.f;
  float m = s1[i]*inv32k;
  float var = s2[i]*inv32k - m*m;
  float rstd = rsqrtf(var + 1e-5f);
  float v = g[i]*((XN[ni]-m)*rstd) + bb[i];   // L1: no NaN mask
  float x = fmaxf(FV[ni] + v, 0.f);
  float s = fmaxf(sc[i*256 + tid], 0.f);
  float xx = x*x, ss = s*s, xs = x*s;
  #pragma unroll
  for (int off = 32; off; off >>= 1) {
    xx += __shfl_down(xx, off); ss += __shfl_down(ss, off); xs += __shfl_down(xs, off);
  }
  if ((tid & 63) == 0) { int w = tid >> 6; red[w*3] = xx; red[w*3+1] = ss; red[w*3+2] = xs; }
  __syncthreads();
  if (tid == 0) {
    float sxx = red[0]+red[3]+red[6]+red[9];
    float sss = red[1]+red[4]+red[7]+red[10];
    float sxs = red[2]+red[5]+red[8]+red[11];
    float nx = fmaxf(sqrtf(sxx), 1e-12f);
    float ns = fmaxf(sqrtf(sss), 1e-12f);
    out[blk] = sxs / (nx * ns);
  }
}

// ---------- host ----------

extern "C" void kernel_launch(void* const* d_in, const int* in_sizes, int n_in,
                              void* d_out, int out_size, void* d_ws, size_t ws_size,
                              hipStream_t stream) {
  (void)in_sizes; (void)n_in; (void)out_size; (void)ws_size;
  const float* af    = (const float*)d_in[0];
  const float* ef    = (const float*)d_in[1];
  const float* gfm   = (const float*)d_in[2];
  const float* attf  = (const float*)d_in[3];
  const float* sfm   = (const float*)d_in[4];
  const float* fam_q = (const float*)d_in[5];
  const float* fam_k = (const float*)d_in[6];
  const float* fam_v = (const float*)d_in[7];
  const float* arm_q = (const float*)d_in[8];
  const float* arm_k = (const float*)d_in[9];
  const float* arm_v = (const float*)d_in[10];
  const float* epw   = (const float*)d_in[11];
  const float* epb   = (const float*)d_in[12];
  const float* gemg  = (const float*)d_in[13];
  const float* gemb  = (const float*)d_in[14];
  const float* Us[2]   = {(const float*)d_in[15], (const float*)d_in[20]};
  const float* Vs[2]   = {(const float*)d_in[16], (const float*)d_in[21]};
  const float* As[2]   = {(const float*)d_in[17], (const float*)d_in[22]};
  const float* Bs[2]   = {(const float*)d_in[18], (const float*)d_in[23]};
  const float* Es[2]   = {(const float*)d_in[19], (const float*)d_in[24]};
  const float* bnvg[2] = {(const float*)d_in[25], (const float*)d_in[29]};
  const float* bnvb[2] = {(const float*)d_in[26], (const float*)d_in[30]};
  const float* bneg[2] = {(const float*)d_in[27], (const float*)d_in[31]};
  const float* bneb[2] = {(const float*)d_in[28], (const float*)d_in[32]};
  const float* scp  = (const float*)d_in[33];
  const float* efw  = (const float*)d_in[34];
  const float* efb  = (const float*)d_in[35];

  char* ws = (char*)d_ws;
  bhalf* PT  = (bhalf*)(ws + O_PT);
  bhalf* WTS = (bhalf*)(ws + O_WTS);
  bhalf* K1B = (bhalf*)(ws + O_K1B);
  bhalf* FW  = (bhalf*)(ws + O_FW);
  bhalf* VQT = (bhalf*)(ws + O_VQT);
  bhalf* VKT = (bhalf*)(ws + O_VKT);
  float* G   = (float*)(ws + O_G);
  bhalf* VWT = (bhalf*)(ws + O_VWT);
  bhalf* Q2B = (bhalf*)(ws + O_Q2B);
  bhalf* K2B = (bhalf*)(ws + O_K2B);
  bhalf* W2T = (bhalf*)(ws + O_W2T);
  float* FV  = (float*)(ws + O_FV);
  float* HWS = (float*)(ws + O_HWS);
  float* EDG = (float*)(ws + O_EDG);
  float* st  = (float*)(ws + O_ST);
  float* XA  = (float*)(ws + O_XA);
  float* XB  = (float*)(ws + O_XB);
  float* XU  = (float*)(ws + O_XU);
  float* XV  = (float*)(ws + O_XV);
  float* EE  = (float*)(ws + O_EE);
  float* ET  = (float*)(ws + O_ET);
  float* XN  = (float*)(ws + O_XN);

  hipMemsetAsync(st, 0, 256*sizeof(float), stream);

  prepAll<<<2176, TPB, 0, stream>>>(fam_q, fam_k, fam_v, arm_q, arm_k, arm_v, epw, WTS,
                                    af, ef, gfm, attf, sfm, PT, FV, G);
  wf2<<<512, TPB, 0, stream>>>(fam_v, arm_q, arm_k, G, FW);
  kv1<<<dim3(128, 10), TPB, 0, stream>>>(PT, WTS, FW, K1B, VQT, VKT, VWT);
  s1ker<<<640, TPB, 0, stream>>>(PT, WTS, K1B, VQT, VKT, VWT, Q2B, K2B, W2T);
  s2ker<<<3200, TPB, 0, stream>>>(Q2B, K2B, W2T, epb, HWS, st+0, st+25);

  float* out = (float*)d_out;
  for (int L = 0; L < 2; ++L) {
    float* es1 = st + 64 + L*64;
    float* es2 = es1 + 25;
    float* ns1 = es1 + 50;
    float* ns2 = es1 + 55;
    gnnProj<<<720, TPB, 0, stream>>>(FV, (L == 0) ? HWS : EDG, st+0, st+25, gemg, gemb,
                                     (L == 0) ? 1 : 0,
                                     As[L], Bs[L], Us[L], Vs[L], Es[L],
                                     XA, XB, XU, XV, EE);
    g2a<<<3200, TPB, 0, stream>>>(XA, XB, EE, ET, es1, es2);
    g2bg3a<<<640, TPB, 0, stream>>>(ET, HWS, EDG, EDG, XV, XU, XN,
                                    st+0, st+25, gemg, gemb,
                                    bneg[L], bneb[L], es1, es2, ns1, ns2,
                                    efw, efb, out, L);
    if (L == 0)
      g3b<<<640, TPB, 0, stream>>>(XN, FV, bnvg[0], bnvb[0], ns1, ns2, 1);
    else
      g3bfin<<<640, TPB, 0, stream>>>(XN, FV, bnvg[1], bnvb[1], ns1, ns2, scp, out);
  }
}

// Round 11
// 251.856 us; speedup vs baseline: 8.8399x; 1.4757x over previous
//
#include <hip/hip_runtime.h>

#define DEV __device__ __forceinline__

typedef unsigned short bhalf;
typedef __attribute__((ext_vector_type(8))) short bf8v;
typedef __attribute__((ext_vector_type(4))) float f4;

namespace {
constexpr int TPB = 256;
constexpr float ATT_SCALE = 0.08838834764831845f; // 1/sqrt(128)

// ---- workspace byte offsets ----
constexpr size_t O_PT  = 0;          // bf16 [640][64][256]  modalities, zero-pad rows
constexpr size_t O_WTS = 20971520;   // bf16 transposed weights (see W_* below)
constexpr size_t O_K1B = 21626880;   // bf16 [128][64][128]
constexpr size_t O_FW  = 23724032;   // bf16 fused weights: VQ[128][256], VK[128][256], VW[256][256]
constexpr size_t O_VQT = 27918336;   // bf16 [128][128][64]  (v1@arm_q)^T
constexpr size_t O_VKT = 30015488;   // bf16 [128][128][64]
constexpr size_t O_G   = 32112640;   // f32  [256][256]  arm_v@epw  (DEAD after wf2 -> reused as ST2 stats shards)
constexpr size_t O_VWT = 36306944;   // bf16 [128][256][64]  (vt@epw)^T
constexpr size_t O_Q2B = 40501248;   // bf16 [640][64][128]
constexpr size_t O_K2B = 50987008;   // bf16 [640][64][128]
constexpr size_t O_W2T = 61472768;   // bf16 [640][256][64]
constexpr size_t O_FV  = 82444288;   // f32  [640][256]  node features X
constexpr size_t O_HWS = 83099648;   // f32  [3200][256]
constexpr size_t O_EDG = 86376448;   // f32  [3200][256]
constexpr size_t O_XA  = 89654272;
constexpr size_t O_XB  = 90309632;
constexpr size_t O_XU  = 90964992;
constexpr size_t O_XV  = 91620352;
constexpr size_t O_EE  = 92275712;
constexpr size_t O_ET  = 95552512;
constexpr size_t O_XN  = 98829312;

// WTS element offsets (bf16 elems), all stored as Wt[n][k=256]
constexpr size_t W_FAMQ = 0, W_FAMK = 32768, W_ARMQ = 65536, W_ARMK = 98304,
                 W_FAMV = 131072, W_ARMV = 196608, W_EPW = 262144;
// FW element offsets
constexpr size_t FW_VQ = 0, FW_VK = 32768, FW_VW = 65536;

// ST2 stat-shard float offsets (slot = xcd*32 + idx, xcd<8):
// gs1 @0, gs2 @256; per layer L: es1 @512+L*1024, es2 @768+L*1024,
// ns1 @1024+L*1024, ns2 @1280+L*1024. Total 2560 floats.
constexpr int ST_GS1 = 0, ST_GS2 = 256;
} // namespace

// ---------- helpers ----------

DEV bhalf f2b(float f) {
  unsigned u = __float_as_uint(f);
  return (bhalf)((u + 0x7FFFu + ((u >> 16) & 1u)) >> 16);
}

DEV f4 mfma16(bf8v a, bf8v b, f4 c) {
  return __builtin_amdgcn_mfma_f32_16x16x32_bf16(a, b, c, 0, 0, 0);
}

// fragment load: lane l reads row (r0 + (l&15)), 8 contiguous k at k0 + (l>>4)*8
DEV bf8v ldfrag(const bhalf* base, int r0, int k0, int S, int l) {
  return *reinterpret_cast<const bf8v*>(base + (size_t)(r0 + (l & 15)) * S + k0 + ((l >> 4) << 3));
}

// swizzled LDS fragment load: byte = row*stride + koffB, XOR'd with ((row&7)<<4)
DEV bf8v ldswz(const bhalf* base, int row, int koffB, int strideB) {
  int byte = row * strideB + koffB;
  byte ^= ((row & 7) << 4);
  return *reinterpret_cast<const bf8v*>(reinterpret_cast<const char*>(base) + byte);
}

// sum the 8 per-XCD shards of one stat
DEV float sumShards(const float* base, int idx) {
  float s = 0.f;
  #pragma unroll
  for (int x = 0; x < 8; ++x) s += base[x*32 + idx];
  return s;
}

// in-register row softmax: sv[nt][reg], row per reg spans cols nt*16+(l&15) across 16 lanes
DEV void regSoftmax(float sv[4][4]) {
  #pragma unroll
  for (int reg = 0; reg < 4; ++reg) {
    float m = fmaxf(fmaxf(sv[0][reg], sv[1][reg]), fmaxf(sv[2][reg], sv[3][reg]));
    #pragma unroll
    for (int off = 1; off <= 8; off <<= 1) m = fmaxf(m, __shfl_xor(m, off));
    float s = 0.f;
    #pragma unroll
    for (int nt = 0; nt < 4; ++nt) { float e = __expf(sv[nt][reg] - m); sv[nt][reg] = e; s += e; }
    #pragma unroll
    for (int off = 1; off <= 8; off <<= 1) s += __shfl_xor(s, off);
    float inv = 1.f / s;
    #pragma unroll
    for (int nt = 0; nt < 4; ++nt) sv[nt][reg] *= inv;
  }
}

// ga/gb already point at the per-XCD shard slot
DEV void reduce2Atomic(float a, float b, float* ga, float* gb, float* red) {
  #pragma unroll
  for (int off = 32; off; off >>= 1) { a += __shfl_down(a, off); b += __shfl_down(b, off); }
  if ((threadIdx.x & 63) == 0) { int w = threadIdx.x >> 6; red[w*2] = a; red[w*2+1] = b; }
  __syncthreads();
  if (threadIdx.x == 0) {
    atomicAdd(ga, red[0]+red[2]+red[4]+red[6]);
    atomicAdd(gb, red[1]+red[3]+red[5]+red[7]);
  }
  __syncthreads();
}

// ---------- prep kernel (wprep + modprep + G=arm_v@epw merged) ----------

__global__ void __launch_bounds__(256) prepAll(const float* fq, const float* fk, const float* fv,
                                               const float* aq, const float* ak, const float* av,
                                               const float* ep, bhalf* WT,
                                               const float* af, const float* ef, const float* gf,
                                               const float* attf, const float* sf,
                                               bhalf* PT, float* FV, float* G) {
  __shared__ float lb[49*260];
  int tid = threadIdx.x;
  if (blockIdx.x < 1280) {
    // ---- wprep: transpose 7 weight matrices to bf16 Wt[n][256] ----
    int blk = blockIdx.x;
    const float* src; bhalf* dst; int N, n;
    if (blk < 512) {
      int m = blk >> 7; n = blk & 127; N = 128;
      src = (m==0)?fq:(m==1)?fk:(m==2)?aq:ak;
      dst = WT + (size_t)m*32768;
    } else {
      int r = blk - 512; int m = r >> 8; n = r & 255; N = 256;
      src = (m==0)?fv:(m==1)?av:ep;
      dst = WT + 131072 + (size_t)m*65536;
    }
    dst[(size_t)n*256 + tid] = f2b(src[(size_t)tid*N + n]);
  } else if (blockIdx.x < 1920) {
    // ---- modprep: per (bt,u) modality transpose + fv means ----
    int blk = blockIdx.x - 1280;
    int u = blk % 5, bt = blk / 5, b = bt >> 4, t = bt & 15;
    const float* src = (u==0)?af:(u==1)?ef:(u==2)?gf:(u==3)?attf:sf;
    src += ((size_t)b*256*16 + t)*49;
    for (int o = tid; o < 49*256; o += TPB) {
      int c = o / 49, p = o % 49;
      lb[p*260 + c] = src[(size_t)c*784 + p];
    }
    __syncthreads();
    bhalf* pt = PT + (size_t)blk*16384;
    for (int p = 0; p < 64; ++p)
      pt[p*256 + tid] = (p < 49) ? f2b(lb[p*260 + tid]) : (bhalf)0;
    float s = 0.f;
    for (int p = 0; p < 49; ++p) s += lb[p*260 + tid];
    FV[(((size_t)(b*5+u)*16) + t)*256 + tid] = s * (1.f/49.f);
  } else {
    // ---- G = arm_v @ epw (f32), row c per block ----
    int c = blockIdx.x - 1920;
    const float* ar = av + (size_t)c*256;
    float acc = 0.f;
    for (int d = 0; d < 256; ++d)
      acc = fmaf(ar[d], ep[(size_t)d*256 + tid], acc);
    G[(size_t)c*256 + tid] = acc;
  }
}

// fused weights: W_VQ[n][k]=sum_c famv[k][c]*armq[c][n]; W_VK likewise; W_VW uses G.
__global__ void __launch_bounds__(256) wf2(const float* fv, const float* aq, const float* ak,
                                           const float* G, bhalf* FW) {
  int blk = blockIdx.x, tid = threadIdx.x;
  if (blk < 256) {
    int k = blk;
    if (tid < 128) {
      float a1 = 0.f, a2 = 0.f;
      for (int c = 0; c < 256; ++c) {
        float f = fv[(size_t)k*256 + c];
        a1 = fmaf(f, aq[(size_t)c*128 + tid], a1);
        a2 = fmaf(f, ak[(size_t)c*128 + tid], a2);
      }
      FW[FW_VQ + (size_t)tid*256 + k] = f2b(a1);
      FW[FW_VK + (size_t)tid*256 + k] = f2b(a2);
    }
  } else {
    int k = blk - 256;
    float a = 0.f;
    for (int c = 0; c < 256; ++c)
      a = fmaf(fv[(size_t)k*256 + c], G[(size_t)c*256 + tid], a);
    FW[FW_VW + (size_t)tid*256 + k] = f2b(a);
  }
}

// ---------- MFMA chain collapsed to ONE kernel: everything from Paf ----------
__global__ void __launch_bounds__(256) kv1(const bhalf* PT, const bhalf* WT, const bhalf* FW,
                                           bhalf* K1B, bhalf* VQT, bhalf* VKT, bhalf* VWT) {
  int bt = blockIdx.x, part = blockIdx.y;
  int tid = threadIdx.x, w = tid >> 6, l = tid & 63;
  const bhalf* A = PT + (size_t)bt*5*16384; // u=0 (af)
  bf8v a8[8];
  #pragma unroll
  for (int kt = 0; kt < 8; ++kt) a8[kt] = ldfrag(A, w*16, kt*32, 256, l);
  if (part < 2) {
    bhalf* dst = K1B + (size_t)bt*8192;
    int nt0 = part*4;
    #pragma unroll
    for (int nn = 0; nn < 4; ++nn) {
      int nt = nt0 + nn;
      f4 acc = {0.f,0.f,0.f,0.f};
      #pragma unroll
      for (int kt = 0; kt < 8; ++kt)
        acc = mfma16(a8[kt], ldfrag(WT + W_FAMK, nt*16, kt*32, 256, l), acc);
      #pragma unroll
      for (int reg = 0; reg < 4; ++reg) {
        int p = w*16 + ((l>>4)<<2) + reg;
        dst[(size_t)p*128 + nt*16 + (l&15)] = f2b(acc[reg]);
      }
    }
  } else if (part < 6) {
    int which = (part - 2) >> 1;
    const bhalf* Wb = FW + ((which == 0) ? FW_VQ : FW_VK);
    bhalf* o = ((which == 0) ? VQT : VKT) + (size_t)bt*8192;
    int nt0 = ((part - 2) & 1) * 4;
    #pragma unroll
    for (int nn = 0; nn < 4; ++nn) {
      int nt = nt0 + nn;
      f4 acc = {0.f,0.f,0.f,0.f};
      #pragma unroll
      for (int kt = 0; kt < 8; ++kt)
        acc = mfma16(a8[kt], ldfrag(Wb, nt*16, kt*32, 256, l), acc);
      #pragma unroll
      for (int reg = 0; reg < 4; ++reg) {
        int p = w*16 + ((l>>4)<<2) + reg;
        int n = nt*16 + (l&15);
        o[(size_t)n*64 + p] = f2b(acc[reg]);   // transposed store
      }
    }
  } else {
    bhalf* ow = VWT + (size_t)bt*16384;
    int nt0 = (part - 6) * 4;
    #pragma unroll
    for (int nn = 0; nn < 4; ++nn) {
      int nt = nt0 + nn;
      f4 acc = {0.f,0.f,0.f,0.f};
      #pragma unroll
      for (int kt = 0; kt < 8; ++kt)
        acc = mfma16(a8[kt], ldfrag(FW + FW_VW, nt*16, kt*32, 256, l), acc);
      #pragma unroll
      for (int reg = 0; reg < 4; ++reg) {
        int p = w*16 + ((l>>4)<<2) + reg;
        ow[(size_t)(nt*16 + (l&15))*64 + p] = f2b(acc[reg]);  // transposed
      }
    }
  }
}

// ---------- stage 1: FAM attention + ARM input projections (column-split PV) ----------
__global__ void __launch_bounds__(256) s1ker(const bhalf* PT, const bhalf* WT,
    const bhalf* K1B, const bhalf* VQT, const bhalf* VKT, const bhalf* VWT,
    bhalf* Q2B, bhalf* K2B, bhalf* W2T)
{
  __shared__ bhalf bufA[64*136];  // q1 staging (17.4 KB), wave-private rows
  __shared__ bhalf bufP[64*72];   // 9.2 KB, cross-wave P
  int orig = blockIdx.x;
  int blk = (orig & 7) * 80 + (orig >> 3);   // bijective XCD grouping
  int bt = blk / 5;
  int tid = threadIdx.x, w = tid >> 6, l = tid & 63;
  const bhalf* Pt = PT + (size_t)blk*16384;
  // phase 1: q1 (M=64, N=128, K=256) -> bufA (own rows)
  {
    bf8v a8[8];
    #pragma unroll
    for (int kt = 0; kt < 8; ++kt) a8[kt] = ldfrag(Pt, w*16, kt*32, 256, l);
    __builtin_amdgcn_s_setprio(1);
    #pragma unroll
    for (int nt = 0; nt < 8; ++nt) {
      f4 acc = {0.f,0.f,0.f,0.f};
      #pragma unroll
      for (int kt = 0; kt < 8; ++kt)
        acc = mfma16(a8[kt], ldfrag(WT + W_FAMQ, nt*16, kt*32, 256, l), acc);
      #pragma unroll
      for (int reg = 0; reg < 4; ++reg)
        bufA[(w*16 + ((l>>4)<<2) + reg)*136 + nt*16 + (l&15)] = f2b(acc[reg]);
    }
    __builtin_amdgcn_s_setprio(0);
  }
  // phase 2 (no barrier: bufA rows are wave-private): scores vs k1, softmax in regs
  float sv[4][4];
  {
    const bhalf* K1 = K1B + (size_t)bt*8192;
    bf8v aq[4];
    #pragma unroll
    for (int kt = 0; kt < 4; ++kt) aq[kt] = ldfrag(bufA, w*16, kt*32, 136, l);
    #pragma unroll
    for (int nt = 0; nt < 4; ++nt) {
      f4 acc = {0.f,0.f,0.f,0.f};
      #pragma unroll
      for (int kt = 0; kt < 4; ++kt)
        acc = mfma16(aq[kt], ldfrag(K1, nt*16, kt*32, 128, l), acc);
      #pragma unroll
      for (int reg = 0; reg < 4; ++reg) sv[nt][reg] = acc[reg] * ATT_SCALE;
    }
  }
  if ((l & 15) > 0) { sv[3][0] = -1e30f; sv[3][1] = -1e30f; sv[3][2] = -1e30f; sv[3][3] = -1e30f; }
  regSoftmax(sv);
  #pragma unroll
  for (int nt = 0; nt < 4; ++nt)
    #pragma unroll
    for (int reg = 0; reg < 4; ++reg)
      bufP[(w*16 + ((l>>4)<<2) + reg)*72 + nt*16 + (l&15)] = f2b(sv[nt][reg]);
  __syncthreads();   // bufP cross-wave
  // phase 3: column-split PVs. A-frags: all 4 row-groups of P.
  bf8v ap0[4], ap1[4];
  #pragma unroll
  for (int g = 0; g < 4; ++g) {
    ap0[g] = ldfrag(bufP, g*16, 0, 72, l);
    ap1[g] = ldfrag(bufP, g*16, 32, 72, l);
  }
  const bhalf* vq = VQT + (size_t)bt*8192;
  const bhalf* vk = VKT + (size_t)bt*8192;
  const bhalf* vw = VWT + (size_t)bt*16384;
  bhalf* q2 = Q2B + (size_t)blk*8192;
  bhalf* k2 = K2B + (size_t)blk*8192;
  bhalf* w2 = W2T + (size_t)blk*16384;
  __builtin_amdgcn_s_setprio(1);
  #pragma unroll
  for (int nn = 0; nn < 2; ++nn) {     // q2 cols nt = 2w+nn
    int nt = w*2 + nn;
    bf8v b0 = ldfrag(vq, nt*16, 0, 64, l);
    bf8v b1 = ldfrag(vq, nt*16, 32, 64, l);
    f4 acc[4];
    #pragma unroll
    for (int g = 0; g < 4; ++g) {
      f4 z = {0.f,0.f,0.f,0.f};
      z = mfma16(ap0[g], b0, z);
      acc[g] = mfma16(ap1[g], b1, z);
    }
    int c = nt*16 + (l & 15);
    #pragma unroll
    for (int g = 0; g < 4; ++g)
      #pragma unroll
      for (int reg = 0; reg < 4; ++reg) {
        int p = g*16 + ((l>>4)<<2) + reg;
        q2[(size_t)p*128 + c] = (p < 49) ? f2b(acc[g][reg]) : (bhalf)0;
      }
  }
  #pragma unroll
  for (int nn = 0; nn < 2; ++nn) {     // k2 cols nt = 2w+nn
    int nt = w*2 + nn;
    bf8v b0 = ldfrag(vk, nt*16, 0, 64, l);
    bf8v b1 = ldfrag(vk, nt*16, 32, 64, l);
    f4 acc[4];
    #pragma unroll
    for (int g = 0; g < 4; ++g) {
      f4 z = {0.f,0.f,0.f,0.f};
      z = mfma16(ap0[g], b0, z);
      acc[g] = mfma16(ap1[g], b1, z);
    }
    int c = nt*16 + (l & 15);
    #pragma unroll
    for (int g = 0; g < 4; ++g)
      #pragma unroll
      for (int reg = 0; reg < 4; ++reg) {
        int p = g*16 + ((l>>4)<<2) + reg;
        k2[(size_t)p*128 + c] = (p < 49) ? f2b(acc[g][reg]) : (bhalf)0;
      }
  }
  #pragma unroll
  for (int nn = 0; nn < 4; ++nn) {     // w2t cols nt = 4w+nn, transposed store
    int nt = w*4 + nn;
    bf8v b0 = ldfrag(vw, nt*16, 0, 64, l);
    bf8v b1 = ldfrag(vw, nt*16, 32, 64, l);
    f4 acc[4];
    #pragma unroll
    for (int g = 0; g < 4; ++g) {
      f4 z = {0.f,0.f,0.f,0.f};
      z = mfma16(ap0[g], b0, z);
      acc[g] = mfma16(ap1[g], b1, z);
    }
    int c = nt*16 + (l & 15);
    #pragma unroll
    for (int g = 0; g < 4; ++g)
      #pragma unroll
      for (int reg = 0; reg < 4; ++reg) {
        int p = g*16 + ((l>>4)<<2) + reg;
        w2[(size_t)c*64 + p] = (p < 49) ? f2b(acc[g][reg]) : (bhalf)0;
      }
  }
  __builtin_amdgcn_s_setprio(0);
}

// ---------- stage 2: ARM attention + edge stats (column-split PV, V in registers) ----------
// Stats land in per-XCD shards (slot = (orig&7)*32 + e) to cut atomic contention 8x.
__global__ void __launch_bounds__(256) s2ker(const bhalf* Q2B, const bhalf* K2B, const bhalf* W2T,
    const float* epb, float* hws, float* gs1, float* gs2)
{
  __shared__ bhalf Kl[64*128];    // 16 KB, swizzled rows of 256 B
  __shared__ bhalf bufP[64*72];   // 9 KB, full P (cross-wave)
  __shared__ float redH[256];     // 1 KB, per-wave disjoint columns
  __shared__ float redS[8];
  int orig = blockIdx.x;
  int blk = (orig & 7) * 400 + (orig >> 3);   // 3200 = 8*400, bijective XCD grouping
  int e = blk % 25, bt = blk / 25, b = bt >> 4, t = bt & 15;
  int i = e / 5, j = e % 5;
  int tid = threadIdx.x, w = tid >> 6, l = tid & 63;
  const bhalf* K = K2B + (size_t)(bt*5 + i)*8192;
  const bhalf* V = W2T + (size_t)(bt*5 + i)*16384;
  const bhalf* Q = Q2B + (size_t)(bt*5 + j)*8192;
  // prefetch Q fragments (independent of LDS staging)
  bf8v aq[4];
  #pragma unroll
  for (int kt = 0; kt < 4; ++kt) aq[kt] = ldfrag(Q, w*16, kt*32, 128, l);
  // ---- stage K (16 KB): coalesced global read, swizzled LDS write ----
  {
    const char* gk = reinterpret_cast<const char*>(K);
    char* lk = reinterpret_cast<char*>(Kl);
    #pragma unroll
    for (int c = 0; c < 4; ++c) {
      int x = (c*256 + tid) << 4;                 // K: row = x>>8 (256 B rows)
      float4 val = *reinterpret_cast<const float4*>(gk + x);
      *reinterpret_cast<float4*>(lk + (x ^ (((x >> 8) & 7) << 4))) = val;
    }
  }
  __syncthreads();
  // QK^T from LDS + in-register softmax
  float sv[4][4];
  __builtin_amdgcn_s_setprio(1);
  #pragma unroll
  for (int nt = 0; nt < 4; ++nt) {
    f4 acc = {0.f,0.f,0.f,0.f};
    #pragma unroll
    for (int kt = 0; kt < 4; ++kt)
      acc = mfma16(aq[kt], ldswz(Kl, nt*16 + (l & 15), kt*64 + ((l >> 4) << 4), 256), acc);
    #pragma unroll
    for (int reg = 0; reg < 4; ++reg) sv[nt][reg] = acc[reg] * ATT_SCALE;
  }
  __builtin_amdgcn_s_setprio(0);
  if ((l & 15) > 0) { sv[3][0] = -1e30f; sv[3][1] = -1e30f; sv[3][2] = -1e30f; sv[3][3] = -1e30f; }
  regSoftmax(sv);
  // write own P rows to bufP
  #pragma unroll
  for (int nt = 0; nt < 4; ++nt)
    #pragma unroll
    for (int reg = 0; reg < 4; ++reg)
      bufP[(w*16 + ((l>>4)<<2) + reg)*72 + nt*16 + (l&15)] = f2b(sv[nt][reg]);
  // V fragments for this wave's column slice (rows [w*64, w*64+64) of W2T tile)
  bf8v vf0[4], vf1[4];
  #pragma unroll
  for (int nn = 0; nn < 4; ++nn) {
    vf0[nn] = ldfrag(V, (w*4 + nn)*16, 0, 64, l);
    vf1[nn] = ldfrag(V, (w*4 + nn)*16, 32, 64, l);
  }
  __syncthreads();   // bufP complete (cross-wave read next)
  // A-fragments: all 4 row-groups of P
  bf8v ap0[4], ap1[4];
  #pragma unroll
  for (int g = 0; g < 4; ++g) {
    ap0[g] = ldfrag(bufP, g*16, 0, 72, l);
    ap1[g] = ldfrag(bufP, g*16, 32, 72, l);
  }
  float sqa = 0.f;
  __builtin_amdgcn_s_setprio(1);
  #pragma unroll
  for (int nn = 0; nn < 4; ++nn) {
    f4 acc[4];
    #pragma unroll
    for (int g = 0; g < 4; ++g) {
      f4 z = {0.f,0.f,0.f,0.f};
      z = mfma16(ap0[g], vf0[nn], z);
      acc[g] = mfma16(ap1[g], vf1[nn], z);
    }
    int c = ((w*4 + nn) << 4) + (l & 15);
    float bias = epb[c];
    float hw = 0.f;
    #pragma unroll
    for (int g = 0; g < 4; ++g) {
      #pragma unroll
      for (int reg = 0; reg < 4; ++reg) {
        int p = g*16 + ((l>>4)<<2) + reg;
        if (p < 49) { float v = acc[g][reg] + bias; hw += v; sqa += v*v; }
      }
    }
    hw += __shfl_xor(hw, 16);
    hw += __shfl_xor(hw, 32);
    if ((l >> 4) == 0) redH[c] = hw;   // per-wave disjoint c
  }
  __builtin_amdgcn_s_setprio(0);
  __syncthreads();
  float hwtot = redH[tid];
  hws[(((size_t)(b*25+e)*16) + t)*256 + tid] = hwtot;
  int slot = (orig & 7)*32 + e;
  reduce2Atomic(hwtot, sqa, gs1 + slot, gs2 + slot, redS);
}

// ---------- GNN back-half (verified fusions, per-XCD stat shards) ----------

// projections, 720 blocks x 8 rows. Edge-src BN applied on the fly when bnfly=1.
__global__ void __launch_bounds__(256) gnnProj(const float* X, const float* ESRC,
    const float* gs1, const float* gs2, const float* gg, const float* gb, int bnfly,
    const float* Wa, const float* Wb, const float* Wu, const float* Wv, const float* We,
    float* xA, float* xB, float* xU, float* xV, float* eE) {
  int blk = blockIdx.x, tid = threadIdx.x;
  const float* src; const float* W; float* dst; int r0; int isE = 0;
  if (blk < 320) {
    int m = blk / 80; r0 = (blk % 80) * 8;
    src = X;
    W   = (m==0)?Wa:(m==1)?Wb:(m==2)?Wu:Wv;
    dst = (m==0)?xA:(m==1)?xB:(m==2)?xU:xV;
  } else { r0 = (blk-320)*8; src = ESRC; W = We; dst = eE; isE = 1; }
  float scl[8], off[8];
  #pragma unroll
  for (int r = 0; r < 8; ++r) { scl[r] = 1.f; off[r] = 0.f; }
  if (isE && bnfly) {
    constexpr float invCnt = 1.f/1605632.f;
    #pragma unroll
    for (int r = 0; r < 8; ++r) {
      int e = ((r0 + r) >> 4) % 25;
      float m = sumShards(gs1, e)*invCnt;
      float var = sumShards(gs2, e)*invCnt - m*m;
      float rstd = rsqrtf(var + 1e-5f);
      float g = gg[e]*rstd;
      scl[r] = g * (1.f/49.f);
      off[r] = gb[e] - g*m;
    }
  }
  float acc[8];
  #pragma unroll
  for (int r = 0; r < 8; ++r) acc[r] = 0.f;
  for (int c = 0; c < 256; c += 4) {
    float w0 = W[(size_t)(c+0)*256 + tid];
    float w1 = W[(size_t)(c+1)*256 + tid];
    float w2 = W[(size_t)(c+2)*256 + tid];
    float w3 = W[(size_t)(c+3)*256 + tid];
    #pragma unroll
    for (int r = 0; r < 8; ++r) {
      float4 a = *reinterpret_cast<const float4*>(&src[(size_t)(r0+r)*256 + c]);
      float ax = fmaf(a.x, scl[r], off[r]);
      float ay = fmaf(a.y, scl[r], off[r]);
      float az = fmaf(a.z, scl[r], off[r]);
      float aw = fmaf(a.w, scl[r], off[r]);
      acc[r] += ax*w0 + ay*w1 + az*w2 + aw*w3;
    }
  }
  #pragma unroll
  for (int r = 0; r < 8; ++r) dst[(size_t)(r0+r)*256 + tid] = acc[r];
}

__global__ void __launch_bounds__(256) g2a(const float* xA, const float* xB, const float* eE,
                                           float* ET, float* s1, float* s2) {
  __shared__ float red[8];
  int blk = blockIdx.x, tid = threadIdx.x;
  int b = blk / 400, e = (blk >> 4) % 25, t = blk & 15;
  int i = e / 5, j = e % 5;
  size_t ni = ((size_t)(b*5+i)*16 + t)*256 + tid;
  size_t nj = ((size_t)(b*5+j)*16 + t)*256 + tid;
  size_t ee = (size_t)blk*256 + tid;
  float v = xA[ni] + xB[nj] + eE[ee];
  ET[ee] = v;
  int slot = (blk & 7)*32 + e;
  reduce2Atomic(v, v*v, s1 + slot, s2 + slot, red);
}

// fused g2b+g3a. Stats read as 8-shard sums; ns written to per-XCD shard.
__global__ void __launch_bounds__(256) g2bg3a(const float* ET, const float* HWS, const float* EDGin,
    float* EDGout, const float* xV, const float* xU, float* XN,
    const float* gs1, const float* gs2, const float* gemg, const float* gemb,
    const float* bg, const float* bb2, const float* es1, const float* es2,
    float* ns1, float* ns2, const float* efw, const float* efb, float* out, int layer) {
  __shared__ float red[8];
  int blk = blockIdx.x, tid = threadIdx.x;
  int b = blk / 80, i = (blk >> 4) % 5, t = blk & 15;
  constexpr float inv32k = 1.f/32768.f;
  constexpr float invCnt = 1.f/1605632.f;
  float ssum = 0.f, exv[5], xvv[5];
  #pragma unroll
  for (int j = 0; j < 5; ++j) {
    int e = i*5 + j;
    size_t ee = ((size_t)(b*25 + e)*16 + t)*256 + tid;
    float m = sumShards(es1, e)*inv32k;
    float var = sumShards(es2, e)*inv32k - m*m;
    float rstd = rsqrtf(var + 1e-5f);
    float v = bg[e]*((ET[ee]-m)*rstd) + bb2[e];
    if (v != v) v = 0.f;
    float base;
    if (layer == 0) {
      float gm = sumShards(gs1, e)*invCnt;
      float gvar = sumShards(gs2, e)*invCnt - gm*gm;
      float gr = rsqrtf(gvar + 1e-5f);
      base = gemg[e]*((HWS[ee]*(1.f/49.f) - gm)*gr) + gemb[e];
    } else {
      base = EDGin[ee];
    }
    float edg = base + fmaxf(v, 0.f);
    if (layer == 0) {
      EDGout[ee] = edg;
    } else {
      // fused finker edge part
      float vv = edg * efw[tid];
      #pragma unroll
      for (int off = 32; off; off >>= 1) vv += __shfl_down(vv, off);
      if ((tid & 63) == 0) red[tid >> 6] = vv;
      __syncthreads();
      if (tid == 0) out[640 + (size_t)(b*25 + e)*16 + t] = red[0]+red[1]+red[2]+red[3] + efb[0];
      __syncthreads();
    }
    float sg = 1.f/(1.f + __expf(-edg));
    exv[j] = __expf(sg);
    ssum += exv[j];
    xvv[j] = xV[((size_t)(b*5+j)*16 + t)*256 + tid];
  }
  float agg = 0.f;
  #pragma unroll
  for (int j = 0; j < 5; ++j) agg += exv[j]*xvv[j];
  agg *= 0.2f/ssum;
  float xn = xU[(size_t)blk*256 + tid] + agg;
  XN[(size_t)blk*256 + tid] = xn;
  int slot = (blk & 7)*32 + i;
  reduce2Atomic(xn, xn*xn, ns1 + slot, ns2 + slot, red);
}

// L0 node BN + residual relu (writes FV for the next layer)
__global__ void __launch_bounds__(256) g3b(const float* XN, float* X, const float* g, const float* bb,
                                           const float* s1, const float* s2, int mask) {
  int blk = blockIdx.x, tid = threadIdx.x;
  int i = (blk >> 4) % 5;
  size_t ni = (size_t)blk*256 + tid;
  constexpr float invCnt = 1.f/32768.f;
  float m = sumShards(s1, i)*invCnt;
  float var = sumShards(s2, i)*invCnt - m*m;
  float rstd = rsqrtf(var + 1e-5f);
  float v = g[i]*((XN[ni]-m)*rstd) + bb[i];
  if (mask && v != v) v = 0.f;
  X[ni] = fmaxf(X[ni] + v, 0.f);
}

// L1 node BN + residual relu fused with finker node part (FV never written)
__global__ void __launch_bounds__(256) g3bfin(const float* XN, const float* FV,
    const float* g, const float* bb, const float* s1, const float* s2,
    const float* sc, float* out) {
  __shared__ float red[12];
  int blk = blockIdx.x, tid = threadIdx.x;
  int i = (blk >> 4) % 5;
  size_t ni = (size_t)blk*256 + tid;
  constexpr float inv32k = 1.f/32768.f;
  float m = sumShards(s1, i)*inv32k;
  float var = sumShards(s2, i)*inv32k - m*m;
  float rstd = rsqrtf(var + 1e-5f);
  float v = g[i]*((XN[ni]-m)*rstd) + bb[i];   // L1: no NaN mask
  float x = fmaxf(FV[ni] + v, 0.f);
  float s = fmaxf(sc[i*256 + tid], 0.f);
  float xx = x*x, ss = s*s, xs = x*s;
  #pragma unroll
  for (int off = 32; off; off >>= 1) {
    xx += __shfl_down(xx, off); ss += __shfl_down(ss, off); xs += __shfl_down(xs, off);
  }
  if ((tid & 63) == 0) { int w = tid >> 6; red[w*3] = xx; red[w*3+1] = ss; red[w*3+2] = xs; }
  __syncthreads();
  if (tid == 0) {
    float sxx = red[0]+red[3]+red[6]+red[9];
    float sss = red[1]+red[4]+red[7]+red[10];
    float sxs = red[2]+red[5]+red[8]+red[11];
    float nx = fmaxf(sqrtf(sxx), 1e-12f);
    float ns = fmaxf(sqrtf(sss), 1e-12f);
    out[blk] = sxs / (nx * ns);
  }
}

// ---------- host ----------

extern "C" void kernel_launch(void* const* d_in, const int* in_sizes, int n_in,
                              void* d_out, int out_size, void* d_ws, size_t ws_size,
                              hipStream_t stream) {
  (void)in_sizes; (void)n_in; (void)out_size; (void)ws_size;
  const float* af    = (const float*)d_in[0];
  const float* ef    = (const float*)d_in[1];
  const float* gfm   = (const float*)d_in[2];
  const float* attf  = (const float*)d_in[3];
  const float* sfm   = (const float*)d_in[4];
  const float* fam_q = (const float*)d_in[5];
  const float* fam_k = (const float*)d_in[6];
  const float* fam_v = (const float*)d_in[7];
  const float* arm_q = (const float*)d_in[8];
  const float* arm_k = (const float*)d_in[9];
  const float* arm_v = (const float*)d_in[10];
  const float* epw   = (const float*)d_in[11];
  const float* epb   = (const float*)d_in[12];
  const float* gemg  = (const float*)d_in[13];
  const float* gemb  = (const float*)d_in[14];
  const float* Us[2]   = {(const float*)d_in[15], (const float*)d_in[20]};
  const float* Vs[2]   = {(const float*)d_in[16], (const float*)d_in[21]};
  const float* As[2]   = {(const float*)d_in[17], (const float*)d_in[22]};
  const float* Bs[2]   = {(const float*)d_in[18], (const float*)d_in[23]};
  const float* Es[2]   = {(const float*)d_in[19], (const float*)d_in[24]};
  const float* bnvg[2] = {(const float*)d_in[25], (const float*)d_in[29]};
  const float* bnvb[2] = {(const float*)d_in[26], (const float*)d_in[30]};
  const float* bneg[2] = {(const float*)d_in[27], (const float*)d_in[31]};
  const float* bneb[2] = {(const float*)d_in[28], (const float*)d_in[32]};
  const float* scp  = (const float*)d_in[33];
  const float* efw  = (const float*)d_in[34];
  const float* efb  = (const float*)d_in[35];

  char* ws = (char*)d_ws;
  bhalf* PT  = (bhalf*)(ws + O_PT);
  bhalf* WTS = (bhalf*)(ws + O_WTS);
  bhalf* K1B = (bhalf*)(ws + O_K1B);
  bhalf* FW  = (bhalf*)(ws + O_FW);
  bhalf* VQT = (bhalf*)(ws + O_VQT);
  bhalf* VKT = (bhalf*)(ws + O_VKT);
  float* G   = (float*)(ws + O_G);
  float* ST2 = (float*)(ws + O_G);    // stat shards reuse G's region (G dead after wf2)
  bhalf* VWT = (bhalf*)(ws + O_VWT);
  bhalf* Q2B = (bhalf*)(ws + O_Q2B);
  bhalf* K2B = (bhalf*)(ws + O_K2B);
  bhalf* W2T = (bhalf*)(ws + O_W2T);
  float* FV  = (float*)(ws + O_FV);
  float* HWS = (float*)(ws + O_HWS);
  float* EDG = (float*)(ws + O_EDG);
  float* XA  = (float*)(ws + O_XA);
  float* XB  = (float*)(ws + O_XB);
  float* XU  = (float*)(ws + O_XU);
  float* XV  = (float*)(ws + O_XV);
  float* EE  = (float*)(ws + O_EE);
  float* ET  = (float*)(ws + O_ET);
  float* XN  = (float*)(ws + O_XN);

  prepAll<<<2176, TPB, 0, stream>>>(fam_q, fam_k, fam_v, arm_q, arm_k, arm_v, epw, WTS,
                                    af, ef, gfm, attf, sfm, PT, FV, G);
  wf2<<<512, TPB, 0, stream>>>(fam_v, arm_q, arm_k, G, FW);
  // G is dead now; zero the stat-shard region (2560 floats) in its place
  hipMemsetAsync(ST2, 0, 2560*sizeof(float), stream);
  kv1<<<dim3(128, 10), TPB, 0, stream>>>(PT, WTS, FW, K1B, VQT, VKT, VWT);
  s1ker<<<640, TPB, 0, stream>>>(PT, WTS, K1B, VQT, VKT, VWT, Q2B, K2B, W2T);
  s2ker<<<3200, TPB, 0, stream>>>(Q2B, K2B, W2T, epb, HWS, ST2 + ST_GS1, ST2 + ST_GS2);

  float* out = (float*)d_out;
  for (int L = 0; L < 2; ++L) {
    float* es1 = ST2 + 512 + L*1024;
    float* es2 = ST2 + 768 + L*1024;
    float* ns1 = ST2 + 1024 + L*1024;
    float* ns2 = ST2 + 1280 + L*1024;
    gnnProj<<<720, TPB, 0, stream>>>(FV, (L == 0) ? HWS : EDG, ST2 + ST_GS1, ST2 + ST_GS2,
                                     gemg, gemb, (L == 0) ? 1 : 0,
                                     As[L], Bs[L], Us[L], Vs[L], Es[L],
                                     XA, XB, XU, XV, EE);
    g2a<<<3200, TPB, 0, stream>>>(XA, XB, EE, ET, es1, es2);
    g2bg3a<<<640, TPB, 0, stream>>>(ET, HWS, EDG, EDG, XV, XU, XN,
                                    ST2 + ST_GS1, ST2 + ST_GS2, gemg, gemb,
                                    bneg[L], bneb[L], es1, es2, ns1, ns2,
                                    efw, efb, out, L);
    if (L == 0)
      g3b<<<640, TPB, 0, stream>>>(XN, FV, bnvg[0], bnvb[0], ns1, ns2, 1);
    else
      g3bfin<<<640, TPB, 0, stream>>>(XN, FV, bnvg[1], bnvb[1], ns1, ns2, scp, out);
  }
}